// Round 1
// baseline (2248.407 us; speedup 1.0000x reference)
//
#include <hip/hip_runtime.h>

#define NN 100000
#define NE 1250000
#define FIN 32
#define HD 64
#define NR 8
#define NG 256
#define BN_EPS 1e-5f

__global__ void k_zero(float* __restrict__ p, int n) {
  int i = blockIdx.x * 256 + threadIdx.x;
  if (i < n) p[i] = 0.0f;
}

// per-(node,relation) edge counts -> later inverted
__global__ void k_count(const int* __restrict__ dst, const int* __restrict__ ty,
                        float* __restrict__ cnt) {
  int e = blockIdx.x * 256 + threadIdx.x;
  if (e < NE) atomicAdd(&cnt[dst[e] * NR + ty[e]], 1.0f);
}

__global__ void k_invcnt(float* __restrict__ cnt) {
  int i = blockIdx.x * 256 + threadIdx.x;
  if (i < NN * NR) cnt[i] = 1.0f / fmaxf(cnt[i], 1.0f);
}

__global__ void k_hist(const int* __restrict__ ty, int* __restrict__ ecnt) {
  __shared__ int lh[NR];
  if (threadIdx.x < NR) lh[threadIdx.x] = 0;
  __syncthreads();
  int e = blockIdx.x * 256 + threadIdx.x;
  if (e < NE) atomicAdd(&lh[ty[e]], 1);
  __syncthreads();
  if (threadIdx.x < NR) atomicAdd(&ecnt[threadIdx.x], lh[threadIdx.x]);
}

__global__ void k_offsets(const int* __restrict__ ecnt, int* __restrict__ eoff,
                          int* __restrict__ epos) {
  if (threadIdx.x == 0) {
    int s = 0;
    for (int r = 0; r < NR; r++) { eoff[r] = s; epos[r] = s; s += ecnt[r]; }
    eoff[NR] = s;
  }
}

// counting-sort edges into per-relation buckets (LDS-aggregated to avoid
// 156K-deep same-address global atomic serialization)
__global__ void k_bucket(const int* __restrict__ src, const int* __restrict__ dst,
                         const int* __restrict__ ty, int* __restrict__ epos,
                         int* __restrict__ bsrc, int* __restrict__ bdst) {
  __shared__ int lh[NR];
  __shared__ int lbase[NR];
  if (threadIdx.x < NR) lh[threadIdx.x] = 0;
  __syncthreads();
  int e = blockIdx.x * 256 + threadIdx.x;
  int t = 0, lpos = 0;
  if (e < NE) {
    t = ty[e];
    lpos = atomicAdd(&lh[t], 1);
  }
  __syncthreads();
  if (threadIdx.x < NR) lbase[threadIdx.x] = atomicAdd(&epos[threadIdx.x], lh[threadIdx.x]);
  __syncthreads();
  if (e < NE) {
    int p = lbase[t] + lpos;
    bsrc[p] = src[e];
    bdst[p] = dst[e];
  }
}

// out[N,64] = X[N,F] @ W[F,64] (+bias). 16 rows/block, 4 rows/thread,
// X rows staged in LDS (broadcast reads), W column reads coalesced+L1-hot.
template <int F, bool BIAS>
__global__ void k_mm(const float* __restrict__ X, const float* __restrict__ W,
                     const float* __restrict__ bias, float* __restrict__ out) {
  __shared__ float xs[16][F];
  int h = threadIdx.x & 63;
  int rg = threadIdx.x >> 6;
  int row0 = blockIdx.x * 16;
  for (int i = threadIdx.x; i < 16 * F; i += 256) {
    xs[i / F][i % F] = X[(size_t)(row0 + i / F) * F + (i % F)];
  }
  __syncthreads();
  float a0 = 0.f, a1 = 0.f, a2 = 0.f, a3 = 0.f;
  for (int k = 0; k < F; k++) {
    float w = W[k * HD + h];
    a0 = fmaf(xs[rg * 4 + 0][k], w, a0);
    a1 = fmaf(xs[rg * 4 + 1][k], w, a1);
    a2 = fmaf(xs[rg * 4 + 2][k], w, a2);
    a3 = fmaf(xs[rg * 4 + 3][k], w, a3);
  }
  float b = BIAS ? bias[h] : 0.0f;
  int r0 = row0 + rg * 4;
  out[(size_t)(r0 + 0) * HD + h] = a0 + b;
  out[(size_t)(r0 + 1) * HD + h] = a1 + b;
  out[(size_t)(r0 + 2) * HD + h] = a2 + b;
  out[(size_t)(r0 + 3) * HD + h] = a3 + b;
}

// out[dst] += h[src] * invcnt[dst,r] over relation-r bucket.
// grid-stride: fixed launch geometry, device-read bucket bounds.
__global__ void k_scatter(const float* __restrict__ hbuf, const int* __restrict__ bsrc,
                          const int* __restrict__ bdst, const int* __restrict__ eoff,
                          const float* __restrict__ invcnt, int r, float* __restrict__ out) {
  int lo = eoff[r], n = eoff[r + 1] - lo;
  int lane = threadIdx.x & 63;
  int grp = threadIdx.x >> 6;
  for (int e = blockIdx.x * 4 + grp; e < n; e += gridDim.x * 4) {
    int s = bsrc[lo + e], d = bdst[lo + e];
    float ic = invcnt[d * NR + r];
    atomicAdd(&out[(size_t)d * HD + lane], hbuf[(size_t)s * HD + lane] * ic);
  }
}

// column sums / sumsq with per-block LDS reduce -> ~512 atomics/address
__global__ void k_bnstats(const float* __restrict__ x, float* __restrict__ stats) {
  __shared__ float sr[256], ssr[256];
  int lane = threadIdx.x & 63, grp = threadIdx.x >> 6;
  float s = 0.f, ss = 0.f;
  for (int i = blockIdx.x * 4 + grp; i < NN; i += gridDim.x * 4) {
    float v = x[(size_t)i * HD + lane];
    s += v;
    ss = fmaf(v, v, ss);
  }
  sr[threadIdx.x] = s;
  ssr[threadIdx.x] = ss;
  __syncthreads();
  if (grp == 0) {
    s = sr[lane] + sr[64 + lane] + sr[128 + lane] + sr[192 + lane];
    ss = ssr[lane] + ssr[64 + lane] + ssr[128 + lane] + ssr[192 + lane];
    atomicAdd(&stats[lane], s);
    atomicAdd(&stats[64 + lane], ss);
  }
}

__global__ void k_bnapply(const float* __restrict__ xin, const float* __restrict__ stats,
                          const float* __restrict__ g, const float* __restrict__ b,
                          float* __restrict__ xout) {
  int lane = threadIdx.x & 63;
  int i = blockIdx.x * 4 + (threadIdx.x >> 6);
  float mu = stats[lane] * (1.0f / NN);
  float var = stats[64 + lane] * (1.0f / NN) - mu * mu;
  float sc = g[lane] * rsqrtf(var + BN_EPS);
  float sh = b[lane] - mu * sc;
  float v = fmaf(xin[(size_t)i * HD + lane], sc, sh);
  xout[(size_t)i * HD + lane] = fmaxf(v, 0.0f);
}

// graph pooling: mean-sums via atomicAdd, max via uint-punned atomicMax
// (valid: post-ReLU values >= 0; empty graph -> 0 matches reference)
__global__ void k_pool(const float* __restrict__ x1, const float* __restrict__ x2,
                       const float* __restrict__ x3, const int* __restrict__ batch,
                       float* __restrict__ psum, unsigned* __restrict__ pmax,
                       float* __restrict__ cntg) {
  int i = blockIdx.x;
  int c = threadIdx.x;  // 0..191
  int g = batch[i];
  float v = (c < 64) ? x1[(size_t)i * 64 + c]
          : (c < 128) ? x2[(size_t)i * 64 + (c - 64)]
                      : x3[(size_t)i * 64 + (c - 128)];
  atomicAdd(&psum[g * 192 + c], v);
  atomicMax(&pmax[g * 192 + c], __float_as_uint(v));
  if (c == 0) atomicAdd(&cntg[g], 1.0f);
}

// fc1: x_graph[g] (built in LDS from pool buffers) @ fc1_w[384,128] + b
__global__ void k_fc1(const float* __restrict__ psum, const unsigned* __restrict__ pmax,
                      const float* __restrict__ cntg, const float* __restrict__ w,
                      const float* __restrict__ bias, float* __restrict__ h1) {
  __shared__ float a[384];
  int g = blockIdx.x;
  float ic = 1.0f / fmaxf(cntg[g], 1.0f);
  for (int c = threadIdx.x; c < 384; c += 128) {
    a[c] = (c < 192) ? psum[g * 192 + c] * ic : __uint_as_float(pmax[g * 192 + (c - 192)]);
  }
  __syncthreads();
  int j = threadIdx.x;
  float acc = bias[j];
  for (int k = 0; k < 384; k++) acc = fmaf(a[k], w[k * 128 + j], acc);
  h1[g * 128 + j] = acc;
}

__global__ void k_fcbn_stats(const float* __restrict__ h1, const float* __restrict__ g,
                             const float* __restrict__ b, float* __restrict__ scsh) {
  __shared__ float sr[512], ssr[512];
  int j = threadIdx.x & 127, q = threadIdx.x >> 7;
  float s = 0.f, ss = 0.f;
  for (int i = q * 64; i < q * 64 + 64; i++) {
    float v = h1[i * 128 + j];
    s += v;
    ss = fmaf(v, v, ss);
  }
  sr[threadIdx.x] = s;
  ssr[threadIdx.x] = ss;
  __syncthreads();
  if (q == 0) {
    s = sr[j] + sr[128 + j] + sr[256 + j] + sr[384 + j];
    ss = ssr[j] + ssr[128 + j] + ssr[256 + j] + ssr[384 + j];
    float mu = s * (1.0f / NG);
    float var = ss * (1.0f / NG) - mu * mu;
    float sc = g[j] * rsqrtf(var + BN_EPS);
    scsh[j] = sc;
    scsh[128 + j] = b[j] - mu * sc;
  }
}

__global__ void k_leaky(float* __restrict__ h1, const float* __restrict__ scsh) {
  int j = threadIdx.x;
  int g = blockIdx.x;
  float v = fmaf(h1[g * 128 + j], scsh[j], scsh[128 + j]);
  h1[g * 128 + j] = v > 0.0f ? v : 0.2f * v;
}

// emb = h1 @ fc2 + b (written to out); pred = leaky(emb@dec1+b1)@dec2 + b2
__global__ void k_head(const float* __restrict__ h1, const float* __restrict__ fc2w,
                       const float* __restrict__ fc2b, const float* __restrict__ d1w,
                       const float* __restrict__ d1b, const float* __restrict__ d2w,
                       const float* __restrict__ d2b, float* __restrict__ out) {
  __shared__ float emb[16];
  int g = blockIdx.x;
  int t = threadIdx.x;  // 0..63
  if (t < 16) {
    float acc = fc2b[t];
    for (int k = 0; k < 128; k++) acc = fmaf(h1[g * 128 + k], fc2w[k * 16 + t], acc);
    emb[t] = acc;
    out[NG + g * 16 + t] = acc;  // emb section after 256 preds
  }
  __syncthreads();
  float acc = d1b[t];
  for (int k = 0; k < 16; k++) acc = fmaf(emb[k], d1w[k * 64 + t], acc);
  acc = acc > 0.0f ? acc : 0.2f * acc;
  float p = acc * d2w[t];
  for (int off = 32; off > 0; off >>= 1) p += __shfl_down(p, off);
  if (t == 0) out[g] = p + d2b[0];
}

extern "C" void kernel_launch(void* const* d_in, const int* in_sizes, int n_in,
                              void* d_out, int out_size, void* d_ws, size_t ws_size,
                              hipStream_t stream) {
  const float* x    = (const float*)d_in[0];
  const int*   ei   = (const int*)d_in[1];
  const int*   ety  = (const int*)d_in[2];
  const int*   batch= (const int*)d_in[3];
  const float* c1w  = (const float*)d_in[4];
  const float* c1r  = (const float*)d_in[5];
  const float* c1b  = (const float*)d_in[6];
  const float* bn1g = (const float*)d_in[7];
  const float* bn1b = (const float*)d_in[8];
  const float* c2w  = (const float*)d_in[9];
  const float* c2r  = (const float*)d_in[10];
  const float* c2b  = (const float*)d_in[11];
  const float* bn2g = (const float*)d_in[12];
  const float* bn2b = (const float*)d_in[13];
  const float* c3w  = (const float*)d_in[14];
  const float* c3r  = (const float*)d_in[15];
  const float* c3b  = (const float*)d_in[16];
  const float* bn3g = (const float*)d_in[17];
  const float* bn3b = (const float*)d_in[18];
  const float* fc1w = (const float*)d_in[19];
  const float* fc1b = (const float*)d_in[20];
  const float* fbg  = (const float*)d_in[21];
  const float* fbb  = (const float*)d_in[22];
  const float* fc2w = (const float*)d_in[23];
  const float* fc2b = (const float*)d_in[24];
  const float* d1w  = (const float*)d_in[25];
  const float* d1b  = (const float*)d_in[26];
  const float* d2w  = (const float*)d_in[27];
  const float* d2b  = (const float*)d_in[28];
  const int* esrc = ei;
  const int* edst = ei + NE;
  float* out = (float*)d_out;

  float* W = (float*)d_ws;
  size_t o = 0;
  auto alloc = [&](size_t n) { float* p = W + o; o += (n + 63) & ~(size_t)63; return p; };
  float*    invcnt = alloc((size_t)NN * NR);
  int*      ecnt   = (int*)alloc(NR);
  float*    psum   = alloc(NG * 192);
  unsigned* pmax   = (unsigned*)alloc(NG * 192);
  float*    cntg   = alloc(NG);
  size_t zone = o;  // buffers [0, zone) need zeroing every call
  float*    stats  = alloc(128);
  int*      eoff   = (int*)alloc(NR + 1);
  int*      epos   = (int*)alloc(NR);
  float*    scsh   = alloc(256);
  float*    h1     = alloc(NG * 128);
  float*    x1     = alloc((size_t)NN * HD);
  float*    x2     = alloc((size_t)NN * HD);
  float*    x3     = alloc((size_t)NN * HD);
  float*    hbuf   = alloc((size_t)NN * HD);
  float*    tmp    = alloc((size_t)NN * HD);
  int*      bsrc   = (int*)alloc(NE);
  int*      bdst   = (int*)alloc(NE);
  (void)ws_size; (void)in_sizes; (void)n_in; (void)out_size;

  // preprocess: counts, inverse means, relation buckets
  k_zero<<<(int)((zone + 255) / 256), 256, 0, stream>>>(W, (int)zone);
  k_count<<<(NE + 255) / 256, 256, 0, stream>>>(edst, ety, invcnt);
  k_invcnt<<<(NN * NR + 255) / 256, 256, 0, stream>>>(invcnt);
  k_hist<<<(NE + 255) / 256, 256, 0, stream>>>(ety, ecnt);
  k_offsets<<<1, 64, 0, stream>>>(ecnt, eoff, epos);
  k_bucket<<<(NE + 255) / 256, 256, 0, stream>>>(esrc, edst, ety, epos, bsrc, bdst);

  auto layer32 = [&](const float* xin, const float* cw, const float* cr, const float* cb,
                     const float* bg, const float* bb, float* xout) {
    k_mm<FIN, true><<<NN / 16, 256, 0, stream>>>(xin, cr, cb, tmp);
    for (int r = 0; r < NR; r++) {
      k_mm<FIN, false><<<NN / 16, 256, 0, stream>>>(xin, cw + (size_t)r * FIN * HD, nullptr, hbuf);
      k_scatter<<<2048, 256, 0, stream>>>(hbuf, bsrc, bdst, eoff, invcnt, r, tmp);
    }
    k_zero<<<1, 256, 0, stream>>>(stats, 128);
    k_bnstats<<<512, 256, 0, stream>>>(tmp, stats);
    k_bnapply<<<NN / 4, 256, 0, stream>>>(tmp, stats, bg, bb, xout);
  };
  auto layer64 = [&](const float* xin, const float* cw, const float* cr, const float* cb,
                     const float* bg, const float* bb, float* xout) {
    k_mm<HD, true><<<NN / 16, 256, 0, stream>>>(xin, cr, cb, tmp);
    for (int r = 0; r < NR; r++) {
      k_mm<HD, false><<<NN / 16, 256, 0, stream>>>(xin, cw + (size_t)r * HD * HD, nullptr, hbuf);
      k_scatter<<<2048, 256, 0, stream>>>(hbuf, bsrc, bdst, eoff, invcnt, r, tmp);
    }
    k_zero<<<1, 256, 0, stream>>>(stats, 128);
    k_bnstats<<<512, 256, 0, stream>>>(tmp, stats);
    k_bnapply<<<NN / 4, 256, 0, stream>>>(tmp, stats, bg, bb, xout);
  };

  layer32(x,  c1w, c1r, c1b, bn1g, bn1b, x1);
  layer64(x1, c2w, c2r, c2b, bn2g, bn2b, x2);
  layer64(x2, c3w, c3r, c3b, bn3g, bn3b, x3);

  // pooling + head
  k_pool<<<NN, 192, 0, stream>>>(x1, x2, x3, batch, psum, pmax, cntg);
  k_fc1<<<NG, 128, 0, stream>>>(psum, pmax, cntg, fc1w, fc1b, h1);
  k_fcbn_stats<<<1, 512, 0, stream>>>(h1, fbg, fbb, scsh);
  k_leaky<<<NG, 128, 0, stream>>>(h1, scsh);
  k_head<<<NG, 64, 0, stream>>>(h1, fc2w, fc2b, d1w, d1b, d2w, d2b, out);
}

// Round 2
// 1755.711 us; speedup vs baseline: 1.2806x; 1.2806x over previous
//
#include <hip/hip_runtime.h>

#define NN 100000
#define NE 1250000
#define FIN 32
#define HD 64
#define NR 8
#define NG 256
#define BN_EPS 1e-5f
#define PCH 100  // nodes per pooling block (divides NN)

__global__ void k_zero(float* __restrict__ p, int n) {
  int i = blockIdx.x * 256 + threadIdx.x;
  if (i < n) p[i] = 0.0f;
}

// per-(node,relation) edge counts -> later inverted
__global__ void k_count(const int* __restrict__ dst, const int* __restrict__ ty,
                        float* __restrict__ cnt) {
  int e = blockIdx.x * 256 + threadIdx.x;
  if (e < NE) atomicAdd(&cnt[dst[e] * NR + ty[e]], 1.0f);
}

__global__ void k_invcnt(float* __restrict__ cnt) {
  int i = blockIdx.x * 256 + threadIdx.x;
  if (i < NN * NR) cnt[i] = 1.0f / fmaxf(cnt[i], 1.0f);
}

__global__ void k_hist(const int* __restrict__ ty, int* __restrict__ ecnt) {
  __shared__ int lh[NR];
  if (threadIdx.x < NR) lh[threadIdx.x] = 0;
  __syncthreads();
  int e = blockIdx.x * 256 + threadIdx.x;
  if (e < NE) atomicAdd(&lh[ty[e]], 1);
  __syncthreads();
  if (threadIdx.x < NR) atomicAdd(&ecnt[threadIdx.x], lh[threadIdx.x]);
}

__global__ void k_offsets(const int* __restrict__ ecnt, int* __restrict__ eoff,
                          int* __restrict__ epos) {
  if (threadIdx.x == 0) {
    int s = 0;
    for (int r = 0; r < NR; r++) { eoff[r] = s; epos[r] = s; s += ecnt[r]; }
    eoff[NR] = s;
  }
}

// counting-sort edges into per-relation buckets (LDS-aggregated to avoid
// 156K-deep same-address global atomic serialization)
__global__ void k_bucket(const int* __restrict__ src, const int* __restrict__ dst,
                         const int* __restrict__ ty, int* __restrict__ epos,
                         int* __restrict__ bsrc, int* __restrict__ bdst) {
  __shared__ int lh[NR];
  __shared__ int lbase[NR];
  if (threadIdx.x < NR) lh[threadIdx.x] = 0;
  __syncthreads();
  int e = blockIdx.x * 256 + threadIdx.x;
  int t = 0, lpos = 0;
  if (e < NE) {
    t = ty[e];
    lpos = atomicAdd(&lh[t], 1);
  }
  __syncthreads();
  if (threadIdx.x < NR) lbase[threadIdx.x] = atomicAdd(&epos[threadIdx.x], lh[threadIdx.x]);
  __syncthreads();
  if (e < NE) {
    int p = lbase[t] + lpos;
    bsrc[p] = src[e];
    bdst[p] = dst[e];
  }
}

// out[N,64] = X[N,F] @ W[F,64] (+bias). 16 rows/block, 4 rows/thread,
// X rows staged in LDS (broadcast reads), W column reads coalesced+L1-hot.
template <int F, bool BIAS>
__global__ void k_mm(const float* __restrict__ X, const float* __restrict__ W,
                     const float* __restrict__ bias, float* __restrict__ out) {
  __shared__ float xs[16][F];
  int h = threadIdx.x & 63;
  int rg = threadIdx.x >> 6;
  int row0 = blockIdx.x * 16;
  for (int i = threadIdx.x; i < 16 * F; i += 256) {
    xs[i / F][i % F] = X[(size_t)(row0 + i / F) * F + (i % F)];
  }
  __syncthreads();
  float a0 = 0.f, a1 = 0.f, a2 = 0.f, a3 = 0.f;
  for (int k = 0; k < F; k++) {
    float w = W[k * HD + h];
    a0 = fmaf(xs[rg * 4 + 0][k], w, a0);
    a1 = fmaf(xs[rg * 4 + 1][k], w, a1);
    a2 = fmaf(xs[rg * 4 + 2][k], w, a2);
    a3 = fmaf(xs[rg * 4 + 3][k], w, a3);
  }
  float b = BIAS ? bias[h] : 0.0f;
  int r0 = row0 + rg * 4;
  out[(size_t)(r0 + 0) * HD + h] = a0 + b;
  out[(size_t)(r0 + 1) * HD + h] = a1 + b;
  out[(size_t)(r0 + 2) * HD + h] = a2 + b;
  out[(size_t)(r0 + 3) * HD + h] = a3 + b;
}

// out[dst] += h[src] * invcnt[dst,r] over relation-r bucket.
// grid-stride: fixed launch geometry, device-read bucket bounds.
__global__ void k_scatter(const float* __restrict__ hbuf, const int* __restrict__ bsrc,
                          const int* __restrict__ bdst, const int* __restrict__ eoff,
                          const float* __restrict__ invcnt, int r, float* __restrict__ out) {
  int lo = eoff[r], n = eoff[r + 1] - lo;
  int lane = threadIdx.x & 63;
  int grp = threadIdx.x >> 6;
  for (int e = blockIdx.x * 4 + grp; e < n; e += gridDim.x * 4) {
    int s = bsrc[lo + e], d = bdst[lo + e];
    float ic = invcnt[d * NR + r];
    atomicAdd(&out[(size_t)d * HD + lane], hbuf[(size_t)s * HD + lane] * ic);
  }
}

// column sums / sumsq with per-block LDS reduce -> ~512 atomics/address
__global__ void k_bnstats(const float* __restrict__ x, float* __restrict__ stats) {
  __shared__ float sr[256], ssr[256];
  int lane = threadIdx.x & 63, grp = threadIdx.x >> 6;
  float s = 0.f, ss = 0.f;
  for (int i = blockIdx.x * 4 + grp; i < NN; i += gridDim.x * 4) {
    float v = x[(size_t)i * HD + lane];
    s += v;
    ss = fmaf(v, v, ss);
  }
  sr[threadIdx.x] = s;
  ssr[threadIdx.x] = ss;
  __syncthreads();
  if (grp == 0) {
    s = sr[lane] + sr[64 + lane] + sr[128 + lane] + sr[192 + lane];
    ss = ssr[lane] + ssr[64 + lane] + ssr[128 + lane] + ssr[192 + lane];
    atomicAdd(&stats[lane], s);
    atomicAdd(&stats[64 + lane], ss);
  }
}

__global__ void k_bnapply(const float* __restrict__ xin, const float* __restrict__ stats,
                          const float* __restrict__ g, const float* __restrict__ b,
                          float* __restrict__ xout) {
  int lane = threadIdx.x & 63;
  int i = blockIdx.x * 4 + (threadIdx.x >> 6);
  float mu = stats[lane] * (1.0f / NN);
  float var = stats[64 + lane] * (1.0f / NN) - mu * mu;
  float sc = g[lane] * rsqrtf(var + BN_EPS);
  float sh = b[lane] - mu * sc;
  float v = fmaf(xin[(size_t)i * HD + lane], sc, sh);
  xout[(size_t)i * HD + lane] = fmaxf(v, 0.0f);
}

// sorted-batch segmented pooling: register-accumulate per equal-graph run,
// atomics only at run boundaries (~1.3K flushes total vs 19.2M before).
// max via uint-punned atomicMax (valid: post-ReLU values >= 0).
__global__ void k_poolseg(const float* __restrict__ x1, const float* __restrict__ x2,
                          const float* __restrict__ x3, const int* __restrict__ batch,
                          float* __restrict__ psum, unsigned* __restrict__ pmax,
                          float* __restrict__ cntg) {
  __shared__ int bsh[PCH];
  int base = blockIdx.x * PCH;
  int c = threadIdx.x;  // 0..191
  for (int i = c; i < PCH; i += 192) bsh[i] = batch[base + i];
  __syncthreads();
  const float* xs = (c < 64) ? x1 : (c < 128) ? x2 : x3;
  int cc = c & 63;
  int cur = bsh[0];
  float sum = 0.0f, mx = 0.0f;
  int runlen = 0;
  #pragma unroll 4
  for (int i = 0; i < PCH; i++) {
    int g = bsh[i];
    float v = xs[(size_t)(base + i) * 64 + cc];
    if (g != cur) {  // wave-uniform, rare (~0.25/block)
      atomicAdd(&psum[cur * 192 + c], sum);
      atomicMax(&pmax[cur * 192 + c], __float_as_uint(mx));
      if (c == 0) atomicAdd(&cntg[cur], (float)runlen);
      cur = g; sum = 0.0f; mx = 0.0f; runlen = 0;
    }
    sum += v;
    mx = fmaxf(mx, v);
    runlen++;
  }
  atomicAdd(&psum[cur * 192 + c], sum);
  atomicMax(&pmax[cur * 192 + c], __float_as_uint(mx));
  if (c == 0) atomicAdd(&cntg[cur], (float)runlen);
}

// fc1: x_graph[g] (built in LDS from pool buffers) @ fc1_w[384,128] + b
__global__ void k_fc1(const float* __restrict__ psum, const unsigned* __restrict__ pmax,
                      const float* __restrict__ cntg, const float* __restrict__ w,
                      const float* __restrict__ bias, float* __restrict__ h1) {
  __shared__ float a[384];
  int g = blockIdx.x;
  float ic = 1.0f / fmaxf(cntg[g], 1.0f);
  for (int c = threadIdx.x; c < 384; c += 128) {
    a[c] = (c < 192) ? psum[g * 192 + c] * ic : __uint_as_float(pmax[g * 192 + (c - 192)]);
  }
  __syncthreads();
  int j = threadIdx.x;
  float acc = bias[j];
  for (int k = 0; k < 384; k++) acc = fmaf(a[k], w[k * 128 + j], acc);
  h1[g * 128 + j] = acc;
}

__global__ void k_fcbn_stats(const float* __restrict__ h1, const float* __restrict__ g,
                             const float* __restrict__ b, float* __restrict__ scsh) {
  __shared__ float sr[512], ssr[512];
  int j = threadIdx.x & 127, q = threadIdx.x >> 7;
  float s = 0.f, ss = 0.f;
  for (int i = q * 64; i < q * 64 + 64; i++) {
    float v = h1[i * 128 + j];
    s += v;
    ss = fmaf(v, v, ss);
  }
  sr[threadIdx.x] = s;
  ssr[threadIdx.x] = ss;
  __syncthreads();
  if (q == 0) {
    s = sr[j] + sr[128 + j] + sr[256 + j] + sr[384 + j];
    ss = ssr[j] + ssr[128 + j] + ssr[256 + j] + ssr[384 + j];
    float mu = s * (1.0f / NG);
    float var = ss * (1.0f / NG) - mu * mu;
    float sc = g[j] * rsqrtf(var + BN_EPS);
    scsh[j] = sc;
    scsh[128 + j] = b[j] - mu * sc;
  }
}

__global__ void k_leaky(float* __restrict__ h1, const float* __restrict__ scsh) {
  int j = threadIdx.x;
  int g = blockIdx.x;
  float v = fmaf(h1[g * 128 + j], scsh[j], scsh[128 + j]);
  h1[g * 128 + j] = v > 0.0f ? v : 0.2f * v;
}

// emb = h1 @ fc2 + b (written to out); pred = leaky(emb@dec1+b1)@dec2 + b2
__global__ void k_head(const float* __restrict__ h1, const float* __restrict__ fc2w,
                       const float* __restrict__ fc2b, const float* __restrict__ d1w,
                       const float* __restrict__ d1b, const float* __restrict__ d2w,
                       const float* __restrict__ d2b, float* __restrict__ out) {
  __shared__ float emb[16];
  int g = blockIdx.x;
  int t = threadIdx.x;  // 0..63
  if (t < 16) {
    float acc = fc2b[t];
    for (int k = 0; k < 128; k++) acc = fmaf(h1[g * 128 + k], fc2w[k * 16 + t], acc);
    emb[t] = acc;
    out[NG + g * 16 + t] = acc;  // emb section after 256 preds
  }
  __syncthreads();
  float acc = d1b[t];
  for (int k = 0; k < 16; k++) acc = fmaf(emb[k], d1w[k * 64 + t], acc);
  acc = acc > 0.0f ? acc : 0.2f * acc;
  float p = acc * d2w[t];
  for (int off = 32; off > 0; off >>= 1) p += __shfl_down(p, off);
  if (t == 0) out[g] = p + d2b[0];
}

extern "C" void kernel_launch(void* const* d_in, const int* in_sizes, int n_in,
                              void* d_out, int out_size, void* d_ws, size_t ws_size,
                              hipStream_t stream) {
  const float* x    = (const float*)d_in[0];
  const int*   ei   = (const int*)d_in[1];
  const int*   ety  = (const int*)d_in[2];
  const int*   batch= (const int*)d_in[3];
  const float* c1w  = (const float*)d_in[4];
  const float* c1r  = (const float*)d_in[5];
  const float* c1b  = (const float*)d_in[6];
  const float* bn1g = (const float*)d_in[7];
  const float* bn1b = (const float*)d_in[8];
  const float* c2w  = (const float*)d_in[9];
  const float* c2r  = (const float*)d_in[10];
  const float* c2b  = (const float*)d_in[11];
  const float* bn2g = (const float*)d_in[12];
  const float* bn2b = (const float*)d_in[13];
  const float* c3w  = (const float*)d_in[14];
  const float* c3r  = (const float*)d_in[15];
  const float* c3b  = (const float*)d_in[16];
  const float* bn3g = (const float*)d_in[17];
  const float* bn3b = (const float*)d_in[18];
  const float* fc1w = (const float*)d_in[19];
  const float* fc1b = (const float*)d_in[20];
  const float* fbg  = (const float*)d_in[21];
  const float* fbb  = (const float*)d_in[22];
  const float* fc2w = (const float*)d_in[23];
  const float* fc2b = (const float*)d_in[24];
  const float* d1w  = (const float*)d_in[25];
  const float* d1b  = (const float*)d_in[26];
  const float* d2w  = (const float*)d_in[27];
  const float* d2b  = (const float*)d_in[28];
  const int* esrc = ei;
  const int* edst = ei + NE;
  float* out = (float*)d_out;

  float* W = (float*)d_ws;
  size_t o = 0;
  auto alloc = [&](size_t n) { float* p = W + o; o += (n + 63) & ~(size_t)63; return p; };
  float*    invcnt = alloc((size_t)NN * NR);
  int*      ecnt   = (int*)alloc(NR);
  float*    psum   = alloc(NG * 192);
  unsigned* pmax   = (unsigned*)alloc(NG * 192);
  float*    cntg   = alloc(NG);
  size_t zone = o;  // buffers [0, zone) need zeroing every call
  float*    stats  = alloc(128);
  int*      eoff   = (int*)alloc(NR + 1);
  int*      epos   = (int*)alloc(NR);
  float*    scsh   = alloc(256);
  float*    h1     = alloc(NG * 128);
  float*    x1     = alloc((size_t)NN * HD);
  float*    x2     = alloc((size_t)NN * HD);
  float*    x3     = alloc((size_t)NN * HD);
  float*    hbuf   = alloc((size_t)NN * HD);
  float*    tmp    = alloc((size_t)NN * HD);
  int*      bsrc   = (int*)alloc(NE);
  int*      bdst   = (int*)alloc(NE);
  (void)ws_size; (void)in_sizes; (void)n_in; (void)out_size;

  // preprocess: counts, inverse means, relation buckets
  k_zero<<<(int)((zone + 255) / 256), 256, 0, stream>>>(W, (int)zone);
  k_count<<<(NE + 255) / 256, 256, 0, stream>>>(edst, ety, invcnt);
  k_invcnt<<<(NN * NR + 255) / 256, 256, 0, stream>>>(invcnt);
  k_hist<<<(NE + 255) / 256, 256, 0, stream>>>(ety, ecnt);
  k_offsets<<<1, 64, 0, stream>>>(ecnt, eoff, epos);
  k_bucket<<<(NE + 255) / 256, 256, 0, stream>>>(esrc, edst, ety, epos, bsrc, bdst);

  auto layer32 = [&](const float* xin, const float* cw, const float* cr, const float* cb,
                     const float* bg, const float* bb, float* xout) {
    k_mm<FIN, true><<<NN / 16, 256, 0, stream>>>(xin, cr, cb, tmp);
    for (int r = 0; r < NR; r++) {
      k_mm<FIN, false><<<NN / 16, 256, 0, stream>>>(xin, cw + (size_t)r * FIN * HD, nullptr, hbuf);
      k_scatter<<<2048, 256, 0, stream>>>(hbuf, bsrc, bdst, eoff, invcnt, r, tmp);
    }
    k_zero<<<1, 256, 0, stream>>>(stats, 128);
    k_bnstats<<<512, 256, 0, stream>>>(tmp, stats);
    k_bnapply<<<NN / 4, 256, 0, stream>>>(tmp, stats, bg, bb, xout);
  };
  auto layer64 = [&](const float* xin, const float* cw, const float* cr, const float* cb,
                     const float* bg, const float* bb, float* xout) {
    k_mm<HD, true><<<NN / 16, 256, 0, stream>>>(xin, cr, cb, tmp);
    for (int r = 0; r < NR; r++) {
      k_mm<HD, false><<<NN / 16, 256, 0, stream>>>(xin, cw + (size_t)r * HD * HD, nullptr, hbuf);
      k_scatter<<<2048, 256, 0, stream>>>(hbuf, bsrc, bdst, eoff, invcnt, r, tmp);
    }
    k_zero<<<1, 256, 0, stream>>>(stats, 128);
    k_bnstats<<<512, 256, 0, stream>>>(tmp, stats);
    k_bnapply<<<NN / 4, 256, 0, stream>>>(tmp, stats, bg, bb, xout);
  };

  layer32(x,  c1w, c1r, c1b, bn1g, bn1b, x1);
  layer64(x1, c2w, c2r, c2b, bn2g, bn2b, x2);
  layer64(x2, c3w, c3r, c3b, bn3g, bn3b, x3);

  // pooling + head
  k_poolseg<<<NN / PCH, 192, 0, stream>>>(x1, x2, x3, batch, psum, pmax, cntg);
  k_fc1<<<NG, 128, 0, stream>>>(psum, pmax, cntg, fc1w, fc1b, h1);
  k_fcbn_stats<<<1, 512, 0, stream>>>(h1, fbg, fbb, scsh);
  k_leaky<<<NG, 128, 0, stream>>>(h1, scsh);
  k_head<<<NG, 64, 0, stream>>>(h1, fc2w, fc2b, d1w, d1b, d2w, d2b, out);
}

// Round 3
// 1347.534 us; speedup vs baseline: 1.6685x; 1.3029x over previous
//
#include <hip/hip_runtime.h>

#define NN 100000
#define NE 1250000
#define FIN 32
#define HD 64
#define NR 8
#define NG 256
#define BN_EPS 1e-5f
#define PCH 100          // nodes per pooling block (divides NN)
#define M_KEYS (NN * NR) // 800000 (dst,rel) segments
#define NB 782           // scan blocks: 782*1024 >= 800000

__global__ void k_zero(float* __restrict__ p, int n) {
  int i = blockIdx.x * 256 + threadIdx.x;
  if (i < n) p[i] = 0.0f;
}

// pass 1: per-(dst,rel) counts + per-edge rank (stable position within segment)
__global__ void k_cnt(const int* __restrict__ dst, const int* __restrict__ ty,
                      unsigned* __restrict__ cnt, int* __restrict__ rank) {
  int e = blockIdx.x * 256 + threadIdx.x;
  if (e < NE) {
    int key = dst[e] * NR + ty[e];
    rank[e] = (int)atomicAdd(&cnt[key], 1u);
  }
}

// hierarchical exclusive scan of cnt[M_KEYS] -> rowstart[M_KEYS+1]
__global__ void k_scanA(const unsigned* __restrict__ cnt, unsigned* __restrict__ bsum) {
  __shared__ unsigned red[256];
  int t = threadIdx.x;
  int base = blockIdx.x * 1024 + t * 4;
  unsigned s = 0;
  #pragma unroll
  for (int i = 0; i < 4; i++) {
    int idx = base + i;
    if (idx < M_KEYS) s += cnt[idx];
  }
  red[t] = s;
  __syncthreads();
  for (int off = 128; off > 0; off >>= 1) {
    if (t < off) red[t] += red[t + off];
    __syncthreads();
  }
  if (t == 0) bsum[blockIdx.x] = red[0];
}

__global__ __launch_bounds__(1024) void k_scanB(const unsigned* __restrict__ bsum,
                                                unsigned* __restrict__ boff,
                                                int* __restrict__ rowstart) {
  __shared__ unsigned sb[1024];
  int t = threadIdx.x;
  unsigned mine = (t < NB) ? bsum[t] : 0u;
  sb[t] = mine;
  __syncthreads();
  for (int off = 1; off < 1024; off <<= 1) {
    unsigned v = (t >= off) ? sb[t - off] : 0u;
    __syncthreads();
    sb[t] += v;
    __syncthreads();
  }
  if (t < NB) boff[t] = sb[t] - mine;
  if (t == 1023) rowstart[M_KEYS] = (int)sb[1023];
}

__global__ void k_scanC(const unsigned* __restrict__ cnt, const unsigned* __restrict__ boff,
                        int* __restrict__ rowstart) {
  __shared__ unsigned sb[256];
  int t = threadIdx.x;
  int base = blockIdx.x * 1024 + t * 4;
  unsigned c0 = (base + 0 < M_KEYS) ? cnt[base + 0] : 0u;
  unsigned c1 = (base + 1 < M_KEYS) ? cnt[base + 1] : 0u;
  unsigned c2 = (base + 2 < M_KEYS) ? cnt[base + 2] : 0u;
  unsigned c3 = (base + 3 < M_KEYS) ? cnt[base + 3] : 0u;
  unsigned tot = c0 + c1 + c2 + c3;
  sb[t] = tot;
  __syncthreads();
  for (int off = 1; off < 256; off <<= 1) {
    unsigned v = (t >= off) ? sb[t - off] : 0u;
    __syncthreads();
    sb[t] += v;
    __syncthreads();
  }
  unsigned run = boff[blockIdx.x] + (sb[t] - tot);
  if (base + 0 < M_KEYS) rowstart[base + 0] = (int)run; run += c0;
  if (base + 1 < M_KEYS) rowstart[base + 1] = (int)run; run += c1;
  if (base + 2 < M_KEYS) rowstart[base + 2] = (int)run; run += c2;
  if (base + 3 < M_KEYS) rowstart[base + 3] = (int)run;
}

// pass 2: place src indices into (dst,rel)-CSR
__global__ void k_place(const int* __restrict__ src, const int* __restrict__ dst,
                        const int* __restrict__ ty, const int* __restrict__ rank,
                        const int* __restrict__ rowstart, int* __restrict__ ebuf) {
  int e = blockIdx.x * 256 + threadIdx.x;
  if (e < NE) {
    int key = dst[e] * NR + ty[e];
    ebuf[rowstart[key] + rank[e]] = src[e];
  }
}

// Fused RGCN layer: per wave, 4 dst nodes.
// Phase A: gather+mean neighbor rows per relation into LDS row [9*F] (slot 8 = self).
// Phase B: out[n,h] = bias[h] + row @ [W_0..W_7 | root]  (K = 9F register GEMM,
// W streamed coalesced, L1/L2-hot since identical across blocks). No atomics.
template <int F>
__global__ __launch_bounds__(256) void k_layer(
    const float* __restrict__ xin, const int* __restrict__ rs,
    const int* __restrict__ ebuf, const float* __restrict__ convw,
    const float* __restrict__ root, const float* __restrict__ bias,
    float* __restrict__ outp) {
  constexpr int KT = 9 * F;
  __shared__ float agg[16 * KT];
  int lane = threadIdx.x & 63;
  int w = threadIdx.x >> 6;
  int nbase = blockIdx.x * 16 + w * 4;

  // ---- phase A ----
  for (int j = 0; j < 4; j++) {
    int n = nbase + j;
    float* row = &agg[(w * 4 + j) * KT];
    if (lane < F) {
      #pragma unroll
      for (int r = 0; r < NR; r++) {
        int lo = rs[n * NR + r], hi = rs[n * NR + r + 1];
        float a0 = 0.f, a1 = 0.f;
        int e = lo;
        for (; e + 1 < hi; e += 2) {  // 2-way ILP on the gather
          int s0 = ebuf[e], s1 = ebuf[e + 1];
          a0 += xin[(size_t)s0 * F + lane];
          a1 += xin[(size_t)s1 * F + lane];
        }
        if (e < hi) a0 += xin[(size_t)ebuf[e] * F + lane];
        float inv = 1.0f / fmaxf((float)(hi - lo), 1.0f);
        row[r * F + lane] = (a0 + a1) * inv;
      }
      row[8 * F + lane] = xin[(size_t)n * F + lane];  // self (root) slot
    }
  }
  // no __syncthreads needed: phase B reads only this wave's own rows

  // ---- phase B ----
  float b = bias[lane];
  float a0 = b, a1 = b, a2 = b, a3 = b;
  const float* rowbase = &agg[(w * 4) * KT];
  for (int k = 0; k < 8 * F; k += 4) {
    float w0 = convw[(k + 0) * HD + lane];
    float w1 = convw[(k + 1) * HD + lane];
    float w2 = convw[(k + 2) * HD + lane];
    float w3 = convw[(k + 3) * HD + lane];
    float4 v0 = *(const float4*)&rowbase[0 * KT + k];
    float4 v1 = *(const float4*)&rowbase[1 * KT + k];
    float4 v2 = *(const float4*)&rowbase[2 * KT + k];
    float4 v3 = *(const float4*)&rowbase[3 * KT + k];
    a0 = fmaf(v0.x, w0, fmaf(v0.y, w1, fmaf(v0.z, w2, fmaf(v0.w, w3, a0))));
    a1 = fmaf(v1.x, w0, fmaf(v1.y, w1, fmaf(v1.z, w2, fmaf(v1.w, w3, a1))));
    a2 = fmaf(v2.x, w0, fmaf(v2.y, w1, fmaf(v2.z, w2, fmaf(v2.w, w3, a2))));
    a3 = fmaf(v3.x, w0, fmaf(v3.y, w1, fmaf(v3.z, w2, fmaf(v3.w, w3, a3))));
  }
  for (int k = 0; k < F; k += 4) {
    float w0 = root[(k + 0) * HD + lane];
    float w1 = root[(k + 1) * HD + lane];
    float w2 = root[(k + 2) * HD + lane];
    float w3 = root[(k + 3) * HD + lane];
    float4 v0 = *(const float4*)&rowbase[0 * KT + 8 * F + k];
    float4 v1 = *(const float4*)&rowbase[1 * KT + 8 * F + k];
    float4 v2 = *(const float4*)&rowbase[2 * KT + 8 * F + k];
    float4 v3 = *(const float4*)&rowbase[3 * KT + 8 * F + k];
    a0 = fmaf(v0.x, w0, fmaf(v0.y, w1, fmaf(v0.z, w2, fmaf(v0.w, w3, a0))));
    a1 = fmaf(v1.x, w0, fmaf(v1.y, w1, fmaf(v1.z, w2, fmaf(v1.w, w3, a1))));
    a2 = fmaf(v2.x, w0, fmaf(v2.y, w1, fmaf(v2.z, w2, fmaf(v2.w, w3, a2))));
    a3 = fmaf(v3.x, w0, fmaf(v3.y, w1, fmaf(v3.z, w2, fmaf(v3.w, w3, a3))));
  }
  outp[(size_t)(nbase + 0) * HD + lane] = a0;
  outp[(size_t)(nbase + 1) * HD + lane] = a1;
  outp[(size_t)(nbase + 2) * HD + lane] = a2;
  outp[(size_t)(nbase + 3) * HD + lane] = a3;
}

// column sums / sumsq with per-block LDS reduce -> ~512 atomics/address
__global__ void k_bnstats(const float* __restrict__ x, float* __restrict__ stats) {
  __shared__ float sr[256], ssr[256];
  int lane = threadIdx.x & 63, grp = threadIdx.x >> 6;
  float s = 0.f, ss = 0.f;
  for (int i = blockIdx.x * 4 + grp; i < NN; i += gridDim.x * 4) {
    float v = x[(size_t)i * HD + lane];
    s += v;
    ss = fmaf(v, v, ss);
  }
  sr[threadIdx.x] = s;
  ssr[threadIdx.x] = ss;
  __syncthreads();
  if (grp == 0) {
    s = sr[lane] + sr[64 + lane] + sr[128 + lane] + sr[192 + lane];
    ss = ssr[lane] + ssr[64 + lane] + ssr[128 + lane] + ssr[192 + lane];
    atomicAdd(&stats[lane], s);
    atomicAdd(&stats[64 + lane], ss);
  }
}

__global__ void k_bnapply(const float* __restrict__ xin, const float* __restrict__ stats,
                          const float* __restrict__ g, const float* __restrict__ b,
                          float* __restrict__ xout) {
  int lane = threadIdx.x & 63;
  int i = blockIdx.x * 4 + (threadIdx.x >> 6);
  float mu = stats[lane] * (1.0f / NN);
  float var = stats[64 + lane] * (1.0f / NN) - mu * mu;
  float sc = g[lane] * rsqrtf(var + BN_EPS);
  float sh = b[lane] - mu * sc;
  float v = fmaf(xin[(size_t)i * HD + lane], sc, sh);
  xout[(size_t)i * HD + lane] = fmaxf(v, 0.0f);
}

// sorted-batch segmented pooling: register-accumulate per equal-graph run,
// atomics only at run boundaries. max via uint-punned atomicMax (post-ReLU >=0).
__global__ void k_poolseg(const float* __restrict__ x1, const float* __restrict__ x2,
                          const float* __restrict__ x3, const int* __restrict__ batch,
                          float* __restrict__ psum, unsigned* __restrict__ pmax,
                          float* __restrict__ cntg) {
  __shared__ int bsh[PCH];
  int base = blockIdx.x * PCH;
  int c = threadIdx.x;  // 0..191
  for (int i = c; i < PCH; i += 192) bsh[i] = batch[base + i];
  __syncthreads();
  const float* xs = (c < 64) ? x1 : (c < 128) ? x2 : x3;
  int cc = c & 63;
  int cur = bsh[0];
  float sum = 0.0f, mx = 0.0f;
  int runlen = 0;
  #pragma unroll 4
  for (int i = 0; i < PCH; i++) {
    int g = bsh[i];
    float v = xs[(size_t)(base + i) * 64 + cc];
    if (g != cur) {  // wave-uniform, rare
      atomicAdd(&psum[cur * 192 + c], sum);
      atomicMax(&pmax[cur * 192 + c], __float_as_uint(mx));
      if (c == 0) atomicAdd(&cntg[cur], (float)runlen);
      cur = g; sum = 0.0f; mx = 0.0f; runlen = 0;
    }
    sum += v;
    mx = fmaxf(mx, v);
    runlen++;
  }
  atomicAdd(&psum[cur * 192 + c], sum);
  atomicMax(&pmax[cur * 192 + c], __float_as_uint(mx));
  if (c == 0) atomicAdd(&cntg[cur], (float)runlen);
}

// fc1: x_graph[g] (built in LDS from pool buffers) @ fc1_w[384,128] + b
__global__ void k_fc1(const float* __restrict__ psum, const unsigned* __restrict__ pmax,
                      const float* __restrict__ cntg, const float* __restrict__ w,
                      const float* __restrict__ bias, float* __restrict__ h1) {
  __shared__ float a[384];
  int g = blockIdx.x;
  float ic = 1.0f / fmaxf(cntg[g], 1.0f);
  for (int c = threadIdx.x; c < 384; c += 128) {
    a[c] = (c < 192) ? psum[g * 192 + c] * ic : __uint_as_float(pmax[g * 192 + (c - 192)]);
  }
  __syncthreads();
  int j = threadIdx.x;
  float acc = bias[j];
  for (int k = 0; k < 384; k++) acc = fmaf(a[k], w[k * 128 + j], acc);
  h1[g * 128 + j] = acc;
}

__global__ void k_fcbn_stats(const float* __restrict__ h1, const float* __restrict__ g,
                             const float* __restrict__ b, float* __restrict__ scsh) {
  __shared__ float sr[512], ssr[512];
  int j = threadIdx.x & 127, q = threadIdx.x >> 7;
  float s = 0.f, ss = 0.f;
  for (int i = q * 64; i < q * 64 + 64; i++) {
    float v = h1[i * 128 + j];
    s += v;
    ss = fmaf(v, v, ss);
  }
  sr[threadIdx.x] = s;
  ssr[threadIdx.x] = ss;
  __syncthreads();
  if (q == 0) {
    s = sr[j] + sr[128 + j] + sr[256 + j] + sr[384 + j];
    ss = ssr[j] + ssr[128 + j] + ssr[256 + j] + ssr[384 + j];
    float mu = s * (1.0f / NG);
    float var = ss * (1.0f / NG) - mu * mu;
    float sc = g[j] * rsqrtf(var + BN_EPS);
    scsh[j] = sc;
    scsh[128 + j] = b[j] - mu * sc;
  }
}

__global__ void k_leaky(float* __restrict__ h1, const float* __restrict__ scsh) {
  int j = threadIdx.x;
  int g = blockIdx.x;
  float v = fmaf(h1[g * 128 + j], scsh[j], scsh[128 + j]);
  h1[g * 128 + j] = v > 0.0f ? v : 0.2f * v;
}

// emb = h1 @ fc2 + b (written to out); pred = leaky(emb@dec1+b1)@dec2 + b2
__global__ void k_head(const float* __restrict__ h1, const float* __restrict__ fc2w,
                       const float* __restrict__ fc2b, const float* __restrict__ d1w,
                       const float* __restrict__ d1b, const float* __restrict__ d2w,
                       const float* __restrict__ d2b, float* __restrict__ out) {
  __shared__ float emb[16];
  int g = blockIdx.x;
  int t = threadIdx.x;  // 0..63
  if (t < 16) {
    float acc = fc2b[t];
    for (int k = 0; k < 128; k++) acc = fmaf(h1[g * 128 + k], fc2w[k * 16 + t], acc);
    emb[t] = acc;
    out[NG + g * 16 + t] = acc;  // emb section after 256 preds
  }
  __syncthreads();
  float acc = d1b[t];
  for (int k = 0; k < 16; k++) acc = fmaf(emb[k], d1w[k * 64 + t], acc);
  acc = acc > 0.0f ? acc : 0.2f * acc;
  float p = acc * d2w[t];
  for (int off = 32; off > 0; off >>= 1) p += __shfl_down(p, off);
  if (t == 0) out[g] = p + d2b[0];
}

extern "C" void kernel_launch(void* const* d_in, const int* in_sizes, int n_in,
                              void* d_out, int out_size, void* d_ws, size_t ws_size,
                              hipStream_t stream) {
  const float* x    = (const float*)d_in[0];
  const int*   ei   = (const int*)d_in[1];
  const int*   ety  = (const int*)d_in[2];
  const int*   batch= (const int*)d_in[3];
  const float* c1w  = (const float*)d_in[4];
  const float* c1r  = (const float*)d_in[5];
  const float* c1b  = (const float*)d_in[6];
  const float* bn1g = (const float*)d_in[7];
  const float* bn1b = (const float*)d_in[8];
  const float* c2w  = (const float*)d_in[9];
  const float* c2r  = (const float*)d_in[10];
  const float* c2b  = (const float*)d_in[11];
  const float* bn2g = (const float*)d_in[12];
  const float* bn2b = (const float*)d_in[13];
  const float* c3w  = (const float*)d_in[14];
  const float* c3r  = (const float*)d_in[15];
  const float* c3b  = (const float*)d_in[16];
  const float* bn3g = (const float*)d_in[17];
  const float* bn3b = (const float*)d_in[18];
  const float* fc1w = (const float*)d_in[19];
  const float* fc1b = (const float*)d_in[20];
  const float* fbg  = (const float*)d_in[21];
  const float* fbb  = (const float*)d_in[22];
  const float* fc2w = (const float*)d_in[23];
  const float* fc2b = (const float*)d_in[24];
  const float* d1w  = (const float*)d_in[25];
  const float* d1b  = (const float*)d_in[26];
  const float* d2w  = (const float*)d_in[27];
  const float* d2b  = (const float*)d_in[28];
  const int* esrc = ei;
  const int* edst = ei + NE;
  float* out = (float*)d_out;

  float* W = (float*)d_ws;
  size_t o = 0;
  auto alloc = [&](size_t n) { float* p = W + o; o += (n + 63) & ~(size_t)63; return p; };
  unsigned* cnt  = (unsigned*)alloc(M_KEYS);
  float*    psum = alloc(NG * 192);
  unsigned* pmax = (unsigned*)alloc(NG * 192);
  float*    cntg = alloc(NG);
  size_t zone = o;  // buffers [0, zone) zeroed every call
  int*      rowstart = (int*)alloc(M_KEYS + 1);
  int*      rank = (int*)alloc(NE);
  int*      ebuf = (int*)alloc(NE);
  unsigned* bsum = (unsigned*)alloc(1024);
  unsigned* boff = (unsigned*)alloc(1024);
  float*    stats = alloc(128);
  float*    scsh = alloc(256);
  float*    h1   = alloc(NG * 128);
  float*    x1   = alloc((size_t)NN * HD);
  float*    x2   = alloc((size_t)NN * HD);
  float*    x3   = alloc((size_t)NN * HD);
  float*    tmp  = alloc((size_t)NN * HD);
  (void)ws_size; (void)in_sizes; (void)n_in; (void)out_size;

  // ---- preprocess: (dst,rel)-keyed CSR, counts give the mean denominators ----
  k_zero<<<(int)((zone + 255) / 256), 256, 0, stream>>>(W, (int)zone);
  k_cnt<<<(NE + 255) / 256, 256, 0, stream>>>(edst, ety, cnt, rank);
  k_scanA<<<NB, 256, 0, stream>>>(cnt, bsum);
  k_scanB<<<1, 1024, 0, stream>>>(bsum, boff, rowstart);
  k_scanC<<<NB, 256, 0, stream>>>(cnt, boff, rowstart);
  k_place<<<(NE + 255) / 256, 256, 0, stream>>>(esrc, edst, ety, rank, rowstart, ebuf);

  auto bnpass = [&](const float* g, const float* b, float* xout) {
    k_zero<<<1, 256, 0, stream>>>(stats, 128);
    k_bnstats<<<512, 256, 0, stream>>>(tmp, stats);
    k_bnapply<<<NN / 4, 256, 0, stream>>>(tmp, stats, g, b, xout);
  };

  k_layer<FIN><<<NN / 16, 256, 0, stream>>>(x, rowstart, ebuf, c1w, c1r, c1b, tmp);
  bnpass(bn1g, bn1b, x1);
  k_layer<HD><<<NN / 16, 256, 0, stream>>>(x1, rowstart, ebuf, c2w, c2r, c2b, tmp);
  bnpass(bn2g, bn2b, x2);
  k_layer<HD><<<NN / 16, 256, 0, stream>>>(x2, rowstart, ebuf, c3w, c3r, c3b, tmp);
  bnpass(bn3g, bn3b, x3);

  // pooling + head
  k_poolseg<<<NN / PCH, 192, 0, stream>>>(x1, x2, x3, batch, psum, pmax, cntg);
  k_fc1<<<NG, 128, 0, stream>>>(psum, pmax, cntg, fc1w, fc1b, h1);
  k_fcbn_stats<<<1, 512, 0, stream>>>(h1, fbg, fbb, scsh);
  k_leaky<<<NG, 128, 0, stream>>>(h1, scsh);
  k_head<<<NG, 64, 0, stream>>>(h1, fc2w, fc2b, d1w, d1b, d2w, d2b, out);
}

// Round 4
// 1282.307 us; speedup vs baseline: 1.7534x; 1.0509x over previous
//
#include <hip/hip_runtime.h>

#define NN 100000
#define NE 1250000
#define FIN 32
#define HD 64
#define NR 8
#define NG 256
#define BN_EPS 1e-5f
#define PCH 100          // nodes per pooling block (divides NN)
#define M_KEYS (NN * NR) // 800000 (dst,rel) segments
#define NB 782           // scan blocks: 782*1024 >= 800000
#define RREP 32          // BN-stat atomic replicas

__global__ void k_zero(float* __restrict__ p, int n) {
  int i = blockIdx.x * 256 + threadIdx.x;
  if (i < n) p[i] = 0.0f;
}

// pass 1: per-(dst,rel) counts + per-edge rank (stable position within segment)
__global__ void k_cnt(const int* __restrict__ dst, const int* __restrict__ ty,
                      unsigned* __restrict__ cnt, int* __restrict__ rank) {
  int e = blockIdx.x * 256 + threadIdx.x;
  if (e < NE) {
    int key = dst[e] * NR + ty[e];
    rank[e] = (int)atomicAdd(&cnt[key], 1u);
  }
}

// hierarchical exclusive scan of cnt[M_KEYS] -> rowstart[M_KEYS+1]
__global__ void k_scanA(const unsigned* __restrict__ cnt, unsigned* __restrict__ bsum) {
  __shared__ unsigned red[256];
  int t = threadIdx.x;
  int base = blockIdx.x * 1024 + t * 4;
  unsigned s = 0;
  #pragma unroll
  for (int i = 0; i < 4; i++) {
    int idx = base + i;
    if (idx < M_KEYS) s += cnt[idx];
  }
  red[t] = s;
  __syncthreads();
  for (int off = 128; off > 0; off >>= 1) {
    if (t < off) red[t] += red[t + off];
    __syncthreads();
  }
  if (t == 0) bsum[blockIdx.x] = red[0];
}

__global__ __launch_bounds__(1024) void k_scanB(const unsigned* __restrict__ bsum,
                                                unsigned* __restrict__ boff,
                                                int* __restrict__ rowstart) {
  __shared__ unsigned sb[1024];
  int t = threadIdx.x;
  unsigned mine = (t < NB) ? bsum[t] : 0u;
  sb[t] = mine;
  __syncthreads();
  for (int off = 1; off < 1024; off <<= 1) {
    unsigned v = (t >= off) ? sb[t - off] : 0u;
    __syncthreads();
    sb[t] += v;
    __syncthreads();
  }
  if (t < NB) boff[t] = sb[t] - mine;
  if (t == 1023) rowstart[M_KEYS] = (int)sb[1023];
}

__global__ void k_scanC(const unsigned* __restrict__ cnt, const unsigned* __restrict__ boff,
                        int* __restrict__ rowstart) {
  __shared__ unsigned sb[256];
  int t = threadIdx.x;
  int base = blockIdx.x * 1024 + t * 4;
  unsigned c0 = (base + 0 < M_KEYS) ? cnt[base + 0] : 0u;
  unsigned c1 = (base + 1 < M_KEYS) ? cnt[base + 1] : 0u;
  unsigned c2 = (base + 2 < M_KEYS) ? cnt[base + 2] : 0u;
  unsigned c3 = (base + 3 < M_KEYS) ? cnt[base + 3] : 0u;
  unsigned tot = c0 + c1 + c2 + c3;
  sb[t] = tot;
  __syncthreads();
  for (int off = 1; off < 256; off <<= 1) {
    unsigned v = (t >= off) ? sb[t - off] : 0u;
    __syncthreads();
    sb[t] += v;
    __syncthreads();
  }
  unsigned run = boff[blockIdx.x] + (sb[t] - tot);
  if (base + 0 < M_KEYS) rowstart[base + 0] = (int)run; run += c0;
  if (base + 1 < M_KEYS) rowstart[base + 1] = (int)run; run += c1;
  if (base + 2 < M_KEYS) rowstart[base + 2] = (int)run; run += c2;
  if (base + 3 < M_KEYS) rowstart[base + 3] = (int)run;
}

// pass 2: place (src | rel<<20) into (dst,rel)-CSR
__global__ void k_place(const int* __restrict__ src, const int* __restrict__ dst,
                        const int* __restrict__ ty, const int* __restrict__ rank,
                        const int* __restrict__ rowstart, int* __restrict__ ebuf) {
  int e = blockIdx.x * 256 + threadIdx.x;
  if (e < NE) {
    int t = ty[e];
    int key = dst[e] * NR + t;
    ebuf[rowstart[key] + rank[e]] = src[e] | (t << 20);
  }
}

// Fused RGCN layer. Per wave: 4 dst nodes.
// Phase A: flat 8-deep-pipelined gather over all edges of the 4 nodes
//   (rel packed in ebuf; LDS read-add-write into (node,rel) slot; post-scale
//   by 1/cnt). Optional inline BN+ReLU on gathered rows (prev layer's BN).
// Phase B: out = bias + [agg_0..agg_7 | self] @ [W_0..W_7 | root], K=9F
//   register GEMM, W L1/L2-hot. Epilogue: BN column stats via LDS reduce +
//   replica atomics. No global atomics on the feature data, no syncthreads
//   until the epilogue.
template <int F, bool APPLY_BN>
__global__ __launch_bounds__(256) void k_layer(
    const float* __restrict__ xin, const float* __restrict__ scsh_in,
    const int* __restrict__ rs, const int* __restrict__ ebuf,
    const float* __restrict__ convw, const float* __restrict__ root,
    const float* __restrict__ bias, float* __restrict__ outp,
    float* __restrict__ statsrep) {
  constexpr int KT = 9 * F;
  __shared__ float agg[16 * KT];
  int lane = threadIdx.x & 63;
  int w = threadIdx.x >> 6;
  int w4 = w * 4;
  int nbase = blockIdx.x * 16 + w4;

  float scr = 0.f, shr = 0.f;
  if (APPLY_BN) { scr = scsh_in[lane]; shr = scsh_in[64 + lane]; }

  // ---- phase A ----
  if (lane < F) {
    #pragma unroll
    for (int j = 0; j < 4; j++)
      #pragma unroll
      for (int r = 0; r < NR; r++)
        agg[(w4 + j) * KT + r * F + lane] = 0.f;
  }
  int nb8 = nbase * NR;
  int lo = rs[nb8];
  int b1 = rs[nb8 + 8], b2 = rs[nb8 + 16], b3 = rs[nb8 + 24];
  int hi = rs[nb8 + 32];
  for (int e = lo; e < hi; e += 8) {
    int m = hi - e;  // wave-uniform
    int pk[8]; float vv[8];
    #pragma unroll
    for (int u = 0; u < 8; u++) pk[u] = (u < m) ? ebuf[e + u] : 0;
    #pragma unroll
    for (int u = 0; u < 8; u++)
      vv[u] = (u < m && lane < F) ? xin[(size_t)(pk[u] & 0xFFFFF) * F + lane] : 0.f;
    if (APPLY_BN) {
      #pragma unroll
      for (int u = 0; u < 8; u++) vv[u] = fmaxf(fmaf(vv[u], scr, shr), 0.f);
    }
    #pragma unroll
    for (int u = 0; u < 8; u++) {
      if (u < m) {  // wave-uniform
        int ee = e + u;
        int ln = (ee >= b1) + (ee >= b2) + (ee >= b3);
        int rel = pk[u] >> 20;
        if (lane < F) agg[(w4 + ln) * KT + rel * F + lane] += vv[u];
      }
    }
  }
  // self slot + mean scaling
  if (lane < F) {
    #pragma unroll
    for (int j = 0; j < 4; j++) {
      float sv = xin[(size_t)(nbase + j) * F + lane];
      if (APPLY_BN) sv = fmaxf(fmaf(sv, scr, shr), 0.f);
      agg[(w4 + j) * KT + 8 * F + lane] = sv;
    }
  }
  for (int j = 0; j < 4; j++) {
    int n8 = (nbase + j) * NR;
    #pragma unroll
    for (int r = 0; r < NR; r++) {
      int c = rs[n8 + r + 1] - rs[n8 + r];
      if (c > 1 && lane < F)
        agg[(w4 + j) * KT + r * F + lane] *= (1.0f / (float)c);
    }
  }
  // no sync: phase B reads only this wave's own rows

  // ---- phase B ----
  float b = bias[lane];
  float a0 = b, a1 = b, a2 = b, a3 = b;
  const float* rowbase = &agg[w4 * KT];
  for (int k = 0; k < 8 * F; k += 4) {
    float w0 = convw[(k + 0) * HD + lane];
    float w1 = convw[(k + 1) * HD + lane];
    float w2 = convw[(k + 2) * HD + lane];
    float w3 = convw[(k + 3) * HD + lane];
    float4 v0 = *(const float4*)&rowbase[0 * KT + k];
    float4 v1 = *(const float4*)&rowbase[1 * KT + k];
    float4 v2 = *(const float4*)&rowbase[2 * KT + k];
    float4 v3 = *(const float4*)&rowbase[3 * KT + k];
    a0 = fmaf(v0.x, w0, fmaf(v0.y, w1, fmaf(v0.z, w2, fmaf(v0.w, w3, a0))));
    a1 = fmaf(v1.x, w0, fmaf(v1.y, w1, fmaf(v1.z, w2, fmaf(v1.w, w3, a1))));
    a2 = fmaf(v2.x, w0, fmaf(v2.y, w1, fmaf(v2.z, w2, fmaf(v2.w, w3, a2))));
    a3 = fmaf(v3.x, w0, fmaf(v3.y, w1, fmaf(v3.z, w2, fmaf(v3.w, w3, a3))));
  }
  for (int k = 0; k < F; k += 4) {
    float w0 = root[(k + 0) * HD + lane];
    float w1 = root[(k + 1) * HD + lane];
    float w2 = root[(k + 2) * HD + lane];
    float w3 = root[(k + 3) * HD + lane];
    float4 v0 = *(const float4*)&rowbase[0 * KT + 8 * F + k];
    float4 v1 = *(const float4*)&rowbase[1 * KT + 8 * F + k];
    float4 v2 = *(const float4*)&rowbase[2 * KT + 8 * F + k];
    float4 v3 = *(const float4*)&rowbase[3 * KT + 8 * F + k];
    a0 = fmaf(v0.x, w0, fmaf(v0.y, w1, fmaf(v0.z, w2, fmaf(v0.w, w3, a0))));
    a1 = fmaf(v1.x, w0, fmaf(v1.y, w1, fmaf(v1.z, w2, fmaf(v1.w, w3, a1))));
    a2 = fmaf(v2.x, w0, fmaf(v2.y, w1, fmaf(v2.z, w2, fmaf(v2.w, w3, a2))));
    a3 = fmaf(v3.x, w0, fmaf(v3.y, w1, fmaf(v3.z, w2, fmaf(v3.w, w3, a3))));
  }
  outp[(size_t)(nbase + 0) * HD + lane] = a0;
  outp[(size_t)(nbase + 1) * HD + lane] = a1;
  outp[(size_t)(nbase + 2) * HD + lane] = a2;
  outp[(size_t)(nbase + 3) * HD + lane] = a3;

  // ---- epilogue: BN column stats (sum, sumsq) ----
  float s = a0 + a1 + a2 + a3;
  float ss = a0 * a0 + a1 * a1 + a2 * a2 + a3 * a3;
  __syncthreads();  // agg no longer needed by any wave
  float* red = agg;
  red[w * 128 + lane] = s;
  red[w * 128 + 64 + lane] = ss;
  __syncthreads();
  if (w == 0) {
    float ts = red[lane] + red[128 + lane] + red[256 + lane] + red[384 + lane];
    float tss = red[64 + lane] + red[192 + lane] + red[320 + lane] + red[448 + lane];
    int rp = blockIdx.x & (RREP - 1);
    atomicAdd(&statsrep[rp * 128 + lane], ts);
    atomicAdd(&statsrep[rp * 128 + 64 + lane], tss);
  }
}

// reduce stat replicas -> BN (scale, shift)
__global__ void k_finstats(const float* __restrict__ rep, const float* __restrict__ g,
                           const float* __restrict__ b, float* __restrict__ scsh) {
  int lane = threadIdx.x;  // 64
  float s = 0.f, ss = 0.f;
  for (int rp = 0; rp < RREP; rp++) {
    s += rep[rp * 128 + lane];
    ss += rep[rp * 128 + 64 + lane];
  }
  float mu = s * (1.0f / NN);
  float var = ss * (1.0f / NN) - mu * mu;
  float sc = g[lane] * rsqrtf(var + BN_EPS);
  scsh[lane] = sc;
  scsh[64 + lane] = b[lane] - mu * sc;
}

// sorted-batch segmented pooling over RAW layer outputs with inline BN+ReLU.
// register-accumulate per equal-graph run, atomics only at run boundaries.
// max via uint-punned atomicMax (post-ReLU >= 0).
__global__ void k_poolseg(const float* __restrict__ t1, const float* __restrict__ t2,
                          const float* __restrict__ t3, const float* __restrict__ scsh,
                          const int* __restrict__ batch, float* __restrict__ psum,
                          unsigned* __restrict__ pmax, float* __restrict__ cntg) {
  __shared__ int bsh[PCH];
  int base = blockIdx.x * PCH;
  int c = threadIdx.x;  // 0..191
  for (int i = c; i < PCH; i += 192) bsh[i] = batch[base + i];
  __syncthreads();
  int L = c >> 6, cc = c & 63;
  const float* xs = (L == 0) ? t1 : (L == 1) ? t2 : t3;
  float sc = scsh[L * 128 + cc], sh = scsh[L * 128 + 64 + cc];
  int cur = bsh[0];
  float sum = 0.0f, mx = 0.0f;
  int runlen = 0;
  #pragma unroll 4
  for (int i = 0; i < PCH; i++) {
    int g = bsh[i];
    float v = fmaxf(fmaf(xs[(size_t)(base + i) * 64 + cc], sc, sh), 0.0f);
    if (g != cur) {  // wave-uniform, rare
      atomicAdd(&psum[cur * 192 + c], sum);
      atomicMax(&pmax[cur * 192 + c], __float_as_uint(mx));
      if (c == 0) atomicAdd(&cntg[cur], (float)runlen);
      cur = g; sum = 0.0f; mx = 0.0f; runlen = 0;
    }
    sum += v;
    mx = fmaxf(mx, v);
    runlen++;
  }
  atomicAdd(&psum[cur * 192 + c], sum);
  atomicMax(&pmax[cur * 192 + c], __float_as_uint(mx));
  if (c == 0) atomicAdd(&cntg[cur], (float)runlen);
}

// fc1: x_graph[g] (built in LDS from pool buffers) @ fc1_w[384,128] + b
__global__ void k_fc1(const float* __restrict__ psum, const unsigned* __restrict__ pmax,
                      const float* __restrict__ cntg, const float* __restrict__ w,
                      const float* __restrict__ bias, float* __restrict__ h1) {
  __shared__ float a[384];
  int g = blockIdx.x;
  float ic = 1.0f / fmaxf(cntg[g], 1.0f);
  for (int c = threadIdx.x; c < 384; c += 128) {
    a[c] = (c < 192) ? psum[g * 192 + c] * ic : __uint_as_float(pmax[g * 192 + (c - 192)]);
  }
  __syncthreads();
  int j = threadIdx.x;
  float acc = bias[j];
  for (int k = 0; k < 384; k++) acc = fmaf(a[k], w[k * 128 + j], acc);
  h1[g * 128 + j] = acc;
}

__global__ void k_fcbn_stats(const float* __restrict__ h1, const float* __restrict__ g,
                             const float* __restrict__ b, float* __restrict__ scsh) {
  __shared__ float sr[512], ssr[512];
  int j = threadIdx.x & 127, q = threadIdx.x >> 7;
  float s = 0.f, ss = 0.f;
  for (int i = q * 64; i < q * 64 + 64; i++) {
    float v = h1[i * 128 + j];
    s += v;
    ss = fmaf(v, v, ss);
  }
  sr[threadIdx.x] = s;
  ssr[threadIdx.x] = ss;
  __syncthreads();
  if (q == 0) {
    s = sr[j] + sr[128 + j] + sr[256 + j] + sr[384 + j];
    ss = ssr[j] + ssr[128 + j] + ssr[256 + j] + ssr[384 + j];
    float mu = s * (1.0f / NG);
    float var = ss * (1.0f / NG) - mu * mu;
    float sc = g[j] * rsqrtf(var + BN_EPS);
    scsh[j] = sc;
    scsh[128 + j] = b[j] - mu * sc;
  }
}

__global__ void k_leaky(float* __restrict__ h1, const float* __restrict__ scsh) {
  int j = threadIdx.x;
  int g = blockIdx.x;
  float v = fmaf(h1[g * 128 + j], scsh[j], scsh[128 + j]);
  h1[g * 128 + j] = v > 0.0f ? v : 0.2f * v;
}

// emb = h1 @ fc2 + b (written to out); pred = leaky(emb@dec1+b1)@dec2 + b2
__global__ void k_head(const float* __restrict__ h1, const float* __restrict__ fc2w,
                       const float* __restrict__ fc2b, const float* __restrict__ d1w,
                       const float* __restrict__ d1b, const float* __restrict__ d2w,
                       const float* __restrict__ d2b, float* __restrict__ out) {
  __shared__ float emb[16];
  int g = blockIdx.x;
  int t = threadIdx.x;  // 0..63
  if (t < 16) {
    float acc = fc2b[t];
    for (int k = 0; k < 128; k++) acc = fmaf(h1[g * 128 + k], fc2w[k * 16 + t], acc);
    emb[t] = acc;
    out[NG + g * 16 + t] = acc;  // emb section after 256 preds
  }
  __syncthreads();
  float acc = d1b[t];
  for (int k = 0; k < 16; k++) acc = fmaf(emb[k], d1w[k * 64 + t], acc);
  acc = acc > 0.0f ? acc : 0.2f * acc;
  float p = acc * d2w[t];
  for (int off = 32; off > 0; off >>= 1) p += __shfl_down(p, off);
  if (t == 0) out[g] = p + d2b[0];
}

extern "C" void kernel_launch(void* const* d_in, const int* in_sizes, int n_in,
                              void* d_out, int out_size, void* d_ws, size_t ws_size,
                              hipStream_t stream) {
  const float* x    = (const float*)d_in[0];
  const int*   ei   = (const int*)d_in[1];
  const int*   ety  = (const int*)d_in[2];
  const int*   batch= (const int*)d_in[3];
  const float* c1w  = (const float*)d_in[4];
  const float* c1r  = (const float*)d_in[5];
  const float* c1b  = (const float*)d_in[6];
  const float* bn1g = (const float*)d_in[7];
  const float* bn1b = (const float*)d_in[8];
  const float* c2w  = (const float*)d_in[9];
  const float* c2r  = (const float*)d_in[10];
  const float* c2b  = (const float*)d_in[11];
  const float* bn2g = (const float*)d_in[12];
  const float* bn2b = (const float*)d_in[13];
  const float* c3w  = (const float*)d_in[14];
  const float* c3r  = (const float*)d_in[15];
  const float* c3b  = (const float*)d_in[16];
  const float* bn3g = (const float*)d_in[17];
  const float* bn3b = (const float*)d_in[18];
  const float* fc1w = (const float*)d_in[19];
  const float* fc1b = (const float*)d_in[20];
  const float* fbg  = (const float*)d_in[21];
  const float* fbb  = (const float*)d_in[22];
  const float* fc2w = (const float*)d_in[23];
  const float* fc2b = (const float*)d_in[24];
  const float* d1w  = (const float*)d_in[25];
  const float* d1b  = (const float*)d_in[26];
  const float* d2w  = (const float*)d_in[27];
  const float* d2b  = (const float*)d_in[28];
  const int* esrc = ei;
  const int* edst = ei + NE;
  float* out = (float*)d_out;

  float* W = (float*)d_ws;
  size_t o = 0;
  auto alloc = [&](size_t n) { float* p = W + o; o += (n + 63) & ~(size_t)63; return p; };
  unsigned* cnt      = (unsigned*)alloc(M_KEYS);
  float*    psum     = alloc(NG * 192);
  unsigned* pmax     = (unsigned*)alloc(NG * 192);
  float*    cntg     = alloc(NG);
  float*    statsrep = alloc(3 * RREP * 128);
  size_t zone = o;  // buffers [0, zone) zeroed every call
  int*      rowstart = (int*)alloc(M_KEYS + 1);
  int*      rank = (int*)alloc(NE);
  int*      ebuf = (int*)alloc(NE);
  unsigned* bsum = (unsigned*)alloc(1024);
  unsigned* boff = (unsigned*)alloc(1024);
  float*    scsh = alloc(3 * 128);   // per-layer BN (scale, shift)
  float*    fcsc = alloc(256);       // fc BN (scale, shift)
  float*    h1   = alloc(NG * 128);
  float*    tmp1 = alloc((size_t)NN * HD);
  float*    tmp2 = alloc((size_t)NN * HD);
  float*    tmp3 = alloc((size_t)NN * HD);
  (void)ws_size; (void)in_sizes; (void)n_in; (void)out_size;

  // ---- preprocess: (dst,rel)-keyed CSR with rel packed into entries ----
  k_zero<<<(int)((zone + 255) / 256), 256, 0, stream>>>(W, (int)zone);
  k_cnt<<<(NE + 255) / 256, 256, 0, stream>>>(edst, ety, cnt, rank);
  k_scanA<<<NB, 256, 0, stream>>>(cnt, bsum);
  k_scanB<<<1, 1024, 0, stream>>>(bsum, boff, rowstart);
  k_scanC<<<NB, 256, 0, stream>>>(cnt, boff, rowstart);
  k_place<<<(NE + 255) / 256, 256, 0, stream>>>(esrc, edst, ety, rank, rowstart, ebuf);

  // ---- fused layers (BN applied on input side of next consumer) ----
  k_layer<FIN, false><<<NN / 16, 256, 0, stream>>>(
      x, nullptr, rowstart, ebuf, c1w, c1r, c1b, tmp1, statsrep);
  k_finstats<<<1, 64, 0, stream>>>(statsrep, bn1g, bn1b, scsh);
  k_layer<HD, true><<<NN / 16, 256, 0, stream>>>(
      tmp1, scsh, rowstart, ebuf, c2w, c2r, c2b, tmp2, statsrep + RREP * 128);
  k_finstats<<<1, 64, 0, stream>>>(statsrep + RREP * 128, bn2g, bn2b, scsh + 128);
  k_layer<HD, true><<<NN / 16, 256, 0, stream>>>(
      tmp2, scsh + 128, rowstart, ebuf, c3w, c3r, c3b, tmp3, statsrep + 2 * RREP * 128);
  k_finstats<<<1, 64, 0, stream>>>(statsrep + 2 * RREP * 128, bn3g, bn3b, scsh + 256);

  // ---- pooling + head ----
  k_poolseg<<<NN / PCH, 192, 0, stream>>>(tmp1, tmp2, tmp3, scsh, batch, psum, pmax, cntg);
  k_fc1<<<NG, 128, 0, stream>>>(psum, pmax, cntg, fc1w, fc1b, h1);
  k_fcbn_stats<<<1, 512, 0, stream>>>(h1, fbg, fbb, fcsc);
  k_leaky<<<NG, 128, 0, stream>>>(h1, fcsc);
  k_head<<<NG, 64, 0, stream>>>(h1, fc2w, fc2b, d1w, d1b, d2w, d2b, out);
}

// Round 5
// 992.163 us; speedup vs baseline: 2.2662x; 1.2924x over previous
//
#include <hip/hip_runtime.h>

#define NN 100000
#define NE 1250000
#define FIN 32
#define HD 64
#define NR 8
#define NG 256
#define BN_EPS 1e-5f
#define PCH 100          // nodes per pooling block (divides NN)
#define M_KEYS (NN * NR) // 800000 (dst,rel) segments
#define NB 782           // scan blocks: 782*1024 >= 800000
#define RREP 32          // BN-stat atomic replicas
#define HW 576           // h width: 8 rel * 64 + root 64

typedef unsigned short ushort_t;

static __device__ __forceinline__ ushort_t f2bf(float f) {
  unsigned u = __float_as_uint(f);
  u += 0x7fffu + ((u >> 16) & 1u);  // RNE
  return (ushort_t)(u >> 16);
}
static __device__ __forceinline__ float bf2f(ushort_t b) {
  return __uint_as_float((unsigned)b << 16);
}

__global__ void k_zero(float* __restrict__ p, int n) {
  int i = blockIdx.x * 256 + threadIdx.x;
  if (i < n) p[i] = 0.0f;
}

// pass 1: per-(dst,rel) counts + per-edge rank
__global__ void k_cnt(const int* __restrict__ dst, const int* __restrict__ ty,
                      unsigned* __restrict__ cnt, int* __restrict__ rank) {
  int e = blockIdx.x * 256 + threadIdx.x;
  if (e < NE) {
    int key = dst[e] * NR + ty[e];
    rank[e] = (int)atomicAdd(&cnt[key], 1u);
  }
}

__global__ void k_invcnt(const unsigned* __restrict__ cnt, float* __restrict__ ic) {
  int i = blockIdx.x * 256 + threadIdx.x;
  if (i < M_KEYS) ic[i] = 1.0f / (float)max(cnt[i], 1u);
}

// hierarchical exclusive scan of cnt[M_KEYS] -> rowstart[M_KEYS+1]
__global__ void k_scanA(const unsigned* __restrict__ cnt, unsigned* __restrict__ bsum) {
  __shared__ unsigned red[256];
  int t = threadIdx.x;
  int base = blockIdx.x * 1024 + t * 4;
  unsigned s = 0;
  #pragma unroll
  for (int i = 0; i < 4; i++) {
    int idx = base + i;
    if (idx < M_KEYS) s += cnt[idx];
  }
  red[t] = s;
  __syncthreads();
  for (int off = 128; off > 0; off >>= 1) {
    if (t < off) red[t] += red[t + off];
    __syncthreads();
  }
  if (t == 0) bsum[blockIdx.x] = red[0];
}

__global__ __launch_bounds__(1024) void k_scanB(const unsigned* __restrict__ bsum,
                                                unsigned* __restrict__ boff,
                                                int* __restrict__ rowstart) {
  __shared__ unsigned sb[1024];
  int t = threadIdx.x;
  unsigned mine = (t < NB) ? bsum[t] : 0u;
  sb[t] = mine;
  __syncthreads();
  for (int off = 1; off < 1024; off <<= 1) {
    unsigned v = (t >= off) ? sb[t - off] : 0u;
    __syncthreads();
    sb[t] += v;
    __syncthreads();
  }
  if (t < NB) boff[t] = sb[t] - mine;
  if (t == 1023) rowstart[M_KEYS] = (int)sb[1023];
}

__global__ void k_scanC(const unsigned* __restrict__ cnt, const unsigned* __restrict__ boff,
                        int* __restrict__ rowstart) {
  __shared__ unsigned sb[256];
  int t = threadIdx.x;
  int base = blockIdx.x * 1024 + t * 4;
  unsigned c0 = (base + 0 < M_KEYS) ? cnt[base + 0] : 0u;
  unsigned c1 = (base + 1 < M_KEYS) ? cnt[base + 1] : 0u;
  unsigned c2 = (base + 2 < M_KEYS) ? cnt[base + 2] : 0u;
  unsigned c3 = (base + 3 < M_KEYS) ? cnt[base + 3] : 0u;
  unsigned tot = c0 + c1 + c2 + c3;
  sb[t] = tot;
  __syncthreads();
  for (int off = 1; off < 256; off <<= 1) {
    unsigned v = (t >= off) ? sb[t - off] : 0u;
    __syncthreads();
    sb[t] += v;
    __syncthreads();
  }
  unsigned run = boff[blockIdx.x] + (sb[t] - tot);
  if (base + 0 < M_KEYS) rowstart[base + 0] = (int)run; run += c0;
  if (base + 1 < M_KEYS) rowstart[base + 1] = (int)run; run += c1;
  if (base + 2 < M_KEYS) rowstart[base + 2] = (int)run; run += c2;
  if (base + 3 < M_KEYS) rowstart[base + 3] = (int)run;
}

// pass 2: place (src | rel<<20) into (dst,rel)-CSR
__global__ void k_place(const int* __restrict__ src, const int* __restrict__ dst,
                        const int* __restrict__ ty, const int* __restrict__ rank,
                        const int* __restrict__ rowstart, int* __restrict__ ebuf) {
  int e = blockIdx.x * 256 + threadIdx.x;
  if (e < NE) {
    int t = ty[e];
    int key = dst[e] * NR + t;
    ebuf[rowstart[key] + rank[e]] = src[e] | (t << 20);
  }
}

// ---------------- transform-first path ----------------
// h[n, r*64+hc] = BNReLU(x[n]) @ W_r ; h[n, 512+hc] = BNReLU(x[n]) @ root.
// thread = output col c (576/block); W column register-resident (wreg[F]);
// x rows staged in LDS with BN+ReLU applied, broadcast-read during compute.
template <int F, bool APPLY_BN>
__global__ __launch_bounds__(576) void k_xform(
    const float* __restrict__ xin, const float* __restrict__ scsh_in,
    const float* __restrict__ convw, const float* __restrict__ root,
    ushort_t* __restrict__ h) {
  __shared__ float xs[16][F];
  int c = threadIdx.x;      // 0..575
  int r = c >> 6;           // 0..8
  int hc = c & 63;
  const float* wp = (r < 8) ? (convw + (size_t)r * F * HD + hc) : (root + hc);
  float wreg[F];
  #pragma unroll
  for (int k = 0; k < F; k++) wreg[k] = wp[(size_t)k * HD];

  int row0 = blockIdx.x * 32;
  #pragma unroll 1
  for (int chunk = 0; chunk < 2; chunk++) {
    int base = row0 + chunk * 16;
    __syncthreads();
    for (int i = c; i < 16 * F; i += 576) {
      int rr = i / F, kk = i % F;
      float v = xin[(size_t)(base + rr) * F + kk];
      if (APPLY_BN) v = fmaxf(fmaf(v, scsh_in[kk], scsh_in[64 + kk]), 0.0f);
      xs[rr][kk] = v;
    }
    __syncthreads();
    #pragma unroll 1
    for (int j = 0; j < 16; j += 4) {
      float a0 = 0.f, a1 = 0.f, a2 = 0.f, a3 = 0.f;
      #pragma unroll
      for (int k = 0; k < F; k += 4) {
        float4 v0 = *(const float4*)&xs[j + 0][k];
        float4 v1 = *(const float4*)&xs[j + 1][k];
        float4 v2 = *(const float4*)&xs[j + 2][k];
        float4 v3 = *(const float4*)&xs[j + 3][k];
        a0 = fmaf(v0.x, wreg[k], fmaf(v0.y, wreg[k+1], fmaf(v0.z, wreg[k+2], fmaf(v0.w, wreg[k+3], a0))));
        a1 = fmaf(v1.x, wreg[k], fmaf(v1.y, wreg[k+1], fmaf(v1.z, wreg[k+2], fmaf(v1.w, wreg[k+3], a1))));
        a2 = fmaf(v2.x, wreg[k], fmaf(v2.y, wreg[k+1], fmaf(v2.z, wreg[k+2], fmaf(v2.w, wreg[k+3], a2))));
        a3 = fmaf(v3.x, wreg[k], fmaf(v3.y, wreg[k+1], fmaf(v3.z, wreg[k+2], fmaf(v3.w, wreg[k+3], a3))));
      }
      h[(size_t)(base + j + 0) * HW + c] = f2bf(a0);
      h[(size_t)(base + j + 1) * HW + c] = f2bf(a1);
      h[(size_t)(base + j + 2) * HW + c] = f2bf(a2);
      h[(size_t)(base + j + 3) * HW + c] = f2bf(a3);
    }
  }
}

// out[n] = bias + h[n,512:576] + sum_edges h[src, rel*64:..] * invcnt[n,rel].
// wave = 1 node, lane = channel; single register accumulator, 8 loads in flight.
// Epilogue: BN column stats via LDS reduce + replica atomics.
__global__ __launch_bounds__(256) void k_agg(
    const ushort_t* __restrict__ h, const int* __restrict__ rs,
    const int* __restrict__ ebuf, const float* __restrict__ invcnt,
    const float* __restrict__ bias, float* __restrict__ outp,
    float* __restrict__ statsrep) {
  __shared__ float red[512];
  int lane = threadIdx.x & 63, w = threadIdx.x >> 6;
  int n = blockIdx.x * 4 + w;
  int lo = rs[n * NR], hi = rs[n * NR + NR];
  float acc = bias[lane] + bf2f(h[(size_t)n * HW + 512 + lane]);
  for (int e = lo; e < hi; e += 8) {
    int m = hi - e;  // wave-uniform
    int pk[8]; float hv[8], ic[8];
    #pragma unroll
    for (int u = 0; u < 8; u++) pk[u] = (u < m) ? ebuf[e + u] : 0;
    #pragma unroll
    for (int u = 0; u < 8; u++)
      hv[u] = (u < m) ? bf2f(h[(size_t)(pk[u] & 0xFFFFF) * HW + ((pk[u] >> 20) << 6) + lane]) : 0.f;
    #pragma unroll
    for (int u = 0; u < 8; u++)
      ic[u] = (u < m) ? invcnt[n * NR + (pk[u] >> 20)] : 0.f;
    #pragma unroll
    for (int u = 0; u < 8; u++) acc = fmaf(hv[u], ic[u], acc);
  }
  outp[(size_t)n * HD + lane] = acc;
  red[w * 128 + lane] = acc;
  red[w * 128 + 64 + lane] = acc * acc;
  __syncthreads();
  if (w == 0) {
    float ts = red[lane] + red[128 + lane] + red[256 + lane] + red[384 + lane];
    float tss = red[64 + lane] + red[192 + lane] + red[320 + lane] + red[448 + lane];
    int rp = blockIdx.x & (RREP - 1);
    atomicAdd(&statsrep[rp * 128 + lane], ts);
    atomicAdd(&statsrep[rp * 128 + 64 + lane], tss);
  }
}

// ---------------- fallback fused layer (round-4) ----------------
template <int F, bool APPLY_BN>
__global__ __launch_bounds__(256) void k_layer(
    const float* __restrict__ xin, const float* __restrict__ scsh_in,
    const int* __restrict__ rs, const int* __restrict__ ebuf,
    const float* __restrict__ convw, const float* __restrict__ root,
    const float* __restrict__ bias, float* __restrict__ outp,
    float* __restrict__ statsrep) {
  constexpr int KT = 9 * F;
  __shared__ float agg[16 * KT];
  int lane = threadIdx.x & 63;
  int w = threadIdx.x >> 6;
  int w4 = w * 4;
  int nbase = blockIdx.x * 16 + w4;
  float scr = 0.f, shr = 0.f;
  if (APPLY_BN) { scr = scsh_in[lane]; shr = scsh_in[64 + lane]; }
  if (lane < F) {
    #pragma unroll
    for (int j = 0; j < 4; j++)
      #pragma unroll
      for (int r = 0; r < NR; r++)
        agg[(w4 + j) * KT + r * F + lane] = 0.f;
  }
  int nb8 = nbase * NR;
  int lo = rs[nb8];
  int b1 = rs[nb8 + 8], b2 = rs[nb8 + 16], b3 = rs[nb8 + 24];
  int hi = rs[nb8 + 32];
  for (int e = lo; e < hi; e += 8) {
    int m = hi - e;
    int pk[8]; float vv[8];
    #pragma unroll
    for (int u = 0; u < 8; u++) pk[u] = (u < m) ? ebuf[e + u] : 0;
    #pragma unroll
    for (int u = 0; u < 8; u++)
      vv[u] = (u < m && lane < F) ? xin[(size_t)(pk[u] & 0xFFFFF) * F + lane] : 0.f;
    if (APPLY_BN) {
      #pragma unroll
      for (int u = 0; u < 8; u++) vv[u] = fmaxf(fmaf(vv[u], scr, shr), 0.f);
    }
    #pragma unroll
    for (int u = 0; u < 8; u++) {
      if (u < m) {
        int ee = e + u;
        int ln = (ee >= b1) + (ee >= b2) + (ee >= b3);
        int rel = pk[u] >> 20;
        if (lane < F) agg[(w4 + ln) * KT + rel * F + lane] += vv[u];
      }
    }
  }
  if (lane < F) {
    #pragma unroll
    for (int j = 0; j < 4; j++) {
      float sv = xin[(size_t)(nbase + j) * F + lane];
      if (APPLY_BN) sv = fmaxf(fmaf(sv, scr, shr), 0.f);
      agg[(w4 + j) * KT + 8 * F + lane] = sv;
    }
  }
  for (int j = 0; j < 4; j++) {
    int n8 = (nbase + j) * NR;
    #pragma unroll
    for (int r = 0; r < NR; r++) {
      int c = rs[n8 + r + 1] - rs[n8 + r];
      if (c > 1 && lane < F)
        agg[(w4 + j) * KT + r * F + lane] *= (1.0f / (float)c);
    }
  }
  float b = bias[lane];
  float a0 = b, a1 = b, a2 = b, a3 = b;
  const float* rowbase = &agg[w4 * KT];
  for (int k = 0; k < 8 * F; k += 4) {
    float w0 = convw[(k + 0) * HD + lane];
    float w1 = convw[(k + 1) * HD + lane];
    float w2 = convw[(k + 2) * HD + lane];
    float w3 = convw[(k + 3) * HD + lane];
    float4 v0 = *(const float4*)&rowbase[0 * KT + k];
    float4 v1 = *(const float4*)&rowbase[1 * KT + k];
    float4 v2 = *(const float4*)&rowbase[2 * KT + k];
    float4 v3 = *(const float4*)&rowbase[3 * KT + k];
    a0 = fmaf(v0.x, w0, fmaf(v0.y, w1, fmaf(v0.z, w2, fmaf(v0.w, w3, a0))));
    a1 = fmaf(v1.x, w0, fmaf(v1.y, w1, fmaf(v1.z, w2, fmaf(v1.w, w3, a1))));
    a2 = fmaf(v2.x, w0, fmaf(v2.y, w1, fmaf(v2.z, w2, fmaf(v2.w, w3, a2))));
    a3 = fmaf(v3.x, w0, fmaf(v3.y, w1, fmaf(v3.z, w2, fmaf(v3.w, w3, a3))));
  }
  for (int k = 0; k < F; k += 4) {
    float w0 = root[(k + 0) * HD + lane];
    float w1 = root[(k + 1) * HD + lane];
    float w2 = root[(k + 2) * HD + lane];
    float w3 = root[(k + 3) * HD + lane];
    float4 v0 = *(const float4*)&rowbase[0 * KT + 8 * F + k];
    float4 v1 = *(const float4*)&rowbase[1 * KT + 8 * F + k];
    float4 v2 = *(const float4*)&rowbase[2 * KT + 8 * F + k];
    float4 v3 = *(const float4*)&rowbase[3 * KT + 8 * F + k];
    a0 = fmaf(v0.x, w0, fmaf(v0.y, w1, fmaf(v0.z, w2, fmaf(v0.w, w3, a0))));
    a1 = fmaf(v1.x, w0, fmaf(v1.y, w1, fmaf(v1.z, w2, fmaf(v1.w, w3, a1))));
    a2 = fmaf(v2.x, w0, fmaf(v2.y, w1, fmaf(v2.z, w2, fmaf(v2.w, w3, a2))));
    a3 = fmaf(v3.x, w0, fmaf(v3.y, w1, fmaf(v3.z, w2, fmaf(v3.w, w3, a3))));
  }
  outp[(size_t)(nbase + 0) * HD + lane] = a0;
  outp[(size_t)(nbase + 1) * HD + lane] = a1;
  outp[(size_t)(nbase + 2) * HD + lane] = a2;
  outp[(size_t)(nbase + 3) * HD + lane] = a3;
  float s = a0 + a1 + a2 + a3;
  float ss = a0 * a0 + a1 * a1 + a2 * a2 + a3 * a3;
  __syncthreads();
  float* red = agg;
  red[w * 128 + lane] = s;
  red[w * 128 + 64 + lane] = ss;
  __syncthreads();
  if (w == 0) {
    float ts = red[lane] + red[128 + lane] + red[256 + lane] + red[384 + lane];
    float tss = red[64 + lane] + red[192 + lane] + red[320 + lane] + red[448 + lane];
    int rp = blockIdx.x & (RREP - 1);
    atomicAdd(&statsrep[rp * 128 + lane], ts);
    atomicAdd(&statsrep[rp * 128 + 64 + lane], tss);
  }
}

// reduce stat replicas -> BN (scale, shift)
__global__ void k_finstats(const float* __restrict__ rep, const float* __restrict__ g,
                           const float* __restrict__ b, float* __restrict__ scsh) {
  int lane = threadIdx.x;  // 64
  float s = 0.f, ss = 0.f;
  for (int rp = 0; rp < RREP; rp++) {
    s += rep[rp * 128 + lane];
    ss += rep[rp * 128 + 64 + lane];
  }
  float mu = s * (1.0f / NN);
  float var = ss * (1.0f / NN) - mu * mu;
  float sc = g[lane] * rsqrtf(var + BN_EPS);
  scsh[lane] = sc;
  scsh[64 + lane] = b[lane] - mu * sc;
}

// sorted-batch segmented pooling over RAW layer outputs with inline BN+ReLU.
__global__ void k_poolseg(const float* __restrict__ t1, const float* __restrict__ t2,
                          const float* __restrict__ t3, const float* __restrict__ scsh,
                          const int* __restrict__ batch, float* __restrict__ psum,
                          unsigned* __restrict__ pmax, float* __restrict__ cntg) {
  __shared__ int bsh[PCH];
  int base = blockIdx.x * PCH;
  int c = threadIdx.x;  // 0..191
  for (int i = c; i < PCH; i += 192) bsh[i] = batch[base + i];
  __syncthreads();
  int L = c >> 6, cc = c & 63;
  const float* xs = (L == 0) ? t1 : (L == 1) ? t2 : t3;
  float sc = scsh[L * 128 + cc], sh = scsh[L * 128 + 64 + cc];
  int cur = bsh[0];
  float sum = 0.0f, mx = 0.0f;
  int runlen = 0;
  #pragma unroll 4
  for (int i = 0; i < PCH; i++) {
    int g = bsh[i];
    float v = fmaxf(fmaf(xs[(size_t)(base + i) * 64 + cc], sc, sh), 0.0f);
    if (g != cur) {
      atomicAdd(&psum[cur * 192 + c], sum);
      atomicMax(&pmax[cur * 192 + c], __float_as_uint(mx));
      if (c == 0) atomicAdd(&cntg[cur], (float)runlen);
      cur = g; sum = 0.0f; mx = 0.0f; runlen = 0;
    }
    sum += v;
    mx = fmaxf(mx, v);
    runlen++;
  }
  atomicAdd(&psum[cur * 192 + c], sum);
  atomicMax(&pmax[cur * 192 + c], __float_as_uint(mx));
  if (c == 0) atomicAdd(&cntg[cur], (float)runlen);
}

__global__ void k_fc1(const float* __restrict__ psum, const unsigned* __restrict__ pmax,
                      const float* __restrict__ cntg, const float* __restrict__ w,
                      const float* __restrict__ bias, float* __restrict__ h1) {
  __shared__ float a[384];
  int g = blockIdx.x;
  float ic = 1.0f / fmaxf(cntg[g], 1.0f);
  for (int c = threadIdx.x; c < 384; c += 128) {
    a[c] = (c < 192) ? psum[g * 192 + c] * ic : __uint_as_float(pmax[g * 192 + (c - 192)]);
  }
  __syncthreads();
  int j = threadIdx.x;
  float acc = bias[j];
  for (int k = 0; k < 384; k++) acc = fmaf(a[k], w[k * 128 + j], acc);
  h1[g * 128 + j] = acc;
}

__global__ void k_fcbn_stats(const float* __restrict__ h1, const float* __restrict__ g,
                             const float* __restrict__ b, float* __restrict__ scsh) {
  __shared__ float sr[512], ssr[512];
  int j = threadIdx.x & 127, q = threadIdx.x >> 7;
  float s = 0.f, ss = 0.f;
  for (int i = q * 64; i < q * 64 + 64; i++) {
    float v = h1[i * 128 + j];
    s += v;
    ss = fmaf(v, v, ss);
  }
  sr[threadIdx.x] = s;
  ssr[threadIdx.x] = ss;
  __syncthreads();
  if (q == 0) {
    s = sr[j] + sr[128 + j] + sr[256 + j] + sr[384 + j];
    ss = ssr[j] + ssr[128 + j] + ssr[256 + j] + ssr[384 + j];
    float mu = s * (1.0f / NG);
    float var = ss * (1.0f / NG) - mu * mu;
    float sc = g[j] * rsqrtf(var + BN_EPS);
    scsh[j] = sc;
    scsh[128 + j] = b[j] - mu * sc;
  }
}

__global__ void k_leaky(float* __restrict__ h1, const float* __restrict__ scsh) {
  int j = threadIdx.x;
  int g = blockIdx.x;
  float v = fmaf(h1[g * 128 + j], scsh[j], scsh[128 + j]);
  h1[g * 128 + j] = v > 0.0f ? v : 0.2f * v;
}

__global__ void k_head(const float* __restrict__ h1, const float* __restrict__ fc2w,
                       const float* __restrict__ fc2b, const float* __restrict__ d1w,
                       const float* __restrict__ d1b, const float* __restrict__ d2w,
                       const float* __restrict__ d2b, float* __restrict__ out) {
  __shared__ float emb[16];
  int g = blockIdx.x;
  int t = threadIdx.x;  // 0..63
  if (t < 16) {
    float acc = fc2b[t];
    for (int k = 0; k < 128; k++) acc = fmaf(h1[g * 128 + k], fc2w[k * 16 + t], acc);
    emb[t] = acc;
    out[NG + g * 16 + t] = acc;
  }
  __syncthreads();
  float acc = d1b[t];
  for (int k = 0; k < 16; k++) acc = fmaf(emb[k], d1w[k * 64 + t], acc);
  acc = acc > 0.0f ? acc : 0.2f * acc;
  float p = acc * d2w[t];
  for (int off = 32; off > 0; off >>= 1) p += __shfl_down(p, off);
  if (t == 0) out[g] = p + d2b[0];
}

extern "C" void kernel_launch(void* const* d_in, const int* in_sizes, int n_in,
                              void* d_out, int out_size, void* d_ws, size_t ws_size,
                              hipStream_t stream) {
  const float* x    = (const float*)d_in[0];
  const int*   ei   = (const int*)d_in[1];
  const int*   ety  = (const int*)d_in[2];
  const int*   batch= (const int*)d_in[3];
  const float* c1w  = (const float*)d_in[4];
  const float* c1r  = (const float*)d_in[5];
  const float* c1b  = (const float*)d_in[6];
  const float* bn1g = (const float*)d_in[7];
  const float* bn1b = (const float*)d_in[8];
  const float* c2w  = (const float*)d_in[9];
  const float* c2r  = (const float*)d_in[10];
  const float* c2b  = (const float*)d_in[11];
  const float* bn2g = (const float*)d_in[12];
  const float* bn2b = (const float*)d_in[13];
  const float* c3w  = (const float*)d_in[14];
  const float* c3r  = (const float*)d_in[15];
  const float* c3b  = (const float*)d_in[16];
  const float* bn3g = (const float*)d_in[17];
  const float* bn3b = (const float*)d_in[18];
  const float* fc1w = (const float*)d_in[19];
  const float* fc1b = (const float*)d_in[20];
  const float* fbg  = (const float*)d_in[21];
  const float* fbb  = (const float*)d_in[22];
  const float* fc2w = (const float*)d_in[23];
  const float* fc2b = (const float*)d_in[24];
  const float* d1w  = (const float*)d_in[25];
  const float* d1b  = (const float*)d_in[26];
  const float* d2w  = (const float*)d_in[27];
  const float* d2b  = (const float*)d_in[28];
  const int* esrc = ei;
  const int* edst = ei + NE;
  float* out = (float*)d_out;

  float* W = (float*)d_ws;
  size_t o = 0;
  auto alloc = [&](size_t n) { float* p = W + o; o += (n + 63) & ~(size_t)63; return p; };
  unsigned* cnt      = (unsigned*)alloc(M_KEYS);
  float*    psum     = alloc(NG * 192);
  unsigned* pmax     = (unsigned*)alloc(NG * 192);
  float*    cntg     = alloc(NG);
  float*    statsrep = alloc(3 * RREP * 128);
  size_t zone = o;  // buffers [0, zone) zeroed every call
  int*      rowstart = (int*)alloc(M_KEYS + 1);
  int*      rank = (int*)alloc(NE);
  int*      ebuf = (int*)alloc(NE);
  unsigned* bsum = (unsigned*)alloc(1024);
  unsigned* boff = (unsigned*)alloc(1024);
  float*    invcnt = alloc(M_KEYS);
  float*    scsh = alloc(3 * 128);
  float*    fcsc = alloc(256);
  float*    h1   = alloc(NG * 128);
  float*    tmp1 = alloc((size_t)NN * HD);
  float*    tmp2 = alloc((size_t)NN * HD);
  float*    tmp3 = alloc((size_t)NN * HD);
  ushort_t* hbig = (ushort_t*)alloc((size_t)NN * HW / 2);  // bf16 h
  size_t need_bytes = o * 4;
  bool big = (need_bytes <= ws_size);
  (void)in_sizes; (void)n_in; (void)out_size;

  // ---- preprocess: (dst,rel)-keyed CSR with rel packed into entries ----
  k_zero<<<(int)((zone + 255) / 256), 256, 0, stream>>>(W, (int)zone);
  k_cnt<<<(NE + 255) / 256, 256, 0, stream>>>(edst, ety, cnt, rank);
  if (big) k_invcnt<<<(M_KEYS + 255) / 256, 256, 0, stream>>>(cnt, invcnt);
  k_scanA<<<NB, 256, 0, stream>>>(cnt, bsum);
  k_scanB<<<1, 1024, 0, stream>>>(bsum, boff, rowstart);
  k_scanC<<<NB, 256, 0, stream>>>(cnt, boff, rowstart);
  k_place<<<(NE + 255) / 256, 256, 0, stream>>>(esrc, edst, ety, rank, rowstart, ebuf);

  if (big) {
    // ---- transform-first layers ----
    k_xform<FIN, false><<<NN / 32, 576, 0, stream>>>(x, nullptr, c1w, c1r, hbig);
    k_agg<<<NN / 4, 256, 0, stream>>>(hbig, rowstart, ebuf, invcnt, c1b, tmp1, statsrep);
    k_finstats<<<1, 64, 0, stream>>>(statsrep, bn1g, bn1b, scsh);
    k_xform<HD, true><<<NN / 32, 576, 0, stream>>>(tmp1, scsh, c2w, c2r, hbig);
    k_agg<<<NN / 4, 256, 0, stream>>>(hbig, rowstart, ebuf, invcnt, c2b, tmp2, statsrep + RREP * 128);
    k_finstats<<<1, 64, 0, stream>>>(statsrep + RREP * 128, bn2g, bn2b, scsh + 128);
    k_xform<HD, true><<<NN / 32, 576, 0, stream>>>(tmp2, scsh + 128, c3w, c3r, hbig);
    k_agg<<<NN / 4, 256, 0, stream>>>(hbig, rowstart, ebuf, invcnt, c3b, tmp3, statsrep + 2 * RREP * 128);
    k_finstats<<<1, 64, 0, stream>>>(statsrep + 2 * RREP * 128, bn3g, bn3b, scsh + 256);
  } else {
    // ---- fallback: fused layers (round-4 path) ----
    k_layer<FIN, false><<<NN / 16, 256, 0, stream>>>(
        x, nullptr, rowstart, ebuf, c1w, c1r, c1b, tmp1, statsrep);
    k_finstats<<<1, 64, 0, stream>>>(statsrep, bn1g, bn1b, scsh);
    k_layer<HD, true><<<NN / 16, 256, 0, stream>>>(
        tmp1, scsh, rowstart, ebuf, c2w, c2r, c2b, tmp2, statsrep + RREP * 128);
    k_finstats<<<1, 64, 0, stream>>>(statsrep + RREP * 128, bn2g, bn2b, scsh + 128);
    k_layer<HD, true><<<NN / 16, 256, 0, stream>>>(
        tmp2, scsh + 128, rowstart, ebuf, c3w, c3r, c3b, tmp3, statsrep + 2 * RREP * 128);
    k_finstats<<<1, 64, 0, stream>>>(statsrep + 2 * RREP * 128, bn3g, bn3b, scsh + 256);
  }

  // ---- pooling + head ----
  k_poolseg<<<NN / PCH, 192, 0, stream>>>(tmp1, tmp2, tmp3, scsh, batch, psum, pmax, cntg);
  k_fc1<<<NG, 128, 0, stream>>>(psum, pmax, cntg, fc1w, fc1b, h1);
  k_fcbn_stats<<<1, 512, 0, stream>>>(h1, fbg, fbb, fcsc);
  k_leaky<<<NG, 128, 0, stream>>>(h1, fcsc);
  k_head<<<NG, 64, 0, stream>>>(h1, fc2w, fc2b, d1w, d1b, d2w, d2b, out);
}

// Round 6
// 748.186 us; speedup vs baseline: 3.0051x; 1.3261x over previous
//
#include <hip/hip_runtime.h>

#define NN 100000
#define NE 1250000
#define FIN 32
#define HD 64
#define NR 8
#define NG 256
#define BN_EPS 1e-5f
#define PCH 100          // nodes per pooling block (divides NN)
#define M_KEYS (NN * NR) // 800000 (dst,rel) segments
#define NB 782           // scan blocks: 782*1024 >= 800000
#define RREP 32          // BN-stat atomic replicas
#define HW 576           // h width: 8 rel * 64 + root 64

typedef unsigned short ushort_t;
typedef __attribute__((ext_vector_type(8))) short short8;
typedef __attribute__((ext_vector_type(4))) float f32x4;

static __device__ __forceinline__ ushort_t f2bf(float f) {
  unsigned u = __float_as_uint(f);
  u += 0x7fffu + ((u >> 16) & 1u);  // RNE
  return (ushort_t)(u >> 16);
}
static __device__ __forceinline__ float bf2f(ushort_t b) {
  return __uint_as_float((unsigned)b << 16);
}

__global__ void k_zero(float* __restrict__ p, int n) {
  int i = blockIdx.x * 256 + threadIdx.x;
  if (i < n) p[i] = 0.0f;
}

// pass 1: per-(dst,rel) counts + per-edge rank
__global__ void k_cnt(const int* __restrict__ dst, const int* __restrict__ ty,
                      unsigned* __restrict__ cnt, int* __restrict__ rank) {
  int e = blockIdx.x * 256 + threadIdx.x;
  if (e < NE) {
    int key = dst[e] * NR + ty[e];
    rank[e] = (int)atomicAdd(&cnt[key], 1u);
  }
}

__global__ void k_invcnt(const unsigned* __restrict__ cnt, float* __restrict__ ic) {
  int i = blockIdx.x * 256 + threadIdx.x;
  if (i < M_KEYS) ic[i] = 1.0f / (float)max(cnt[i], 1u);
}

// hierarchical exclusive scan of cnt[M_KEYS] -> rowstart[M_KEYS+1]
__global__ void k_scanA(const unsigned* __restrict__ cnt, unsigned* __restrict__ bsum) {
  __shared__ unsigned red[256];
  int t = threadIdx.x;
  int base = blockIdx.x * 1024 + t * 4;
  unsigned s = 0;
  #pragma unroll
  for (int i = 0; i < 4; i++) {
    int idx = base + i;
    if (idx < M_KEYS) s += cnt[idx];
  }
  red[t] = s;
  __syncthreads();
  for (int off = 128; off > 0; off >>= 1) {
    if (t < off) red[t] += red[t + off];
    __syncthreads();
  }
  if (t == 0) bsum[blockIdx.x] = red[0];
}

__global__ __launch_bounds__(1024) void k_scanB(const unsigned* __restrict__ bsum,
                                                unsigned* __restrict__ boff,
                                                int* __restrict__ rowstart) {
  __shared__ unsigned sb[1024];
  int t = threadIdx.x;
  unsigned mine = (t < NB) ? bsum[t] : 0u;
  sb[t] = mine;
  __syncthreads();
  for (int off = 1; off < 1024; off <<= 1) {
    unsigned v = (t >= off) ? sb[t - off] : 0u;
    __syncthreads();
    sb[t] += v;
    __syncthreads();
  }
  if (t < NB) boff[t] = sb[t] - mine;
  if (t == 1023) rowstart[M_KEYS] = (int)sb[1023];
}

__global__ void k_scanC(const unsigned* __restrict__ cnt, const unsigned* __restrict__ boff,
                        int* __restrict__ rowstart) {
  __shared__ unsigned sb[256];
  int t = threadIdx.x;
  int base = blockIdx.x * 1024 + t * 4;
  unsigned c0 = (base + 0 < M_KEYS) ? cnt[base + 0] : 0u;
  unsigned c1 = (base + 1 < M_KEYS) ? cnt[base + 1] : 0u;
  unsigned c2 = (base + 2 < M_KEYS) ? cnt[base + 2] : 0u;
  unsigned c3 = (base + 3 < M_KEYS) ? cnt[base + 3] : 0u;
  unsigned tot = c0 + c1 + c2 + c3;
  sb[t] = tot;
  __syncthreads();
  for (int off = 1; off < 256; off <<= 1) {
    unsigned v = (t >= off) ? sb[t - off] : 0u;
    __syncthreads();
    sb[t] += v;
    __syncthreads();
  }
  unsigned run = boff[blockIdx.x] + (sb[t] - tot);
  if (base + 0 < M_KEYS) rowstart[base + 0] = (int)run; run += c0;
  if (base + 1 < M_KEYS) rowstart[base + 1] = (int)run; run += c1;
  if (base + 2 < M_KEYS) rowstart[base + 2] = (int)run; run += c2;
  if (base + 3 < M_KEYS) rowstart[base + 3] = (int)run;
}

// pass 2: place (src | rel<<20) into (dst,rel)-CSR
__global__ void k_place(const int* __restrict__ src, const int* __restrict__ dst,
                        const int* __restrict__ ty, const int* __restrict__ rank,
                        const int* __restrict__ rowstart, int* __restrict__ ebuf) {
  int e = blockIdx.x * 256 + threadIdx.x;
  if (e < NE) {
    int t = ty[e];
    int key = dst[e] * NR + t;
    ebuf[rowstart[key] + rank[e]] = src[e] | (t << 20);
  }
}

// ---------------- transform-first path (MFMA) ----------------
// xbf[n] = hi/lo bf16 split of BNReLU(x[n]): [n][0..F-1]=hi, [n][F..2F-1]=lo
template <int F, bool APPLY_BN>
__global__ void k_tobf(const float* __restrict__ xin, const float* __restrict__ scsh,
                       ushort_t* __restrict__ xbf) {
  int i = blockIdx.x * 256 + threadIdx.x;  // over NN*F
  int n = i / F, k = i % F;
  float v = xin[i];
  if (APPLY_BN) v = fmaxf(fmaf(v, scsh[k], scsh[64 + k]), 0.0f);
  ushort_t hi = f2bf(v);
  xbf[(size_t)n * (2 * F) + k] = hi;
  xbf[(size_t)n * (2 * F) + F + k] = f2bf(v - bf2f(hi));
}

// wt[c][k] = bf16 of column c of [W_0..W_7 | root] (transposed for contiguous frags)
template <int F>
__global__ void k_wconv(const float* __restrict__ convw, const float* __restrict__ root,
                        ushort_t* __restrict__ wt) {
  int i = blockIdx.x * 256 + threadIdx.x;  // over 576*F
  if (i >= 576 * F) return;
  int c = i / F, k = i % F;
  float v = (c < 512) ? convw[((size_t)(c >> 6) * F + k) * 64 + (c & 63)]
                      : root[(size_t)k * 64 + (c & 63)];
  wt[(size_t)c * F + k] = f2bf(v);
}

// MFMA xform: h[16 rows x 576 cols per block] = xbf(hi+lo) @ wt.
// B frags register-resident (wt is 74KB, L2-hot); A frags direct from global;
// zero LDS. 36 MFMA + ~40 16B loads per wave.
template <int F>
__global__ __launch_bounds__(256) void k_xmm(const ushort_t* __restrict__ xbf,
                                             const ushort_t* __restrict__ wt,
                                             ushort_t* __restrict__ h) {
  constexpr int KK = 2 * F;
  int lane = threadIdx.x & 63;
  int w = threadIdx.x >> 6;
  int nbase = blockIdx.x * 16;
  int m = lane & 15;   // A row / B col within tile
  int q = lane >> 4;   // quad 0..3, k-offset q*8
  const ushort_t* xrow = xbf + (size_t)(nbase + m) * KK + q * 8;
  f32x4 acc[9];
  #pragma unroll
  for (int t = 0; t < 9; t++) acc[t] = (f32x4){0.f, 0.f, 0.f, 0.f};
  int ct0 = w * 9;
  #pragma unroll
  for (int ks = 0; ks < F / 32; ks++) {
    short8 ah = *(const short8*)(xrow + ks * 32);       // hi half
    short8 al = *(const short8*)(xrow + F + ks * 32);   // lo half
    #pragma unroll
    for (int t = 0; t < 9; t++) {
      const ushort_t* wp = wt + (size_t)((ct0 + t) * 16 + m) * F + ks * 32 + q * 8;
      short8 b = *(const short8*)wp;
      acc[t] = __builtin_amdgcn_mfma_f32_16x16x32_bf16(ah, b, acc[t], 0, 0, 0);
      acc[t] = __builtin_amdgcn_mfma_f32_16x16x32_bf16(al, b, acc[t], 0, 0, 0);
    }
  }
  #pragma unroll
  for (int t = 0; t < 9; t++) {
    int col = (ct0 + t) * 16 + m;
    #pragma unroll
    for (int j = 0; j < 4; j++) {
      int row = nbase + q * 4 + j;  // C/D: col=lane&15, row=(lane>>4)*4+reg
      h[(size_t)row * HW + col] = f2bf(acc[t][j]);
    }
  }
}

// out[n] = bias + h[n,512:576] + sum_edges h[src, rel*64:..] * invcnt[n,rel].
// wave = 1 node, lane = channel; single register accumulator, 8 loads in flight.
// Epilogue: BN column stats via LDS reduce + replica atomics.
__global__ __launch_bounds__(256) void k_agg(
    const ushort_t* __restrict__ h, const int* __restrict__ rs,
    const int* __restrict__ ebuf, const float* __restrict__ invcnt,
    const float* __restrict__ bias, float* __restrict__ outp,
    float* __restrict__ statsrep) {
  __shared__ float red[512];
  int lane = threadIdx.x & 63, w = threadIdx.x >> 6;
  int n = blockIdx.x * 4 + w;
  int lo = rs[n * NR], hi = rs[n * NR + NR];
  float acc = bias[lane] + bf2f(h[(size_t)n * HW + 512 + lane]);
  for (int e = lo; e < hi; e += 8) {
    int m = hi - e;  // wave-uniform
    int pk[8]; float hv[8], ic[8];
    #pragma unroll
    for (int u = 0; u < 8; u++) pk[u] = (u < m) ? ebuf[e + u] : 0;
    #pragma unroll
    for (int u = 0; u < 8; u++)
      hv[u] = (u < m) ? bf2f(h[(size_t)(pk[u] & 0xFFFFF) * HW + ((pk[u] >> 20) << 6) + lane]) : 0.f;
    #pragma unroll
    for (int u = 0; u < 8; u++)
      ic[u] = (u < m) ? invcnt[n * NR + (pk[u] >> 20)] : 0.f;
    #pragma unroll
    for (int u = 0; u < 8; u++) acc = fmaf(hv[u], ic[u], acc);
  }
  outp[(size_t)n * HD + lane] = acc;
  red[w * 128 + lane] = acc;
  red[w * 128 + 64 + lane] = acc * acc;
  __syncthreads();
  if (w == 0) {
    float ts = red[lane] + red[128 + lane] + red[256 + lane] + red[384 + lane];
    float tss = red[64 + lane] + red[192 + lane] + red[320 + lane] + red[448 + lane];
    int rp = blockIdx.x & (RREP - 1);
    atomicAdd(&statsrep[rp * 128 + lane], ts);
    atomicAdd(&statsrep[rp * 128 + 64 + lane], tss);
  }
}

// ---------------- fallback fused layer (round-4, used if ws too small) ----------------
template <int F, bool APPLY_BN>
__global__ __launch_bounds__(256) void k_layer(
    const float* __restrict__ xin, const float* __restrict__ scsh_in,
    const int* __restrict__ rs, const int* __restrict__ ebuf,
    const float* __restrict__ convw, const float* __restrict__ root,
    const float* __restrict__ bias, float* __restrict__ outp,
    float* __restrict__ statsrep) {
  constexpr int KT = 9 * F;
  __shared__ float agg[16 * KT];
  int lane = threadIdx.x & 63;
  int w = threadIdx.x >> 6;
  int w4 = w * 4;
  int nbase = blockIdx.x * 16 + w4;
  float scr = 0.f, shr = 0.f;
  if (APPLY_BN) { scr = scsh_in[lane]; shr = scsh_in[64 + lane]; }
  if (lane < F) {
    #pragma unroll
    for (int j = 0; j < 4; j++)
      #pragma unroll
      for (int r = 0; r < NR; r++)
        agg[(w4 + j) * KT + r * F + lane] = 0.f;
  }
  int nb8 = nbase * NR;
  int lo = rs[nb8];
  int b1 = rs[nb8 + 8], b2 = rs[nb8 + 16], b3 = rs[nb8 + 24];
  int hi = rs[nb8 + 32];
  for (int e = lo; e < hi; e += 8) {
    int m = hi - e;
    int pk[8]; float vv[8];
    #pragma unroll
    for (int u = 0; u < 8; u++) pk[u] = (u < m) ? ebuf[e + u] : 0;
    #pragma unroll
    for (int u = 0; u < 8; u++)
      vv[u] = (u < m && lane < F) ? xin[(size_t)(pk[u] & 0xFFFFF) * F + lane] : 0.f;
    if (APPLY_BN) {
      #pragma unroll
      for (int u = 0; u < 8; u++) vv[u] = fmaxf(fmaf(vv[u], scr, shr), 0.f);
    }
    #pragma unroll
    for (int u = 0; u < 8; u++) {
      if (u < m) {
        int ee = e + u;
        int ln = (ee >= b1) + (ee >= b2) + (ee >= b3);
        int rel = pk[u] >> 20;
        if (lane < F) agg[(w4 + ln) * KT + rel * F + lane] += vv[u];
      }
    }
  }
  if (lane < F) {
    #pragma unroll
    for (int j = 0; j < 4; j++) {
      float sv = xin[(size_t)(nbase + j) * F + lane];
      if (APPLY_BN) sv = fmaxf(fmaf(sv, scr, shr), 0.f);
      agg[(w4 + j) * KT + 8 * F + lane] = sv;
    }
  }
  for (int j = 0; j < 4; j++) {
    int n8 = (nbase + j) * NR;
    #pragma unroll
    for (int r = 0; r < NR; r++) {
      int c = rs[n8 + r + 1] - rs[n8 + r];
      if (c > 1 && lane < F)
        agg[(w4 + j) * KT + r * F + lane] *= (1.0f / (float)c);
    }
  }
  float b = bias[lane];
  float a0 = b, a1 = b, a2 = b, a3 = b;
  const float* rowbase = &agg[w4 * KT];
  for (int k = 0; k < 8 * F; k += 4) {
    float w0 = convw[(k + 0) * HD + lane];
    float w1 = convw[(k + 1) * HD + lane];
    float w2 = convw[(k + 2) * HD + lane];
    float w3 = convw[(k + 3) * HD + lane];
    float4 v0 = *(const float4*)&rowbase[0 * KT + k];
    float4 v1 = *(const float4*)&rowbase[1 * KT + k];
    float4 v2 = *(const float4*)&rowbase[2 * KT + k];
    float4 v3 = *(const float4*)&rowbase[3 * KT + k];
    a0 = fmaf(v0.x, w0, fmaf(v0.y, w1, fmaf(v0.z, w2, fmaf(v0.w, w3, a0))));
    a1 = fmaf(v1.x, w0, fmaf(v1.y, w1, fmaf(v1.z, w2, fmaf(v1.w, w3, a1))));
    a2 = fmaf(v2.x, w0, fmaf(v2.y, w1, fmaf(v2.z, w2, fmaf(v2.w, w3, a2))));
    a3 = fmaf(v3.x, w0, fmaf(v3.y, w1, fmaf(v3.z, w2, fmaf(v3.w, w3, a3))));
  }
  for (int k = 0; k < F; k += 4) {
    float w0 = root[(k + 0) * HD + lane];
    float w1 = root[(k + 1) * HD + lane];
    float w2 = root[(k + 2) * HD + lane];
    float w3 = root[(k + 3) * HD + lane];
    float4 v0 = *(const float4*)&rowbase[0 * KT + 8 * F + k];
    float4 v1 = *(const float4*)&rowbase[1 * KT + 8 * F + k];
    float4 v2 = *(const float4*)&rowbase[2 * KT + 8 * F + k];
    float4 v3 = *(const float4*)&rowbase[3 * KT + 8 * F + k];
    a0 = fmaf(v0.x, w0, fmaf(v0.y, w1, fmaf(v0.z, w2, fmaf(v0.w, w3, a0))));
    a1 = fmaf(v1.x, w0, fmaf(v1.y, w1, fmaf(v1.z, w2, fmaf(v1.w, w3, a1))));
    a2 = fmaf(v2.x, w0, fmaf(v2.y, w1, fmaf(v2.z, w2, fmaf(v2.w, w3, a2))));
    a3 = fmaf(v3.x, w0, fmaf(v3.y, w1, fmaf(v3.w, w3, a3)));
  }
  outp[(size_t)(nbase + 0) * HD + lane] = a0;
  outp[(size_t)(nbase + 1) * HD + lane] = a1;
  outp[(size_t)(nbase + 2) * HD + lane] = a2;
  outp[(size_t)(nbase + 3) * HD + lane] = a3;
  float s = a0 + a1 + a2 + a3;
  float ss = a0 * a0 + a1 * a1 + a2 * a2 + a3 * a3;
  __syncthreads();
  float* red = agg;
  red[w * 128 + lane] = s;
  red[w * 128 + 64 + lane] = ss;
  __syncthreads();
  if (w == 0) {
    float ts = red[lane] + red[128 + lane] + red[256 + lane] + red[384 + lane];
    float tss = red[64 + lane] + red[192 + lane] + red[320 + lane] + red[448 + lane];
    int rp = blockIdx.x & (RREP - 1);
    atomicAdd(&statsrep[rp * 128 + lane], ts);
    atomicAdd(&statsrep[rp * 128 + 64 + lane], tss);
  }
}

// reduce stat replicas -> BN (scale, shift)
__global__ void k_finstats(const float* __restrict__ rep, const float* __restrict__ g,
                           const float* __restrict__ b, float* __restrict__ scsh) {
  int lane = threadIdx.x;  // 64
  float s = 0.f, ss = 0.f;
  for (int rp = 0; rp < RREP; rp++) {
    s += rep[rp * 128 + lane];
    ss += rep[rp * 128 + 64 + lane];
  }
  float mu = s * (1.0f / NN);
  float var = ss * (1.0f / NN) - mu * mu;
  float sc = g[lane] * rsqrtf(var + BN_EPS);
  scsh[lane] = sc;
  scsh[64 + lane] = b[lane] - mu * sc;
}

// sorted-batch segmented pooling over RAW layer outputs with inline BN+ReLU.
__global__ void k_poolseg(const float* __restrict__ t1, const float* __restrict__ t2,
                          const float* __restrict__ t3, const float* __restrict__ scsh,
                          const int* __restrict__ batch, float* __restrict__ psum,
                          unsigned* __restrict__ pmax, float* __restrict__ cntg) {
  __shared__ int bsh[PCH];
  int base = blockIdx.x * PCH;
  int c = threadIdx.x;  // 0..191
  for (int i = c; i < PCH; i += 192) bsh[i] = batch[base + i];
  __syncthreads();
  int L = c >> 6, cc = c & 63;
  const float* xs = (L == 0) ? t1 : (L == 1) ? t2 : t3;
  float sc = scsh[L * 128 + cc], sh = scsh[L * 128 + 64 + cc];
  int cur = bsh[0];
  float sum = 0.0f, mx = 0.0f;
  int runlen = 0;
  #pragma unroll 4
  for (int i = 0; i < PCH; i++) {
    int g = bsh[i];
    float v = fmaxf(fmaf(xs[(size_t)(base + i) * 64 + cc], sc, sh), 0.0f);
    if (g != cur) {
      atomicAdd(&psum[cur * 192 + c], sum);
      atomicMax(&pmax[cur * 192 + c], __float_as_uint(mx));
      if (c == 0) atomicAdd(&cntg[cur], (float)runlen);
      cur = g; sum = 0.0f; mx = 0.0f; runlen = 0;
    }
    sum += v;
    mx = fmaxf(mx, v);
    runlen++;
  }
  atomicAdd(&psum[cur * 192 + c], sum);
  atomicMax(&pmax[cur * 192 + c], __float_as_uint(mx));
  if (c == 0) atomicAdd(&cntg[cur], (float)runlen);
}

__global__ void k_fc1(const float* __restrict__ psum, const unsigned* __restrict__ pmax,
                      const float* __restrict__ cntg, const float* __restrict__ w,
                      const float* __restrict__ bias, float* __restrict__ h1) {
  __shared__ float a[384];
  int g = blockIdx.x;
  float ic = 1.0f / fmaxf(cntg[g], 1.0f);
  for (int c = threadIdx.x; c < 384; c += 128) {
    a[c] = (c < 192) ? psum[g * 192 + c] * ic : __uint_as_float(pmax[g * 192 + (c - 192)]);
  }
  __syncthreads();
  int j = threadIdx.x;
  float acc = bias[j];
  for (int k = 0; k < 384; k++) acc = fmaf(a[k], w[k * 128 + j], acc);
  h1[g * 128 + j] = acc;
}

__global__ void k_fcbn_stats(const float* __restrict__ h1, const float* __restrict__ g,
                             const float* __restrict__ b, float* __restrict__ scsh) {
  __shared__ float sr[512], ssr[512];
  int j = threadIdx.x & 127, q = threadIdx.x >> 7;
  float s = 0.f, ss = 0.f;
  for (int i = q * 64; i < q * 64 + 64; i++) {
    float v = h1[i * 128 + j];
    s += v;
    ss = fmaf(v, v, ss);
  }
  sr[threadIdx.x] = s;
  ssr[threadIdx.x] = ss;
  __syncthreads();
  if (q == 0) {
    s = sr[j] + sr[128 + j] + sr[256 + j] + sr[384 + j];
    ss = ssr[j] + ssr[128 + j] + ssr[256 + j] + ssr[384 + j];
    float mu = s * (1.0f / NG);
    float var = ss * (1.0f / NG) - mu * mu;
    float sc = g[j] * rsqrtf(var + BN_EPS);
    scsh[j] = sc;
    scsh[128 + j] = b[j] - mu * sc;
  }
}

__global__ void k_leaky(float* __restrict__ h1, const float* __restrict__ scsh) {
  int j = threadIdx.x;
  int g = blockIdx.x;
  float v = fmaf(h1[g * 128 + j], scsh[j], scsh[128 + j]);
  h1[g * 128 + j] = v > 0.0f ? v : 0.2f * v;
}

__global__ void k_head(const float* __restrict__ h1, const float* __restrict__ fc2w,
                       const float* __restrict__ fc2b, const float* __restrict__ d1w,
                       const float* __restrict__ d1b, const float* __restrict__ d2w,
                       const float* __restrict__ d2b, float* __restrict__ out) {
  __shared__ float emb[16];
  int g = blockIdx.x;
  int t = threadIdx.x;  // 0..63
  if (t < 16) {
    float acc = fc2b[t];
    for (int k = 0; k < 128; k++) acc = fmaf(h1[g * 128 + k], fc2w[k * 16 + t], acc);
    emb[t] = acc;
    out[NG + g * 16 + t] = acc;
  }
  __syncthreads();
  float acc = d1b[t];
  for (int k = 0; k < 16; k++) acc = fmaf(emb[k], d1w[k * 64 + t], acc);
  acc = acc > 0.0f ? acc : 0.2f * acc;
  float p = acc * d2w[t];
  for (int off = 32; off > 0; off >>= 1) p += __shfl_down(p, off);
  if (t == 0) out[g] = p + d2b[0];
}

extern "C" void kernel_launch(void* const* d_in, const int* in_sizes, int n_in,
                              void* d_out, int out_size, void* d_ws, size_t ws_size,
                              hipStream_t stream) {
  const float* x    = (const float*)d_in[0];
  const int*   ei   = (const int*)d_in[1];
  const int*   ety  = (const int*)d_in[2];
  const int*   batch= (const int*)d_in[3];
  const float* c1w  = (const float*)d_in[4];
  const float* c1r  = (const float*)d_in[5];
  const float* c1b  = (const float*)d_in[6];
  const float* bn1g = (const float*)d_in[7];
  const float* bn1b = (const float*)d_in[8];
  const float* c2w  = (const float*)d_in[9];
  const float* c2r  = (const float*)d_in[10];
  const float* c2b  = (const float*)d_in[11];
  const float* bn2g = (const float*)d_in[12];
  const float* bn2b = (const float*)d_in[13];
  const float* c3w  = (const float*)d_in[14];
  const float* c3r  = (const float*)d_in[15];
  const float* c3b  = (const float*)d_in[16];
  const float* bn3g = (const float*)d_in[17];
  const float* bn3b = (const float*)d_in[18];
  const float* fc1w = (const float*)d_in[19];
  const float* fc1b = (const float*)d_in[20];
  const float* fbg  = (const float*)d_in[21];
  const float* fbb  = (const float*)d_in[22];
  const float* fc2w = (const float*)d_in[23];
  const float* fc2b = (const float*)d_in[24];
  const float* d1w  = (const float*)d_in[25];
  const float* d1b  = (const float*)d_in[26];
  const float* d2w  = (const float*)d_in[27];
  const float* d2b  = (const float*)d_in[28];
  const int* esrc = ei;
  const int* edst = ei + NE;
  float* out = (float*)d_out;

  float* W = (float*)d_ws;
  size_t o = 0;
  auto alloc = [&](size_t n) { float* p = W + o; o += (n + 63) & ~(size_t)63; return p; };
  unsigned* cnt      = (unsigned*)alloc(M_KEYS);
  float*    psum     = alloc(NG * 192);
  unsigned* pmax     = (unsigned*)alloc(NG * 192);
  float*    cntg     = alloc(NG);
  float*    statsrep = alloc(3 * RREP * 128);
  size_t zone = o;  // buffers [0, zone) zeroed every call
  int*      rowstart = (int*)alloc(M_KEYS + 1);
  int*      rank = (int*)alloc(NE);
  int*      ebuf = (int*)alloc(NE);
  unsigned* bsum = (unsigned*)alloc(1024);
  unsigned* boff = (unsigned*)alloc(1024);
  float*    invcnt = alloc(M_KEYS);
  float*    scsh = alloc(3 * 128);
  float*    fcsc = alloc(256);
  float*    h1   = alloc(NG * 128);
  float*    tmp1 = alloc((size_t)NN * HD);
  float*    tmp2 = alloc((size_t)NN * HD);
  float*    tmp3 = alloc((size_t)NN * HD);
  ushort_t* hbig = (ushort_t*)alloc((size_t)NN * HW / 2);    // bf16 h
  ushort_t* xbf  = (ushort_t*)alloc((size_t)NN * HD);        // bf16 hi/lo x (2*64 shorts/row max)
  ushort_t* wt   = (ushort_t*)alloc(576 * HD / 2);           // bf16 W^T
  size_t need_bytes = o * 4;
  bool big = (need_bytes <= ws_size);
  (void)in_sizes; (void)n_in; (void)out_size;

  // ---- preprocess: (dst,rel)-keyed CSR with rel packed into entries ----
  k_zero<<<(int)((zone + 255) / 256), 256, 0, stream>>>(W, (int)zone);
  k_cnt<<<(NE + 255) / 256, 256, 0, stream>>>(edst, ety, cnt, rank);
  if (big) k_invcnt<<<(M_KEYS + 255) / 256, 256, 0, stream>>>(cnt, invcnt);
  k_scanA<<<NB, 256, 0, stream>>>(cnt, bsum);
  k_scanB<<<1, 1024, 0, stream>>>(bsum, boff, rowstart);
  k_scanC<<<NB, 256, 0, stream>>>(cnt, boff, rowstart);
  k_place<<<(NE + 255) / 256, 256, 0, stream>>>(esrc, edst, ety, rank, rowstart, ebuf);

  if (big) {
    // ---- MFMA transform-first layers ----
    k_tobf<FIN, false><<<NN * FIN / 256, 256, 0, stream>>>(x, nullptr, xbf);
    k_wconv<FIN><<<(576 * FIN + 255) / 256, 256, 0, stream>>>(c1w, c1r, wt);
    k_xmm<FIN><<<NN / 16, 256, 0, stream>>>(xbf, wt, hbig);
    k_agg<<<NN / 4, 256, 0, stream>>>(hbig, rowstart, ebuf, invcnt, c1b, tmp1, statsrep);
    k_finstats<<<1, 64, 0, stream>>>(statsrep, bn1g, bn1b, scsh);

    k_tobf<HD, true><<<NN * HD / 256, 256, 0, stream>>>(tmp1, scsh, xbf);
    k_wconv<HD><<<(576 * HD + 255) / 256, 256, 0, stream>>>(c2w, c2r, wt);
    k_xmm<HD><<<NN / 16, 256, 0, stream>>>(xbf, wt, hbig);
    k_agg<<<NN / 4, 256, 0, stream>>>(hbig, rowstart, ebuf, invcnt, c2b, tmp2, statsrep + RREP * 128);
    k_finstats<<<1, 64, 0, stream>>>(statsrep + RREP * 128, bn2g, bn2b, scsh + 128);

    k_tobf<HD, true><<<NN * HD / 256, 256, 0, stream>>>(tmp2, scsh + 128, xbf);
    k_wconv<HD><<<(576 * HD + 255) / 256, 256, 0, stream>>>(c3w, c3r, wt);
    k_xmm<HD><<<NN / 16, 256, 0, stream>>>(xbf, wt, hbig);
    k_agg<<<NN / 4, 256, 0, stream>>>(hbig, rowstart, ebuf, invcnt, c3b, tmp3, statsrep + 2 * RREP * 128);
    k_finstats<<<1, 64, 0, stream>>>(statsrep + 2 * RREP * 128, bn3g, bn3b, scsh + 256);
  } else {
    // ---- fallback: fused layers (round-4 path) ----
    k_layer<FIN, false><<<NN / 16, 256, 0, stream>>>(
        x, nullptr, rowstart, ebuf, c1w, c1r, c1b, tmp1, statsrep);
    k_finstats<<<1, 64, 0, stream>>>(statsrep, bn1g, bn1b, scsh);
    k_layer<HD, true><<<NN / 16, 256, 0, stream>>>(
        tmp1, scsh, rowstart, ebuf, c2w, c2r, c2b, tmp2, statsrep + RREP * 128);
    k_finstats<<<1, 64, 0, stream>>>(statsrep + RREP * 128, bn2g, bn2b, scsh + 128);
    k_layer<HD, true><<<NN / 16, 256, 0, stream>>>(
        tmp2, scsh + 128, rowstart, ebuf, c3w, c3r, c3b, tmp3, statsrep + 2 * RREP * 128);
    k_finstats<<<1, 64, 0, stream>>>(statsrep + 2 * RREP * 128, bn3g, bn3b, scsh + 256);
  }

  // ---- pooling + head ----
  k_poolseg<<<NN / PCH, 192, 0, stream>>>(tmp1, tmp2, tmp3, scsh, batch, psum, pmax, cntg);
  k_fc1<<<NG, 128, 0, stream>>>(psum, pmax, cntg, fc1w, fc1b, h1);
  k_fcbn_stats<<<1, 512, 0, stream>>>(h1, fbg, fbb, fcsc);
  k_leaky<<<NG, 128, 0, stream>>>(h1, fcsc);
  k_head<<<NG, 64, 0, stream>>>(h1, fc2w, fc2b, d1w, d1b, d2w, d2b, out);
}

// Round 7
// 726.640 us; speedup vs baseline: 3.0943x; 1.0297x over previous
//
#include <hip/hip_runtime.h>

#define NN 100000
#define NE 1250000
#define FIN 32
#define HD 64
#define NR 8
#define NG 256
#define BN_EPS 1e-5f
#define PCH 100          // nodes per pooling block (divides NN)
#define M_KEYS (NN * NR) // 800000 (dst,rel) segments
#define NB 782           // scan blocks: 782*1024 >= 800000
#define RREP 32          // BN-stat atomic replicas

typedef unsigned short ushort_t;
typedef __attribute__((ext_vector_type(8))) short short8;
typedef __attribute__((ext_vector_type(4))) float f32x4;

static __device__ __forceinline__ ushort_t f2bf(float f) {
  unsigned u = __float_as_uint(f);
  u += 0x7fffu + ((u >> 16) & 1u);  // RNE
  return (ushort_t)(u >> 16);
}
static __device__ __forceinline__ float bf2f(ushort_t b) {
  return __uint_as_float((unsigned)b << 16);
}

__global__ void k_zero(float* __restrict__ p, int n) {
  int i = blockIdx.x * 256 + threadIdx.x;
  if (i < n) p[i] = 0.0f;
}

// pass 1: per-(dst,rel) counts + per-edge rank
__global__ void k_cnt(const int* __restrict__ dst, const int* __restrict__ ty,
                      unsigned* __restrict__ cnt, int* __restrict__ rank) {
  int e = blockIdx.x * 256 + threadIdx.x;
  if (e < NE) {
    int key = dst[e] * NR + ty[e];
    rank[e] = (int)atomicAdd(&cnt[key], 1u);
  }
}

// hierarchical exclusive scan of cnt[M_KEYS] -> rowstart[M_KEYS+1]
__global__ void k_scanA(const unsigned* __restrict__ cnt, unsigned* __restrict__ bsum) {
  __shared__ unsigned red[256];
  int t = threadIdx.x;
  int base = blockIdx.x * 1024 + t * 4;
  unsigned s = 0;
  #pragma unroll
  for (int i = 0; i < 4; i++) {
    int idx = base + i;
    if (idx < M_KEYS) s += cnt[idx];
  }
  red[t] = s;
  __syncthreads();
  for (int off = 128; off > 0; off >>= 1) {
    if (t < off) red[t] += red[t + off];
    __syncthreads();
  }
  if (t == 0) bsum[blockIdx.x] = red[0];
}

__global__ __launch_bounds__(1024) void k_scanB(const unsigned* __restrict__ bsum,
                                                unsigned* __restrict__ boff,
                                                int* __restrict__ rowstart) {
  __shared__ unsigned sb[1024];
  int t = threadIdx.x;
  unsigned mine = (t < NB) ? bsum[t] : 0u;
  sb[t] = mine;
  __syncthreads();
  for (int off = 1; off < 1024; off <<= 1) {
    unsigned v = (t >= off) ? sb[t - off] : 0u;
    __syncthreads();
    sb[t] += v;
    __syncthreads();
  }
  if (t < NB) boff[t] = sb[t] - mine;
  if (t == 1023) rowstart[M_KEYS] = (int)sb[1023];
}

__global__ void k_scanC(const unsigned* __restrict__ cnt, const unsigned* __restrict__ boff,
                        int* __restrict__ rowstart) {
  __shared__ unsigned sb[256];
  int t = threadIdx.x;
  int base = blockIdx.x * 1024 + t * 4;
  unsigned c0 = (base + 0 < M_KEYS) ? cnt[base + 0] : 0u;
  unsigned c1 = (base + 1 < M_KEYS) ? cnt[base + 1] : 0u;
  unsigned c2 = (base + 2 < M_KEYS) ? cnt[base + 2] : 0u;
  unsigned c3 = (base + 3 < M_KEYS) ? cnt[base + 3] : 0u;
  unsigned tot = c0 + c1 + c2 + c3;
  sb[t] = tot;
  __syncthreads();
  for (int off = 1; off < 256; off <<= 1) {
    unsigned v = (t >= off) ? sb[t - off] : 0u;
    __syncthreads();
    sb[t] += v;
    __syncthreads();
  }
  unsigned run = boff[blockIdx.x] + (sb[t] - tot);
  if (base + 0 < M_KEYS) rowstart[base + 0] = (int)run; run += c0;
  if (base + 1 < M_KEYS) rowstart[base + 1] = (int)run; run += c1;
  if (base + 2 < M_KEYS) rowstart[base + 2] = (int)run; run += c2;
  if (base + 3 < M_KEYS) rowstart[base + 3] = (int)run;
}

// pass 2: place (src | rel<<20) into (dst,rel)-CSR
__global__ void k_place(const int* __restrict__ src, const int* __restrict__ dst,
                        const int* __restrict__ ty, const int* __restrict__ rank,
                        const int* __restrict__ rowstart, int* __restrict__ ebuf) {
  int e = blockIdx.x * 256 + threadIdx.x;
  if (e < NE) {
    int t = ty[e];
    int key = dst[e] * NR + t;
    ebuf[rowstart[key] + rank[e]] = src[e] | (t << 20);
  }
}

// wtT[c][k] bf16, c<64 output cols, k<9F: [W_0..W_7 | root] transposed so
// each MFMA B-fragment is a contiguous short8.
template <int F>
__global__ void k_wconv(const float* __restrict__ convw, const float* __restrict__ root,
                        ushort_t* __restrict__ wtT) {
  constexpr int KT = 9 * F;
  int i = blockIdx.x * 256 + threadIdx.x;  // over 64*KT
  if (i >= 64 * KT) return;
  int c = i / KT, k = i % KT;
  float v = (k < 8 * F) ? convw[(size_t)k * 64 + c] : root[(size_t)(k - 8 * F) * 64 + c];
  wtT[i] = f2bf(v);
}

// Fused RGCN layer, aggregate-first + MFMA:
// Phase A (per wave: 4 nodes): walk the node's (dst,rel)-sorted edge list,
//   register-accumulate per rel-run (gathers hit L3: xin is 12-26 MB, just
//   written), BN+ReLU fused on the gathered values, flush mean as hi/lo bf16
//   into LDS agg rows. Self row in slot 8.
// Phase B (per wave: 16 output cols): 16x16x32 MFMA over K=9F with hi/lo A
//   from LDS, B from L2-hot wtT. Epilogue: +bias, store f32, BN column stats
//   via shfl reduce + replica atomics.
template <int F, bool APPLY_BN>
__global__ __launch_bounds__(256) void k_fused(
    const float* __restrict__ xin, const float* __restrict__ scsh_in,
    const int* __restrict__ rs, const int* __restrict__ ebuf,
    const ushort_t* __restrict__ wtT, const float* __restrict__ bias,
    float* __restrict__ outp, float* __restrict__ statsrep) {
  constexpr int KT = 9 * F;
  constexpr int LDW = KT + 8;  // pad: row stride 4 words mod 32 -> spread banks
  __shared__ ushort_t aggh[16][LDW];
  __shared__ ushort_t aggl[16][LDW];
  int lane = threadIdx.x & 63, w = threadIdx.x >> 6;
  int w4 = w * 4;
  int nbase = blockIdx.x * 16;

  float scr = 0.f, shr = 0.f;
  if (APPLY_BN && lane < F) { scr = scsh_in[lane]; shr = scsh_in[64 + lane]; }

  // zero own 4 rows (both arrays)
  {
    uint* zh = (uint*)&aggh[w4][0];
    uint* zl = (uint*)&aggl[w4][0];
    for (int i = lane; i < 2 * LDW; i += 64) { zh[i] = 0u; zl[i] = 0u; }
  }

  // ---- phase A ----
  for (int j = 0; j < 4; j++) {
    int n = nbase + w4 + j;
    int row = w4 + j;
    int lo = rs[n * NR], hi = rs[n * NR + NR];
    float acc = 0.f;
    int cur = -1, cnt = 0;
    for (int e = lo; e < hi; e += 8) {
      int m = hi - e;  // wave-uniform
      int pk[8]; float v[8];
      #pragma unroll
      for (int u = 0; u < 8; u++) pk[u] = (u < m) ? ebuf[e + u] : 0;
      #pragma unroll
      for (int u = 0; u < 8; u++) {
        float t = (u < m && lane < F) ? xin[(size_t)(pk[u] & 0xFFFFF) * F + lane] : 0.f;
        if (APPLY_BN) t = fmaxf(fmaf(t, scr, shr), 0.f);
        v[u] = t;
      }
      #pragma unroll
      for (int u = 0; u < 8; u++) {
        if (u < m) {  // wave-uniform
          int r = pk[u] >> 20;
          if (r != cur) {
            if (cnt > 0) {
              float mean = acc * (1.0f / (float)cnt);
              ushort_t hh = f2bf(mean);
              if (lane < F) {
                aggh[row][cur * F + lane] = hh;
                aggl[row][cur * F + lane] = f2bf(mean - bf2f(hh));
              }
            }
            cur = r; acc = 0.f; cnt = 0;
          }
          acc += v[u];
          cnt++;
        }
      }
    }
    if (cnt > 0) {
      float mean = acc * (1.0f / (float)cnt);
      ushort_t hh = f2bf(mean);
      if (lane < F) {
        aggh[row][cur * F + lane] = hh;
        aggl[row][cur * F + lane] = f2bf(mean - bf2f(hh));
      }
    }
    // self slot
    if (lane < F) {
      float sv = xin[(size_t)n * F + lane];
      if (APPLY_BN) sv = fmaxf(fmaf(sv, scr, shr), 0.f);
      ushort_t hh = f2bf(sv);
      aggh[row][8 * F + lane] = hh;
      aggl[row][8 * F + lane] = f2bf(sv - bf2f(hh));
    }
  }
  __syncthreads();

  // ---- phase B ----
  int m16 = lane & 15, q = lane >> 4;
  int col = w * 16 + m16;
  const ushort_t* bp = wtT + (size_t)col * KT + q * 8;
  f32x4 acc4 = (f32x4){0.f, 0.f, 0.f, 0.f};
  #pragma unroll
  for (int ks = 0; ks < KT / 32; ks++) {
    short8 ah = *(const short8*)&aggh[m16][ks * 32 + q * 8];
    short8 al = *(const short8*)&aggl[m16][ks * 32 + q * 8];
    short8 bb = *(const short8*)(bp + ks * 32);
    acc4 = __builtin_amdgcn_mfma_f32_16x16x32_bf16(ah, bb, acc4, 0, 0, 0);
    acc4 = __builtin_amdgcn_mfma_f32_16x16x32_bf16(al, bb, acc4, 0, 0, 0);
  }
  float bcol = bias[col];
  float s = 0.f, ss = 0.f;
  #pragma unroll
  for (int j = 0; j < 4; j++) {
    int node = nbase + q * 4 + j;  // C/D: col=lane&15, row=(lane>>4)*4+reg
    float d = acc4[j] + bcol;
    outp[(size_t)node * HD + col] = d;
    s += d;
    ss += d * d;
  }
  s += __shfl_xor(s, 16); s += __shfl_xor(s, 32);
  ss += __shfl_xor(ss, 16); ss += __shfl_xor(ss, 32);
  if (q == 0) {
    int rp = blockIdx.x & (RREP - 1);
    atomicAdd(&statsrep[rp * 128 + col], s);
    atomicAdd(&statsrep[rp * 128 + 64 + col], ss);
  }
}

// reduce stat replicas -> BN (scale, shift)
__global__ void k_finstats(const float* __restrict__ rep, const float* __restrict__ g,
                           const float* __restrict__ b, float* __restrict__ scsh) {
  int lane = threadIdx.x;  // 64
  float s = 0.f, ss = 0.f;
  for (int rp = 0; rp < RREP; rp++) {
    s += rep[rp * 128 + lane];
    ss += rep[rp * 128 + 64 + lane];
  }
  float mu = s * (1.0f / NN);
  float var = ss * (1.0f / NN) - mu * mu;
  float sc = g[lane] * rsqrtf(var + BN_EPS);
  scsh[lane] = sc;
  scsh[64 + lane] = b[lane] - mu * sc;
}

// sorted-batch segmented pooling over RAW layer outputs with inline BN+ReLU.
__global__ void k_poolseg(const float* __restrict__ t1, const float* __restrict__ t2,
                          const float* __restrict__ t3, const float* __restrict__ scsh,
                          const int* __restrict__ batch, float* __restrict__ psum,
                          unsigned* __restrict__ pmax, float* __restrict__ cntg) {
  __shared__ int bsh[PCH];
  int base = blockIdx.x * PCH;
  int c = threadIdx.x;  // 0..191
  for (int i = c; i < PCH; i += 192) bsh[i] = batch[base + i];
  __syncthreads();
  int L = c >> 6, cc = c & 63;
  const float* xs = (L == 0) ? t1 : (L == 1) ? t2 : t3;
  float sc = scsh[L * 128 + cc], sh = scsh[L * 128 + 64 + cc];
  int cur = bsh[0];
  float sum = 0.0f, mx = 0.0f;
  int runlen = 0;
  #pragma unroll 4
  for (int i = 0; i < PCH; i++) {
    int g = bsh[i];
    float v = fmaxf(fmaf(xs[(size_t)(base + i) * 64 + cc], sc, sh), 0.0f);
    if (g != cur) {  // wave-uniform, rare
      atomicAdd(&psum[cur * 192 + c], sum);
      atomicMax(&pmax[cur * 192 + c], __float_as_uint(mx));
      if (c == 0) atomicAdd(&cntg[cur], (float)runlen);
      cur = g; sum = 0.0f; mx = 0.0f; runlen = 0;
    }
    sum += v;
    mx = fmaxf(mx, v);
    runlen++;
  }
  atomicAdd(&psum[cur * 192 + c], sum);
  atomicMax(&pmax[cur * 192 + c], __float_as_uint(mx));
  if (c == 0) atomicAdd(&cntg[cur], (float)runlen);
}

__global__ void k_fc1(const float* __restrict__ psum, const unsigned* __restrict__ pmax,
                      const float* __restrict__ cntg, const float* __restrict__ w,
                      const float* __restrict__ bias, float* __restrict__ h1) {
  __shared__ float a[384];
  int g = blockIdx.x;
  float ic = 1.0f / fmaxf(cntg[g], 1.0f);
  for (int c = threadIdx.x; c < 384; c += 128) {
    a[c] = (c < 192) ? psum[g * 192 + c] * ic : __uint_as_float(pmax[g * 192 + (c - 192)]);
  }
  __syncthreads();
  int j = threadIdx.x;
  float acc = bias[j];
  for (int k = 0; k < 384; k++) acc = fmaf(a[k], w[k * 128 + j], acc);
  h1[g * 128 + j] = acc;
}

__global__ void k_fcbn_stats(const float* __restrict__ h1, const float* __restrict__ g,
                             const float* __restrict__ b, float* __restrict__ scsh) {
  __shared__ float sr[512], ssr[512];
  int j = threadIdx.x & 127, q = threadIdx.x >> 7;
  float s = 0.f, ss = 0.f;
  for (int i = q * 64; i < q * 64 + 64; i++) {
    float v = h1[i * 128 + j];
    s += v;
    ss = fmaf(v, v, ss);
  }
  sr[threadIdx.x] = s;
  ssr[threadIdx.x] = ss;
  __syncthreads();
  if (q == 0) {
    s = sr[j] + sr[128 + j] + sr[256 + j] + sr[384 + j];
    ss = ssr[j] + ssr[128 + j] + ssr[256 + j] + ssr[384 + j];
    float mu = s * (1.0f / NG);
    float var = ss * (1.0f / NG) - mu * mu;
    float sc = g[j] * rsqrtf(var + BN_EPS);
    scsh[j] = sc;
    scsh[128 + j] = b[j] - mu * sc;
  }
}

__global__ void k_leaky(float* __restrict__ h1, const float* __restrict__ scsh) {
  int j = threadIdx.x;
  int g = blockIdx.x;
  float v = fmaf(h1[g * 128 + j], scsh[j], scsh[128 + j]);
  h1[g * 128 + j] = v > 0.0f ? v : 0.2f * v;
}

__global__ void k_head(const float* __restrict__ h1, const float* __restrict__ fc2w,
                       const float* __restrict__ fc2b, const float* __restrict__ d1w,
                       const float* __restrict__ d1b, const float* __restrict__ d2w,
                       const float* __restrict__ d2b, float* __restrict__ out) {
  __shared__ float emb[16];
  int g = blockIdx.x;
  int t = threadIdx.x;  // 0..63
  if (t < 16) {
    float acc = fc2b[t];
    for (int k = 0; k < 128; k++) acc = fmaf(h1[g * 128 + k], fc2w[k * 16 + t], acc);
    emb[t] = acc;
    out[NG + g * 16 + t] = acc;
  }
  __syncthreads();
  float acc = d1b[t];
  for (int k = 0; k < 16; k++) acc = fmaf(emb[k], d1w[k * 64 + t], acc);
  acc = acc > 0.0f ? acc : 0.2f * acc;
  float p = acc * d2w[t];
  for (int off = 32; off > 0; off >>= 1) p += __shfl_down(p, off);
  if (t == 0) out[g] = p + d2b[0];
}

extern "C" void kernel_launch(void* const* d_in, const int* in_sizes, int n_in,
                              void* d_out, int out_size, void* d_ws, size_t ws_size,
                              hipStream_t stream) {
  const float* x    = (const float*)d_in[0];
  const int*   ei   = (const int*)d_in[1];
  const int*   ety  = (const int*)d_in[2];
  const int*   batch= (const int*)d_in[3];
  const float* c1w  = (const float*)d_in[4];
  const float* c1r  = (const float*)d_in[5];
  const float* c1b  = (const float*)d_in[6];
  const float* bn1g = (const float*)d_in[7];
  const float* bn1b = (const float*)d_in[8];
  const float* c2w  = (const float*)d_in[9];
  const float* c2r  = (const float*)d_in[10];
  const float* c2b  = (const float*)d_in[11];
  const float* bn2g = (const float*)d_in[12];
  const float* bn2b = (const float*)d_in[13];
  const float* c3w  = (const float*)d_in[14];
  const float* c3r  = (const float*)d_in[15];
  const float* c3b  = (const float*)d_in[16];
  const float* bn3g = (const float*)d_in[17];
  const float* bn3b = (const float*)d_in[18];
  const float* fc1w = (const float*)d_in[19];
  const float* fc1b = (const float*)d_in[20];
  const float* fbg  = (const float*)d_in[21];
  const float* fbb  = (const float*)d_in[22];
  const float* fc2w = (const float*)d_in[23];
  const float* fc2b = (const float*)d_in[24];
  const float* d1w  = (const float*)d_in[25];
  const float* d1b  = (const float*)d_in[26];
  const float* d2w  = (const float*)d_in[27];
  const float* d2b  = (const float*)d_in[28];
  const int* esrc = ei;
  const int* edst = ei + NE;
  float* out = (float*)d_out;

  float* W = (float*)d_ws;
  size_t o = 0;
  auto alloc = [&](size_t n) { float* p = W + o; o += (n + 63) & ~(size_t)63; return p; };
  unsigned* cnt      = (unsigned*)alloc(M_KEYS);
  float*    psum     = alloc(NG * 192);
  unsigned* pmax     = (unsigned*)alloc(NG * 192);
  float*    cntg     = alloc(NG);
  float*    statsrep = alloc(3 * RREP * 128);
  size_t zone = o;  // buffers [0, zone) zeroed every call
  int*      rowstart = (int*)alloc(M_KEYS + 1);
  int*      rank = (int*)alloc(NE);
  int*      ebuf = (int*)alloc(NE);
  unsigned* bsum = (unsigned*)alloc(1024);
  unsigned* boff = (unsigned*)alloc(1024);
  float*    scsh = alloc(3 * 128);
  float*    fcsc = alloc(256);
  float*    h1   = alloc(NG * 128);
  float*    tmp1 = alloc((size_t)NN * HD);
  float*    tmp2 = alloc((size_t)NN * HD);
  float*    tmp3 = alloc((size_t)NN * HD);
  ushort_t* wt1  = (ushort_t*)alloc(64 * 9 * FIN / 2);
  ushort_t* wt2  = (ushort_t*)alloc(64 * 9 * HD / 2);
  ushort_t* wt3  = (ushort_t*)alloc(64 * 9 * HD / 2);
  (void)ws_size; (void)in_sizes; (void)n_in; (void)out_size;

  // ---- preprocess: (dst,rel)-keyed CSR with rel packed into entries ----
  k_zero<<<(int)((zone + 255) / 256), 256, 0, stream>>>(W, (int)zone);
  k_cnt<<<(NE + 255) / 256, 256, 0, stream>>>(edst, ety, cnt, rank);
  k_scanA<<<NB, 256, 0, stream>>>(cnt, bsum);
  k_scanB<<<1, 1024, 0, stream>>>(bsum, boff, rowstart);
  k_scanC<<<NB, 256, 0, stream>>>(cnt, boff, rowstart);
  k_place<<<(NE + 255) / 256, 256, 0, stream>>>(esrc, edst, ety, rank, rowstart, ebuf);
  k_wconv<FIN><<<(64 * 9 * FIN + 255) / 256, 256, 0, stream>>>(c1w, c1r, wt1);
  k_wconv<HD><<<(64 * 9 * HD + 255) / 256, 256, 0, stream>>>(c2w, c2r, wt2);
  k_wconv<HD><<<(64 * 9 * HD + 255) / 256, 256, 0, stream>>>(c3w, c3r, wt3);

  // ---- fused aggregate-first + MFMA layers ----
  k_fused<FIN, false><<<NN / 16, 256, 0, stream>>>(
      x, nullptr, rowstart, ebuf, wt1, c1b, tmp1, statsrep);
  k_finstats<<<1, 64, 0, stream>>>(statsrep, bn1g, bn1b, scsh);
  k_fused<HD, true><<<NN / 16, 256, 0, stream>>>(
      tmp1, scsh, rowstart, ebuf, wt2, c2b, tmp2, statsrep + RREP * 128);
  k_finstats<<<1, 64, 0, stream>>>(statsrep + RREP * 128, bn2g, bn2b, scsh + 128);
  k_fused<HD, true><<<NN / 16, 256, 0, stream>>>(
      tmp2, scsh + 128, rowstart, ebuf, wt3, c3b, tmp3, statsrep + 2 * RREP * 128);
  k_finstats<<<1, 64, 0, stream>>>(statsrep + 2 * RREP * 128, bn3g, bn3b, scsh + 256);

  // ---- pooling + head ----
  k_poolseg<<<NN / PCH, 192, 0, stream>>>(tmp1, tmp2, tmp3, scsh, batch, psum, pmax, cntg);
  k_fc1<<<NG, 128, 0, stream>>>(psum, pmax, cntg, fc1w, fc1b, h1);
  k_fcbn_stats<<<1, 512, 0, stream>>>(h1, fbg, fbb, fcsc);
  k_leaky<<<NG, 128, 0, stream>>>(h1, fcsc);
  k_head<<<NG, 64, 0, stream>>>(h1, fc2w, fc2b, d1w, d1b, d2w, d2b, out);
}

// Round 8
// 614.719 us; speedup vs baseline: 3.6576x; 1.1821x over previous
//
#include <hip/hip_runtime.h>

#define NN 100000
#define NE 1250000
#define FIN 32
#define HD 64
#define NR 8
#define NG 256
#define BN_EPS 1e-5f
#define PCH 100          // nodes per pooling block (divides NN)
#define M_KEYS (NN * NR) // 800000 (dst,rel) segments
#define NB 782           // scan blocks: 782*1024 >= 800000
#define RREP 32          // BN-stat atomic replicas

typedef unsigned short ushort_t;
typedef __attribute__((ext_vector_type(8))) short short8;
typedef __attribute__((ext_vector_type(4))) float f32x4;

static __device__ __forceinline__ ushort_t f2bf(float f) {
  unsigned u = __float_as_uint(f);
  u += 0x7fffu + ((u >> 16) & 1u);  // RNE
  return (ushort_t)(u >> 16);
}
static __device__ __forceinline__ float bf2f(ushort_t b) {
  return __uint_as_float((unsigned)b << 16);
}

__global__ void k_zero(float* __restrict__ p, int n) {
  int i = blockIdx.x * 256 + threadIdx.x;
  if (i < n) p[i] = 0.0f;
}

// pass 1: per-(dst,rel) counts + per-edge rank
__global__ void k_cnt(const int* __restrict__ dst, const int* __restrict__ ty,
                      unsigned* __restrict__ cnt, int* __restrict__ rank) {
  int e = blockIdx.x * 256 + threadIdx.x;
  if (e < NE) {
    int key = dst[e] * NR + ty[e];
    rank[e] = (int)atomicAdd(&cnt[key], 1u);
  }
}

// hierarchical exclusive scan of cnt[M_KEYS] -> rowstart[M_KEYS+1]
__global__ void k_scanA(const unsigned* __restrict__ cnt, unsigned* __restrict__ bsum) {
  __shared__ unsigned red[256];
  int t = threadIdx.x;
  int base = blockIdx.x * 1024 + t * 4;
  unsigned s = 0;
  #pragma unroll
  for (int i = 0; i < 4; i++) {
    int idx = base + i;
    if (idx < M_KEYS) s += cnt[idx];
  }
  red[t] = s;
  __syncthreads();
  for (int off = 128; off > 0; off >>= 1) {
    if (t < off) red[t] += red[t + off];
    __syncthreads();
  }
  if (t == 0) bsum[blockIdx.x] = red[0];
}

__global__ __launch_bounds__(1024) void k_scanB(const unsigned* __restrict__ bsum,
                                                unsigned* __restrict__ boff,
                                                int* __restrict__ rowstart) {
  __shared__ unsigned sb[1024];
  int t = threadIdx.x;
  unsigned mine = (t < NB) ? bsum[t] : 0u;
  sb[t] = mine;
  __syncthreads();
  for (int off = 1; off < 1024; off <<= 1) {
    unsigned v = (t >= off) ? sb[t - off] : 0u;
    __syncthreads();
    sb[t] += v;
    __syncthreads();
  }
  if (t < NB) boff[t] = sb[t] - mine;
  if (t == 1023) rowstart[M_KEYS] = (int)sb[1023];
}

__global__ void k_scanC(const unsigned* __restrict__ cnt, const unsigned* __restrict__ boff,
                        int* __restrict__ rowstart) {
  __shared__ unsigned sb[256];
  int t = threadIdx.x;
  int base = blockIdx.x * 1024 + t * 4;
  unsigned c0 = (base + 0 < M_KEYS) ? cnt[base + 0] : 0u;
  unsigned c1 = (base + 1 < M_KEYS) ? cnt[base + 1] : 0u;
  unsigned c2 = (base + 2 < M_KEYS) ? cnt[base + 2] : 0u;
  unsigned c3 = (base + 3 < M_KEYS) ? cnt[base + 3] : 0u;
  unsigned tot = c0 + c1 + c2 + c3;
  sb[t] = tot;
  __syncthreads();
  for (int off = 1; off < 256; off <<= 1) {
    unsigned v = (t >= off) ? sb[t - off] : 0u;
    __syncthreads();
    sb[t] += v;
    __syncthreads();
  }
  unsigned run = boff[blockIdx.x] + (sb[t] - tot);
  if (base + 0 < M_KEYS) rowstart[base + 0] = (int)run; run += c0;
  if (base + 1 < M_KEYS) rowstart[base + 1] = (int)run; run += c1;
  if (base + 2 < M_KEYS) rowstart[base + 2] = (int)run; run += c2;
  if (base + 3 < M_KEYS) rowstart[base + 3] = (int)run;
}

// pass 2: place (src | rel<<20) into (dst,rel)-CSR
__global__ void k_place(const int* __restrict__ src, const int* __restrict__ dst,
                        const int* __restrict__ ty, const int* __restrict__ rank,
                        const int* __restrict__ rowstart, int* __restrict__ ebuf) {
  int e = blockIdx.x * 256 + threadIdx.x;
  if (e < NE) {
    int t = ty[e];
    int key = dst[e] * NR + t;
    ebuf[rowstart[key] + rank[e]] = src[e] | (t << 20);
  }
}

// wtT[c][k] bf16, c<64 output cols, k<9F: [W_0..W_7 | root] transposed so
// each MFMA B-fragment is a contiguous short8.
template <int F>
__global__ void k_wconv(const float* __restrict__ convw, const float* __restrict__ root,
                        ushort_t* __restrict__ wtT) {
  constexpr int KT = 9 * F;
  int i = blockIdx.x * 256 + threadIdx.x;  // over 64*KT
  if (i >= 64 * KT) return;
  int c = i / KT, k = i % KT;
  float v = (k < 8 * F) ? convw[(size_t)k * 64 + c] : root[(size_t)(k - 8 * F) * 64 + c];
  wtT[i] = f2bf(v);
}

// xbf = bf16(BNReLU(xin)) — the gather-side feature array (halves gather bytes,
// removes BN math from the hot loop)
template <int F, bool APPLY_BN>
__global__ void k_tobf(const float* __restrict__ xin, const float* __restrict__ scsh,
                       ushort_t* __restrict__ xbf) {
  int i = blockIdx.x * 256 + threadIdx.x;  // over NN*F (exact multiple of 256)
  int k = i & (F - 1);
  float v = xin[i];
  if (APPLY_BN) v = fmaxf(fmaf(v, scsh[k], scsh[64 + k]), 0.0f);
  xbf[i] = f2bf(v);
}

// Fused RGCN layer, aggregate-first + MFMA:
// Phase A (per wave: 4 nodes): walk the node's (dst,rel)-sorted edge list,
//   register-accumulate per rel-run gathering bf16 rows (128B/edge), flush
//   mean as bf16 into LDS agg rows. Self row in slot 8.
// Phase B (per wave: 16 output cols): 16x16x32 MFMA over K=9F, A from LDS,
//   B from L2-hot wtT. Epilogue: +bias, store f32, BN column stats.
// LDS ~18.7KB (hi-only) -> 8 blocks/CU.
template <int F>
__global__ __launch_bounds__(256) void k_fused(
    const ushort_t* __restrict__ xbf, const int* __restrict__ rs,
    const int* __restrict__ ebuf, const ushort_t* __restrict__ wtT,
    const float* __restrict__ bias, float* __restrict__ outp,
    float* __restrict__ statsrep) {
  constexpr int KT = 9 * F;
  constexpr int LDW = KT + 8;  // pad to spread banks across rows
  __shared__ ushort_t aggh[16][LDW];
  int lane = threadIdx.x & 63, w = threadIdx.x >> 6;
  int w4 = w * 4;
  int nbase = blockIdx.x * 16;

  // zero own 4 rows
  {
    uint* zh = (uint*)&aggh[w4][0];
    for (int i = lane; i < 2 * LDW; i += 64) zh[i] = 0u;
  }

  // ---- phase A ----
  for (int j = 0; j < 4; j++) {
    int n = nbase + w4 + j;
    int row = w4 + j;
    int lo = rs[n * NR], hi = rs[n * NR + NR];
    float acc = 0.f;
    int cur = -1, cnt = 0;
    for (int e = lo; e < hi; e += 8) {
      int m = hi - e;  // wave-uniform
      int pk[8]; float v[8];
      #pragma unroll
      for (int u = 0; u < 8; u++) pk[u] = (u < m) ? ebuf[e + u] : 0;
      #pragma unroll
      for (int u = 0; u < 8; u++)
        v[u] = (u < m && lane < F) ? bf2f(xbf[(size_t)(pk[u] & 0xFFFFF) * F + lane]) : 0.f;
      #pragma unroll
      for (int u = 0; u < 8; u++) {
        if (u < m) {  // wave-uniform
          int r = pk[u] >> 20;
          if (r != cur) {
            if (cnt > 0 && lane < F)
              aggh[row][cur * F + lane] = f2bf(acc * (1.0f / (float)cnt));
            cur = r; acc = 0.f; cnt = 0;
          }
          acc += v[u];
          cnt++;
        }
      }
    }
    if (cnt > 0 && lane < F)
      aggh[row][cur * F + lane] = f2bf(acc * (1.0f / (float)cnt));
    // self slot
    if (lane < F)
      aggh[row][8 * F + lane] = xbf[(size_t)n * F + lane];
  }
  __syncthreads();

  // ---- phase B ----
  int m16 = lane & 15, q = lane >> 4;
  int col = w * 16 + m16;
  const ushort_t* bp = wtT + (size_t)col * KT + q * 8;
  f32x4 acc4 = (f32x4){0.f, 0.f, 0.f, 0.f};
  #pragma unroll
  for (int ks = 0; ks < KT / 32; ks++) {
    short8 ah = *(const short8*)&aggh[m16][ks * 32 + q * 8];
    short8 bb = *(const short8*)(bp + ks * 32);
    acc4 = __builtin_amdgcn_mfma_f32_16x16x32_bf16(ah, bb, acc4, 0, 0, 0);
  }
  float bcol = bias[col];
  float s = 0.f, ss = 0.f;
  #pragma unroll
  for (int j = 0; j < 4; j++) {
    int node = nbase + q * 4 + j;  // C/D: col=lane&15, row=(lane>>4)*4+reg
    float d = acc4[j] + bcol;
    outp[(size_t)node * HD + col] = d;
    s += d;
    ss += d * d;
  }
  s += __shfl_xor(s, 16); s += __shfl_xor(s, 32);
  ss += __shfl_xor(ss, 16); ss += __shfl_xor(ss, 32);
  if (q == 0) {
    int rp = blockIdx.x & (RREP - 1);
    atomicAdd(&statsrep[rp * 128 + col], s);
    atomicAdd(&statsrep[rp * 128 + 64 + col], ss);
  }
}

// reduce stat replicas -> BN (scale, shift)
__global__ void k_finstats(const float* __restrict__ rep, const float* __restrict__ g,
                           const float* __restrict__ b, float* __restrict__ scsh) {
  int lane = threadIdx.x;  // 64
  float s = 0.f, ss = 0.f;
  for (int rp = 0; rp < RREP; rp++) {
    s += rep[rp * 128 + lane];
    ss += rep[rp * 128 + 64 + lane];
  }
  float mu = s * (1.0f / NN);
  float var = ss * (1.0f / NN) - mu * mu;
  float sc = g[lane] * rsqrtf(var + BN_EPS);
  scsh[lane] = sc;
  scsh[64 + lane] = b[lane] - mu * sc;
}

// sorted-batch segmented pooling over RAW layer outputs with inline BN+ReLU.
__global__ void k_poolseg(const float* __restrict__ t1, const float* __restrict__ t2,
                          const float* __restrict__ t3, const float* __restrict__ scsh,
                          const int* __restrict__ batch, float* __restrict__ psum,
                          unsigned* __restrict__ pmax, float* __restrict__ cntg) {
  __shared__ int bsh[PCH];
  int base = blockIdx.x * PCH;
  int c = threadIdx.x;  // 0..191
  for (int i = c; i < PCH; i += 192) bsh[i] = batch[base + i];
  __syncthreads();
  int L = c >> 6, cc = c & 63;
  const float* xs = (L == 0) ? t1 : (L == 1) ? t2 : t3;
  float sc = scsh[L * 128 + cc], sh = scsh[L * 128 + 64 + cc];
  int cur = bsh[0];
  float sum = 0.0f, mx = 0.0f;
  int runlen = 0;
  #pragma unroll 4
  for (int i = 0; i < PCH; i++) {
    int g = bsh[i];
    float v = fmaxf(fmaf(xs[(size_t)(base + i) * 64 + cc], sc, sh), 0.0f);
    if (g != cur) {  // wave-uniform, rare
      atomicAdd(&psum[cur * 192 + c], sum);
      atomicMax(&pmax[cur * 192 + c], __float_as_uint(mx));
      if (c == 0) atomicAdd(&cntg[cur], (float)runlen);
      cur = g; sum = 0.0f; mx = 0.0f; runlen = 0;
    }
    sum += v;
    mx = fmaxf(mx, v);
    runlen++;
  }
  atomicAdd(&psum[cur * 192 + c], sum);
  atomicMax(&pmax[cur * 192 + c], __float_as_uint(mx));
  if (c == 0) atomicAdd(&cntg[cur], (float)runlen);
}

__global__ void k_fc1(const float* __restrict__ psum, const unsigned* __restrict__ pmax,
                      const float* __restrict__ cntg, const float* __restrict__ w,
                      const float* __restrict__ bias, float* __restrict__ h1) {
  __shared__ float a[384];
  int g = blockIdx.x;
  float ic = 1.0f / fmaxf(cntg[g], 1.0f);
  for (int c = threadIdx.x; c < 384; c += 128) {
    a[c] = (c < 192) ? psum[g * 192 + c] * ic : __uint_as_float(pmax[g * 192 + (c - 192)]);
  }
  __syncthreads();
  int j = threadIdx.x;
  float acc = bias[j];
  for (int k = 0; k < 384; k++) acc = fmaf(a[k], w[k * 128 + j], acc);
  h1[g * 128 + j] = acc;
}

__global__ void k_fcbn_stats(const float* __restrict__ h1, const float* __restrict__ g,
                             const float* __restrict__ b, float* __restrict__ scsh) {
  __shared__ float sr[512], ssr[512];
  int j = threadIdx.x & 127, q = threadIdx.x >> 7;
  float s = 0.f, ss = 0.f;
  for (int i = q * 64; i < q * 64 + 64; i++) {
    float v = h1[i * 128 + j];
    s += v;
    ss = fmaf(v, v, ss);
  }
  sr[threadIdx.x] = s;
  ssr[threadIdx.x] = ss;
  __syncthreads();
  if (q == 0) {
    s = sr[j] + sr[128 + j] + sr[256 + j] + sr[384 + j];
    ss = ssr[j] + ssr[128 + j] + ssr[256 + j] + ssr[384 + j];
    float mu = s * (1.0f / NG);
    float var = ss * (1.0f / NG) - mu * mu;
    float sc = g[j] * rsqrtf(var + BN_EPS);
    scsh[j] = sc;
    scsh[128 + j] = b[j] - mu * sc;
  }
}

__global__ void k_leaky(float* __restrict__ h1, const float* __restrict__ scsh) {
  int j = threadIdx.x;
  int g = blockIdx.x;
  float v = fmaf(h1[g * 128 + j], scsh[j], scsh[128 + j]);
  h1[g * 128 + j] = v > 0.0f ? v : 0.2f * v;
}

__global__ void k_head(const float* __restrict__ h1, const float* __restrict__ fc2w,
                       const float* __restrict__ fc2b, const float* __restrict__ d1w,
                       const float* __restrict__ d1b, const float* __restrict__ d2w,
                       const float* __restrict__ d2b, float* __restrict__ out) {
  __shared__ float emb[16];
  int g = blockIdx.x;
  int t = threadIdx.x;  // 0..63
  if (t < 16) {
    float acc = fc2b[t];
    for (int k = 0; k < 128; k++) acc = fmaf(h1[g * 128 + k], fc2w[k * 16 + t], acc);
    emb[t] = acc;
    out[NG + g * 16 + t] = acc;
  }
  __syncthreads();
  float acc = d1b[t];
  for (int k = 0; k < 16; k++) acc = fmaf(emb[k], d1w[k * 64 + t], acc);
  acc = acc > 0.0f ? acc : 0.2f * acc;
  float p = acc * d2w[t];
  for (int off = 32; off > 0; off >>= 1) p += __shfl_down(p, off);
  if (t == 0) out[g] = p + d2b[0];
}

extern "C" void kernel_launch(void* const* d_in, const int* in_sizes, int n_in,
                              void* d_out, int out_size, void* d_ws, size_t ws_size,
                              hipStream_t stream) {
  const float* x    = (const float*)d_in[0];
  const int*   ei   = (const int*)d_in[1];
  const int*   ety  = (const int*)d_in[2];
  const int*   batch= (const int*)d_in[3];
  const float* c1w  = (const float*)d_in[4];
  const float* c1r  = (const float*)d_in[5];
  const float* c1b  = (const float*)d_in[6];
  const float* bn1g = (const float*)d_in[7];
  const float* bn1b = (const float*)d_in[8];
  const float* c2w  = (const float*)d_in[9];
  const float* c2r  = (const float*)d_in[10];
  const float* c2b  = (const float*)d_in[11];
  const float* bn2g = (const float*)d_in[12];
  const float* bn2b = (const float*)d_in[13];
  const float* c3w  = (const float*)d_in[14];
  const float* c3r  = (const float*)d_in[15];
  const float* c3b  = (const float*)d_in[16];
  const float* bn3g = (const float*)d_in[17];
  const float* bn3b = (const float*)d_in[18];
  const float* fc1w = (const float*)d_in[19];
  const float* fc1b = (const float*)d_in[20];
  const float* fbg  = (const float*)d_in[21];
  const float* fbb  = (const float*)d_in[22];
  const float* fc2w = (const float*)d_in[23];
  const float* fc2b = (const float*)d_in[24];
  const float* d1w  = (const float*)d_in[25];
  const float* d1b  = (const float*)d_in[26];
  const float* d2w  = (const float*)d_in[27];
  const float* d2b  = (const float*)d_in[28];
  const int* esrc = ei;
  const int* edst = ei + NE;
  float* out = (float*)d_out;

  float* W = (float*)d_ws;
  size_t o = 0;
  auto alloc = [&](size_t n) { float* p = W + o; o += (n + 63) & ~(size_t)63; return p; };
  unsigned* cnt      = (unsigned*)alloc(M_KEYS);
  float*    psum     = alloc(NG * 192);
  unsigned* pmax     = (unsigned*)alloc(NG * 192);
  float*    cntg     = alloc(NG);
  float*    statsrep = alloc(3 * RREP * 128);
  size_t zone = o;  // buffers [0, zone) zeroed every call
  int*      rowstart = (int*)alloc(M_KEYS + 1);
  int*      rank = (int*)alloc(NE);
  int*      ebuf = (int*)alloc(NE);
  unsigned* bsum = (unsigned*)alloc(1024);
  unsigned* boff = (unsigned*)alloc(1024);
  float*    scsh = alloc(3 * 128);
  float*    fcsc = alloc(256);
  float*    h1   = alloc(NG * 128);
  float*    tmp1 = alloc((size_t)NN * HD);
  float*    tmp2 = alloc((size_t)NN * HD);
  float*    tmp3 = alloc((size_t)NN * HD);
  ushort_t* xbf  = (ushort_t*)alloc((size_t)NN * HD / 2);
  ushort_t* wt1  = (ushort_t*)alloc(64 * 9 * FIN / 2);
  ushort_t* wt2  = (ushort_t*)alloc(64 * 9 * HD / 2);
  ushort_t* wt3  = (ushort_t*)alloc(64 * 9 * HD / 2);
  (void)ws_size; (void)in_sizes; (void)n_in; (void)out_size;

  // ---- preprocess: (dst,rel)-keyed CSR with rel packed into entries ----
  k_zero<<<(int)((zone + 255) / 256), 256, 0, stream>>>(W, (int)zone);
  k_cnt<<<(NE + 255) / 256, 256, 0, stream>>>(edst, ety, cnt, rank);
  k_scanA<<<NB, 256, 0, stream>>>(cnt, bsum);
  k_scanB<<<1, 1024, 0, stream>>>(bsum, boff, rowstart);
  k_scanC<<<NB, 256, 0, stream>>>(cnt, boff, rowstart);
  k_place<<<(NE + 255) / 256, 256, 0, stream>>>(esrc, edst, ety, rank, rowstart, ebuf);
  k_wconv<FIN><<<(64 * 9 * FIN + 255) / 256, 256, 0, stream>>>(c1w, c1r, wt1);
  k_wconv<HD><<<(64 * 9 * HD + 255) / 256, 256, 0, stream>>>(c2w, c2r, wt2);
  k_wconv<HD><<<(64 * 9 * HD + 255) / 256, 256, 0, stream>>>(c3w, c3r, wt3);

  // ---- fused aggregate-first + MFMA layers ----
  k_tobf<FIN, false><<<NN * FIN / 256, 256, 0, stream>>>(x, nullptr, xbf);
  k_fused<FIN><<<NN / 16, 256, 0, stream>>>(xbf, rowstart, ebuf, wt1, c1b, tmp1, statsrep);
  k_finstats<<<1, 64, 0, stream>>>(statsrep, bn1g, bn1b, scsh);

  k_tobf<HD, true><<<NN * HD / 256, 256, 0, stream>>>(tmp1, scsh, xbf);
  k_fused<HD><<<NN / 16, 256, 0, stream>>>(xbf, rowstart, ebuf, wt2, c2b, tmp2, statsrep + RREP * 128);
  k_finstats<<<1, 64, 0, stream>>>(statsrep + RREP * 128, bn2g, bn2b, scsh + 128);

  k_tobf<HD, true><<<NN * HD / 256, 256, 0, stream>>>(tmp2, scsh + 128, xbf);
  k_fused<HD><<<NN / 16, 256, 0, stream>>>(xbf, rowstart, ebuf, wt3, c3b, tmp3, statsrep + 2 * RREP * 128);
  k_finstats<<<1, 64, 0, stream>>>(statsrep + 2 * RREP * 128, bn3g, bn3b, scsh + 256);

  // ---- pooling + head ----
  k_poolseg<<<NN / PCH, 192, 0, stream>>>(tmp1, tmp2, tmp3, scsh, batch, psum, pmax, cntg);
  k_fc1<<<NG, 128, 0, stream>>>(psum, pmax, cntg, fc1w, fc1b, h1);
  k_fcbn_stats<<<1, 512, 0, stream>>>(h1, fbg, fbb, fcsc);
  k_leaky<<<NG, 128, 0, stream>>>(h1, fcsc);
  k_head<<<NG, 64, 0, stream>>>(h1, fc2w, fc2b, d1w, d1b, d2w, d2b, out);
}

// Round 9
// 524.458 us; speedup vs baseline: 4.2871x; 1.1721x over previous
//
#include <hip/hip_runtime.h>

#define NN 100000
#define NE 1250000
#define FIN 32
#define HD 64
#define NR 8
#define NG 256
#define BN_EPS 1e-5f
#define PCH 100          // nodes per pooling block (divides NN)
#define M_KEYS (NN * NR) // 800000 (dst,rel) segments
#define NB 782           // scan blocks: 782*1024 >= 800000
#define RREP 32          // BN-stat atomic replicas
#define HW 576           // h width: 8 rel * 64 + root 64

typedef unsigned short ushort_t;
typedef __attribute__((ext_vector_type(8))) short short8;
typedef __attribute__((ext_vector_type(4))) float f32x4;

static __device__ __forceinline__ ushort_t f2bf(float f) {
  unsigned u = __float_as_uint(f);
  u += 0x7fffu + ((u >> 16) & 1u);  // RNE
  return (ushort_t)(u >> 16);
}
static __device__ __forceinline__ float bf2f(ushort_t b) {
  return __uint_as_float((unsigned)b << 16);
}

__global__ void k_zero(float* __restrict__ p, int n) {
  int i = blockIdx.x * 256 + threadIdx.x;
  if (i < n) p[i] = 0.0f;
}

// pass 1: per-(dst,rel) counts + per-edge rank
__global__ void k_cnt(const int* __restrict__ dst, const int* __restrict__ ty,
                      unsigned* __restrict__ cnt, int* __restrict__ rank) {
  int e = blockIdx.x * 256 + threadIdx.x;
  if (e < NE) {
    int key = dst[e] * NR + ty[e];
    rank[e] = (int)atomicAdd(&cnt[key], 1u);
  }
}

// hierarchical exclusive scan of cnt[M_KEYS] -> rowstart[M_KEYS+1]
__global__ void k_scanA(const unsigned* __restrict__ cnt, unsigned* __restrict__ bsum) {
  __shared__ unsigned red[256];
  int t = threadIdx.x;
  int base = blockIdx.x * 1024 + t * 4;
  unsigned s = 0;
  #pragma unroll
  for (int i = 0; i < 4; i++) {
    int idx = base + i;
    if (idx < M_KEYS) s += cnt[idx];
  }
  red[t] = s;
  __syncthreads();
  for (int off = 128; off > 0; off >>= 1) {
    if (t < off) red[t] += red[t + off];
    __syncthreads();
  }
  if (t == 0) bsum[blockIdx.x] = red[0];
}

__global__ __launch_bounds__(1024) void k_scanB(const unsigned* __restrict__ bsum,
                                                unsigned* __restrict__ boff,
                                                int* __restrict__ rowstart) {
  __shared__ unsigned sb[1024];
  int t = threadIdx.x;
  unsigned mine = (t < NB) ? bsum[t] : 0u;
  sb[t] = mine;
  __syncthreads();
  for (int off = 1; off < 1024; off <<= 1) {
    unsigned v = (t >= off) ? sb[t - off] : 0u;
    __syncthreads();
    sb[t] += v;
    __syncthreads();
  }
  if (t < NB) boff[t] = sb[t] - mine;
  if (t == 1023) rowstart[M_KEYS] = (int)sb[1023];
}

__global__ void k_scanC(const unsigned* __restrict__ cnt, const unsigned* __restrict__ boff,
                        int* __restrict__ rowstart) {
  __shared__ unsigned sb[256];
  int t = threadIdx.x;
  int base = blockIdx.x * 1024 + t * 4;
  unsigned c0 = (base + 0 < M_KEYS) ? cnt[base + 0] : 0u;
  unsigned c1 = (base + 1 < M_KEYS) ? cnt[base + 1] : 0u;
  unsigned c2 = (base + 2 < M_KEYS) ? cnt[base + 2] : 0u;
  unsigned c3 = (base + 3 < M_KEYS) ? cnt[base + 3] : 0u;
  unsigned tot = c0 + c1 + c2 + c3;
  sb[t] = tot;
  __syncthreads();
  for (int off = 1; off < 256; off <<= 1) {
    unsigned v = (t >= off) ? sb[t - off] : 0u;
    __syncthreads();
    sb[t] += v;
    __syncthreads();
  }
  unsigned run = boff[blockIdx.x] + (sb[t] - tot);
  if (base + 0 < M_KEYS) rowstart[base + 0] = (int)run; run += c0;
  if (base + 1 < M_KEYS) rowstart[base + 1] = (int)run; run += c1;
  if (base + 2 < M_KEYS) rowstart[base + 2] = (int)run; run += c2;
  if (base + 3 < M_KEYS) rowstart[base + 3] = (int)run;
}

// pass 2: place {h-offset, invcnt} records into (dst,rel)-CSR (8B/edge)
__global__ void k_place(const int* __restrict__ src, const int* __restrict__ dst,
                        const int* __restrict__ ty, const int* __restrict__ rank,
                        const int* __restrict__ rowstart, const unsigned* __restrict__ cnt,
                        int2* __restrict__ eb) {
  int e = blockIdx.x * 256 + threadIdx.x;
  if (e < NE) {
    int t = ty[e];
    int key = dst[e] * NR + t;
    float ic = 1.0f / (float)max(cnt[key], 1u);
    int2 v;
    v.x = src[e] * HW + t * 64;   // element offset into h
    v.y = __float_as_int(ic);
    eb[rowstart[key] + rank[e]] = v;
  }
}

// wt[c][k] bf16, c<576 output cols of [W_0..W_7 | root], k<F (transposed so
// each MFMA B-fragment is a contiguous short8).
template <int F>
__global__ void k_wconv(const float* __restrict__ convw, const float* __restrict__ root,
                        ushort_t* __restrict__ wt) {
  int i = blockIdx.x * 256 + threadIdx.x;  // over 576*F
  if (i >= 576 * F) return;
  int c = i / F, k = i % F;
  float v = (c < 512) ? convw[((size_t)(c >> 6) * F + k) * 64 + (c & 63)]
                      : root[(size_t)k * 64 + (c & 63)];
  wt[(size_t)c * F + k] = f2bf(v);
}

// xbf[n] = hi/lo bf16 split of BNReLU(x[n]): [n][0..F-1]=hi, [n][F..2F-1]=lo
template <int F, bool APPLY_BN>
__global__ void k_tobf(const float* __restrict__ xin, const float* __restrict__ scsh,
                       ushort_t* __restrict__ xbf) {
  int i = blockIdx.x * 256 + threadIdx.x;  // over NN*F
  int n = i / F, k = i % F;
  float v = xin[i];
  if (APPLY_BN) v = fmaxf(fmaf(v, scsh[k], scsh[64 + k]), 0.0f);
  ushort_t hi = f2bf(v);
  xbf[(size_t)n * (2 * F) + k] = hi;
  xbf[(size_t)n * (2 * F) + F + k] = f2bf(v - bf2f(hi));
}

// MFMA xform: h[16 rows x 576 cols per block] = xbf(hi+lo) @ wt.
// B frags register-resident (wt <=74KB, L2-hot); A frags direct from global.
template <int F>
__global__ __launch_bounds__(256) void k_xmm(const ushort_t* __restrict__ xbf,
                                             const ushort_t* __restrict__ wt,
                                             ushort_t* __restrict__ h) {
  constexpr int KK = 2 * F;
  int lane = threadIdx.x & 63;
  int w = threadIdx.x >> 6;
  int nbase = blockIdx.x * 16;
  int m = lane & 15;   // A row / B col within tile
  int q = lane >> 4;   // quad 0..3, k-offset q*8
  const ushort_t* xrow = xbf + (size_t)(nbase + m) * KK + q * 8;
  f32x4 acc[9];
  #pragma unroll
  for (int t = 0; t < 9; t++) acc[t] = (f32x4){0.f, 0.f, 0.f, 0.f};
  int ct0 = w * 9;
  #pragma unroll
  for (int ks = 0; ks < F / 32; ks++) {
    short8 ah = *(const short8*)(xrow + ks * 32);       // hi half
    short8 al = *(const short8*)(xrow + F + ks * 32);   // lo half
    #pragma unroll
    for (int t = 0; t < 9; t++) {
      const ushort_t* wp = wt + (size_t)((ct0 + t) * 16 + m) * F + ks * 32 + q * 8;
      short8 b = *(const short8*)wp;
      acc[t] = __builtin_amdgcn_mfma_f32_16x16x32_bf16(ah, b, acc[t], 0, 0, 0);
      acc[t] = __builtin_amdgcn_mfma_f32_16x16x32_bf16(al, b, acc[t], 0, 0, 0);
    }
  }
  #pragma unroll
  for (int t = 0; t < 9; t++) {
    int col = (ct0 + t) * 16 + m;
    #pragma unroll
    for (int j = 0; j < 4; j++) {
      int row = nbase + q * 4 + j;  // C/D: col=lane&15, row=(lane>>4)*4+reg
      h[(size_t)row * HW + col] = f2bf(acc[t][j]);
    }
  }
}

// 4-edges-per-instruction aggregation: wave = 1 node; lane groups of 16 each
// own one edge stream; each lane loads uint2 = 4 bf16 channels of its group's
// edge; flat acc += h * invcnt (no run logic); 2 shfl_xor combine at end.
// Epilogue: +self+bias, f32 store, BN column stats via LDS + replica atomics.
__global__ __launch_bounds__(256) void k_agg4(
    const ushort_t* __restrict__ h, const int* __restrict__ rs,
    const int2* __restrict__ eb, const float* __restrict__ bias,
    float* __restrict__ outp, float* __restrict__ statsrep) {
  __shared__ float red[512];
  int lane = threadIdx.x & 63, w = threadIdx.x >> 6;
  int n = blockIdx.x * 4 + w;
  int lo = rs[n * NR];
  int cnt = rs[n * NR + NR] - lo;
  int g = lane >> 4;          // edge group 0..3
  int c4 = (lane & 15) * 4;   // channel base
  float a0 = 0.f, a1 = 0.f, a2 = 0.f, a3 = 0.f;
  for (int base = 0; base < cnt; base += 16) {
    int2 eo[4];
    #pragma unroll
    for (int s = 0; s < 4; s++) {
      int el = base + s * 4 + g;
      int idx = lo + (el < cnt ? el : cnt - 1);
      eo[s] = eb[idx];
      if (el >= cnt) eo[s].y = 0;  // weight 0 for padding lanes
    }
    uint2 hv[4];
    #pragma unroll
    for (int s = 0; s < 4; s++)
      hv[s] = *(const uint2*)(h + (size_t)eo[s].x + c4);
    #pragma unroll
    for (int s = 0; s < 4; s++) {
      float ic = __int_as_float(eo[s].y);
      a0 = fmaf(__uint_as_float(hv[s].x << 16), ic, a0);
      a1 = fmaf(__uint_as_float(hv[s].x & 0xffff0000u), ic, a1);
      a2 = fmaf(__uint_as_float(hv[s].y << 16), ic, a2);
      a3 = fmaf(__uint_as_float(hv[s].y & 0xffff0000u), ic, a3);
    }
  }
  a0 += __shfl_xor(a0, 16); a0 += __shfl_xor(a0, 32);
  a1 += __shfl_xor(a1, 16); a1 += __shfl_xor(a1, 32);
  a2 += __shfl_xor(a2, 16); a2 += __shfl_xor(a2, 32);
  a3 += __shfl_xor(a3, 16); a3 += __shfl_xor(a3, 32);
  if (g == 0) {
    uint2 sv = *(const uint2*)(h + (size_t)n * HW + 512 + c4);
    float4 b4 = *(const float4*)(bias + c4);
    float d0 = a0 + __uint_as_float(sv.x << 16) + b4.x;
    float d1 = a1 + __uint_as_float(sv.x & 0xffff0000u) + b4.y;
    float d2 = a2 + __uint_as_float(sv.y << 16) + b4.z;
    float d3 = a3 + __uint_as_float(sv.y & 0xffff0000u) + b4.w;
    *(float4*)(outp + (size_t)n * HD + c4) = make_float4(d0, d1, d2, d3);
    *(float4*)(&red[w * 64 + c4]) = make_float4(d0, d1, d2, d3);
    *(float4*)(&red[256 + w * 64 + c4]) =
        make_float4(d0 * d0, d1 * d1, d2 * d2, d3 * d3);
  }
  __syncthreads();
  if (w == 0) {
    float ts = red[lane] + red[64 + lane] + red[128 + lane] + red[192 + lane];
    float tss = red[256 + lane] + red[320 + lane] + red[384 + lane] + red[448 + lane];
    int rp = blockIdx.x & (RREP - 1);
    atomicAdd(&statsrep[rp * 128 + lane], ts);
    atomicAdd(&statsrep[rp * 128 + 64 + lane], tss);
  }
}

// reduce stat replicas -> BN (scale, shift)
__global__ void k_finstats(const float* __restrict__ rep, const float* __restrict__ g,
                           const float* __restrict__ b, float* __restrict__ scsh) {
  int lane = threadIdx.x;  // 64
  float s = 0.f, ss = 0.f;
  for (int rp = 0; rp < RREP; rp++) {
    s += rep[rp * 128 + lane];
    ss += rep[rp * 128 + 64 + lane];
  }
  float mu = s * (1.0f / NN);
  float var = ss * (1.0f / NN) - mu * mu;
  float sc = g[lane] * rsqrtf(var + BN_EPS);
  scsh[lane] = sc;
  scsh[64 + lane] = b[lane] - mu * sc;
}

// sorted-batch segmented pooling over RAW layer outputs with inline BN+ReLU.
__global__ void k_poolseg(const float* __restrict__ t1, const float* __restrict__ t2,
                          const float* __restrict__ t3, const float* __restrict__ scsh,
                          const int* __restrict__ batch, float* __restrict__ psum,
                          unsigned* __restrict__ pmax, float* __restrict__ cntg) {
  __shared__ int bsh[PCH];
  int base = blockIdx.x * PCH;
  int c = threadIdx.x;  // 0..191
  for (int i = c; i < PCH; i += 192) bsh[i] = batch[base + i];
  __syncthreads();
  int L = c >> 6, cc = c & 63;
  const float* xs = (L == 0) ? t1 : (L == 1) ? t2 : t3;
  float sc = scsh[L * 128 + cc], sh = scsh[L * 128 + 64 + cc];
  int cur = bsh[0];
  float sum = 0.0f, mx = 0.0f;
  int runlen = 0;
  #pragma unroll 4
  for (int i = 0; i < PCH; i++) {
    int g = bsh[i];
    float v = fmaxf(fmaf(xs[(size_t)(base + i) * 64 + cc], sc, sh), 0.0f);
    if (g != cur) {  // wave-uniform, rare
      atomicAdd(&psum[cur * 192 + c], sum);
      atomicMax(&pmax[cur * 192 + c], __float_as_uint(mx));
      if (c == 0) atomicAdd(&cntg[cur], (float)runlen);
      cur = g; sum = 0.0f; mx = 0.0f; runlen = 0;
    }
    sum += v;
    mx = fmaxf(mx, v);
    runlen++;
  }
  atomicAdd(&psum[cur * 192 + c], sum);
  atomicMax(&pmax[cur * 192 + c], __float_as_uint(mx));
  if (c == 0) atomicAdd(&cntg[cur], (float)runlen);
}

__global__ void k_fc1(const float* __restrict__ psum, const unsigned* __restrict__ pmax,
                      const float* __restrict__ cntg, const float* __restrict__ w,
                      const float* __restrict__ bias, float* __restrict__ h1) {
  __shared__ float a[384];
  int g = blockIdx.x;
  float ic = 1.0f / fmaxf(cntg[g], 1.0f);
  for (int c = threadIdx.x; c < 384; c += 128) {
    a[c] = (c < 192) ? psum[g * 192 + c] * ic : __uint_as_float(pmax[g * 192 + (c - 192)]);
  }
  __syncthreads();
  int j = threadIdx.x;
  float acc = bias[j];
  for (int k = 0; k < 384; k++) acc = fmaf(a[k], w[k * 128 + j], acc);
  h1[g * 128 + j] = acc;
}

__global__ void k_fcbn_stats(const float* __restrict__ h1, const float* __restrict__ g,
                             const float* __restrict__ b, float* __restrict__ scsh) {
  __shared__ float sr[512], ssr[512];
  int j = threadIdx.x & 127, q = threadIdx.x >> 7;
  float s = 0.f, ss = 0.f;
  for (int i = q * 64; i < q * 64 + 64; i++) {
    float v = h1[i * 128 + j];
    s += v;
    ss = fmaf(v, v, ss);
  }
  sr[threadIdx.x] = s;
  ssr[threadIdx.x] = ss;
  __syncthreads();
  if (q == 0) {
    s = sr[j] + sr[128 + j] + sr[256 + j] + sr[384 + j];
    ss = ssr[j] + ssr[128 + j] + ssr[256 + j] + ssr[384 + j];
    float mu = s * (1.0f / NG);
    float var = ss * (1.0f / NG) - mu * mu;
    float sc = g[j] * rsqrtf(var + BN_EPS);
    scsh[j] = sc;
    scsh[128 + j] = b[j] - mu * sc;
  }
}

__global__ void k_leaky(float* __restrict__ h1, const float* __restrict__ scsh) {
  int j = threadIdx.x;
  int g = blockIdx.x;
  float v = fmaf(h1[g * 128 + j], scsh[j], scsh[128 + j]);
  h1[g * 128 + j] = v > 0.0f ? v : 0.2f * v;
}

__global__ void k_head(const float* __restrict__ h1, const float* __restrict__ fc2w,
                       const float* __restrict__ fc2b, const float* __restrict__ d1w,
                       const float* __restrict__ d1b, const float* __restrict__ d2w,
                       const float* __restrict__ d2b, float* __restrict__ out) {
  __shared__ float emb[16];
  int g = blockIdx.x;
  int t = threadIdx.x;  // 0..63
  if (t < 16) {
    float acc = fc2b[t];
    for (int k = 0; k < 128; k++) acc = fmaf(h1[g * 128 + k], fc2w[k * 16 + t], acc);
    emb[t] = acc;
    out[NG + g * 16 + t] = acc;
  }
  __syncthreads();
  float acc = d1b[t];
  for (int k = 0; k < 16; k++) acc = fmaf(emb[k], d1w[k * 64 + t], acc);
  acc = acc > 0.0f ? acc : 0.2f * acc;
  float p = acc * d2w[t];
  for (int off = 32; off > 0; off >>= 1) p += __shfl_down(p, off);
  if (t == 0) out[g] = p + d2b[0];
}

extern "C" void kernel_launch(void* const* d_in, const int* in_sizes, int n_in,
                              void* d_out, int out_size, void* d_ws, size_t ws_size,
                              hipStream_t stream) {
  const float* x    = (const float*)d_in[0];
  const int*   ei   = (const int*)d_in[1];
  const int*   ety  = (const int*)d_in[2];
  const int*   batch= (const int*)d_in[3];
  const float* c1w  = (const float*)d_in[4];
  const float* c1r  = (const float*)d_in[5];
  const float* c1b  = (const float*)d_in[6];
  const float* bn1g = (const float*)d_in[7];
  const float* bn1b = (const float*)d_in[8];
  const float* c2w  = (const float*)d_in[9];
  const float* c2r  = (const float*)d_in[10];
  const float* c2b  = (const float*)d_in[11];
  const float* bn2g = (const float*)d_in[12];
  const float* bn2b = (const float*)d_in[13];
  const float* c3w  = (const float*)d_in[14];
  const float* c3r  = (const float*)d_in[15];
  const float* c3b  = (const float*)d_in[16];
  const float* bn3g = (const float*)d_in[17];
  const float* bn3b = (const float*)d_in[18];
  const float* fc1w = (const float*)d_in[19];
  const float* fc1b = (const float*)d_in[20];
  const float* fbg  = (const float*)d_in[21];
  const float* fbb  = (const float*)d_in[22];
  const float* fc2w = (const float*)d_in[23];
  const float* fc2b = (const float*)d_in[24];
  const float* d1w  = (const float*)d_in[25];
  const float* d1b  = (const float*)d_in[26];
  const float* d2w  = (const float*)d_in[27];
  const float* d2b  = (const float*)d_in[28];
  const int* esrc = ei;
  const int* edst = ei + NE;
  float* out = (float*)d_out;

  float* W = (float*)d_ws;
  size_t o = 0;
  auto alloc = [&](size_t n) { float* p = W + o; o += (n + 63) & ~(size_t)63; return p; };
  unsigned* cnt      = (unsigned*)alloc(M_KEYS);
  float*    psum     = alloc(NG * 192);
  unsigned* pmax     = (unsigned*)alloc(NG * 192);
  float*    cntg     = alloc(NG);
  float*    statsrep = alloc(3 * RREP * 128);
  size_t zone = o;  // buffers [0, zone) zeroed every call
  int*      rowstart = (int*)alloc(M_KEYS + 1);
  int*      rank = (int*)alloc(NE);
  int2*     eb   = (int2*)alloc((size_t)2 * NE);
  unsigned* bsum = (unsigned*)alloc(1024);
  unsigned* boff = (unsigned*)alloc(1024);
  float*    scsh = alloc(3 * 128);
  float*    fcsc = alloc(256);
  float*    h1   = alloc(NG * 128);
  float*    tmp1 = alloc((size_t)NN * HD);
  float*    tmp2 = alloc((size_t)NN * HD);
  float*    tmp3 = alloc((size_t)NN * HD);
  ushort_t* hbig = (ushort_t*)alloc((size_t)NN * HW / 2);  // bf16 h
  ushort_t* xbf  = (ushort_t*)alloc((size_t)NN * HD);      // hi/lo bf16 x (2F shorts/row)
  ushort_t* wt1  = (ushort_t*)alloc(576 * FIN / 2);
  ushort_t* wt2  = (ushort_t*)alloc(576 * HD / 2);
  ushort_t* wt3  = (ushort_t*)alloc(576 * HD / 2);
  (void)ws_size; (void)in_sizes; (void)n_in; (void)out_size;

  // ---- preprocess: (dst,rel)-keyed CSR with {offset, invcnt} records ----
  k_zero<<<(int)((zone + 255) / 256), 256, 0, stream>>>(W, (int)zone);
  k_cnt<<<(NE + 255) / 256, 256, 0, stream>>>(edst, ety, cnt, rank);
  k_scanA<<<NB, 256, 0, stream>>>(cnt, bsum);
  k_scanB<<<1, 1024, 0, stream>>>(bsum, boff, rowstart);
  k_scanC<<<NB, 256, 0, stream>>>(cnt, boff, rowstart);
  k_place<<<(NE + 255) / 256, 256, 0, stream>>>(esrc, edst, ety, rank, rowstart, cnt, eb);
  k_wconv<FIN><<<(576 * FIN + 255) / 256, 256, 0, stream>>>(c1w, c1r, wt1);
  k_wconv<HD><<<(576 * HD + 255) / 256, 256, 0, stream>>>(c2w, c2r, wt2);
  k_wconv<HD><<<(576 * HD + 255) / 256, 256, 0, stream>>>(c3w, c3r, wt3);

  // ---- transform-first layers: tobf -> MFMA xform -> 4x-packed aggregate ----
  k_tobf<FIN, false><<<NN * FIN / 256, 256, 0, stream>>>(x, nullptr, xbf);
  k_xmm<FIN><<<NN / 16, 256, 0, stream>>>(xbf, wt1, hbig);
  k_agg4<<<NN / 4, 256, 0, stream>>>(hbig, rowstart, eb, c1b, tmp1, statsrep);
  k_finstats<<<1, 64, 0, stream>>>(statsrep, bn1g, bn1b, scsh);

  k_tobf<HD, true><<<NN * HD / 256, 256, 0, stream>>>(tmp1, scsh, xbf);
  k_xmm<HD><<<NN / 16, 256, 0, stream>>>(xbf, wt2, hbig);
  k_agg4<<<NN / 4, 256, 0, stream>>>(hbig, rowstart, eb, c2b, tmp2, statsrep + RREP * 128);
  k_finstats<<<1, 64, 0, stream>>>(statsrep + RREP * 128, bn2g, bn2b, scsh + 128);

  k_tobf<HD, true><<<NN * HD / 256, 256, 0, stream>>>(tmp2, scsh + 128, xbf);
  k_xmm<HD><<<NN / 16, 256, 0, stream>>>(xbf, wt3, hbig);
  k_agg4<<<NN / 4, 256, 0, stream>>>(hbig, rowstart, eb, c3b, tmp3, statsrep + 2 * RREP * 128);
  k_finstats<<<1, 64, 0, stream>>>(statsrep + 2 * RREP * 128, bn3g, bn3b, scsh + 256);

  // ---- pooling + head ----
  k_poolseg<<<NN / PCH, 192, 0, stream>>>(tmp1, tmp2, tmp3, scsh, batch, psum, pmax, cntg);
  k_fc1<<<NG, 128, 0, stream>>>(psum, pmax, cntg, fc1w, fc1b, h1);
  k_fcbn_stats<<<1, 512, 0, stream>>>(h1, fbg, fbb, fcsc);
  k_leaky<<<NG, 128, 0, stream>>>(h1, fcsc);
  k_head<<<NG, 64, 0, stream>>>(h1, fc2w, fc2b, d1w, d1b, d2w, d2b, out);
}

// Round 10
// 521.860 us; speedup vs baseline: 4.3084x; 1.0050x over previous
//
#include <hip/hip_runtime.h>

#define NN 100000
#define NE 1250000
#define FIN 32
#define HD 64
#define NR 8
#define NG 256
#define BN_EPS 1e-5f
#define PCH 100          // nodes per pooling block (divides NN)
#define M_KEYS (NN * NR) // 800000 (dst,rel) segments
#define NB 782           // scan blocks: 782*1024 >= 800000
#define RREP 32          // BN-stat atomic replicas
#define HW 576           // h width: 8 rel * 64 + root 64

typedef unsigned short ushort_t;
typedef __attribute__((ext_vector_type(8))) short short8;
typedef __attribute__((ext_vector_type(4))) float f32x4;

static __device__ __forceinline__ ushort_t f2bf(float f) {
  unsigned u = __float_as_uint(f);
  u += 0x7fffu + ((u >> 16) & 1u);  // RNE
  return (ushort_t)(u >> 16);
}
static __device__ __forceinline__ float bf2f(ushort_t b) {
  return __uint_as_float((unsigned)b << 16);
}

__global__ void k_zero(float* __restrict__ p, int n) {
  int i = blockIdx.x * 256 + threadIdx.x;
  if (i < n) p[i] = 0.0f;
}

// pass 1: per-(dst,rel) counts + per-edge rank
__global__ void k_cnt(const int* __restrict__ dst, const int* __restrict__ ty,
                      unsigned* __restrict__ cnt, int* __restrict__ rank) {
  int e = blockIdx.x * 256 + threadIdx.x;
  if (e < NE) {
    int key = dst[e] * NR + ty[e];
    rank[e] = (int)atomicAdd(&cnt[key], 1u);
  }
}

// hierarchical exclusive scan of cnt[M_KEYS] -> rowstart[M_KEYS+1]
__global__ void k_scanA(const unsigned* __restrict__ cnt, unsigned* __restrict__ bsum) {
  __shared__ unsigned red[256];
  int t = threadIdx.x;
  int base = blockIdx.x * 1024 + t * 4;
  unsigned s = 0;
  #pragma unroll
  for (int i = 0; i < 4; i++) {
    int idx = base + i;
    if (idx < M_KEYS) s += cnt[idx];
  }
  red[t] = s;
  __syncthreads();
  for (int off = 128; off > 0; off >>= 1) {
    if (t < off) red[t] += red[t + off];
    __syncthreads();
  }
  if (t == 0) bsum[blockIdx.x] = red[0];
}

__global__ __launch_bounds__(1024) void k_scanB(const unsigned* __restrict__ bsum,
                                                unsigned* __restrict__ boff,
                                                int* __restrict__ rowstart) {
  __shared__ unsigned sb[1024];
  int t = threadIdx.x;
  unsigned mine = (t < NB) ? bsum[t] : 0u;
  sb[t] = mine;
  __syncthreads();
  for (int off = 1; off < 1024; off <<= 1) {
    unsigned v = (t >= off) ? sb[t - off] : 0u;
    __syncthreads();
    sb[t] += v;
    __syncthreads();
  }
  if (t < NB) boff[t] = sb[t] - mine;
  if (t == 1023) rowstart[M_KEYS] = (int)sb[1023];
}

__global__ void k_scanC(const unsigned* __restrict__ cnt, const unsigned* __restrict__ boff,
                        int* __restrict__ rowstart) {
  __shared__ unsigned sb[256];
  int t = threadIdx.x;
  int base = blockIdx.x * 1024 + t * 4;
  unsigned c0 = (base + 0 < M_KEYS) ? cnt[base + 0] : 0u;
  unsigned c1 = (base + 1 < M_KEYS) ? cnt[base + 1] : 0u;
  unsigned c2 = (base + 2 < M_KEYS) ? cnt[base + 2] : 0u;
  unsigned c3 = (base + 3 < M_KEYS) ? cnt[base + 3] : 0u;
  unsigned tot = c0 + c1 + c2 + c3;
  sb[t] = tot;
  __syncthreads();
  for (int off = 1; off < 256; off <<= 1) {
    unsigned v = (t >= off) ? sb[t - off] : 0u;
    __syncthreads();
    sb[t] += v;
    __syncthreads();
  }
  unsigned run = boff[blockIdx.x] + (sb[t] - tot);
  if (base + 0 < M_KEYS) rowstart[base + 0] = (int)run; run += c0;
  if (base + 1 < M_KEYS) rowstart[base + 1] = (int)run; run += c1;
  if (base + 2 < M_KEYS) rowstart[base + 2] = (int)run; run += c2;
  if (base + 3 < M_KEYS) rowstart[base + 3] = (int)run;
}

// pass 2: place {h-offset, invcnt} records into (dst,rel)-CSR (8B/edge)
__global__ void k_place(const int* __restrict__ src, const int* __restrict__ dst,
                        const int* __restrict__ ty, const int* __restrict__ rank,
                        const int* __restrict__ rowstart, const unsigned* __restrict__ cnt,
                        int2* __restrict__ eb) {
  int e = blockIdx.x * 256 + threadIdx.x;
  if (e < NE) {
    int t = ty[e];
    int key = dst[e] * NR + t;
    float ic = 1.0f / (float)max(cnt[key], 1u);
    int2 v;
    v.x = src[e] * HW + t * 64;   // element offset into h
    v.y = __float_as_int(ic);
    eb[rowstart[key] + rank[e]] = v;
  }
}

// wt[c][k] bf16, c<576 output cols of [W_0..W_7 | root], k<F (transposed so
// each MFMA B-fragment is a contiguous short8).
template <int F>
__global__ void k_wconv(const float* __restrict__ convw, const float* __restrict__ root,
                        ushort_t* __restrict__ wt) {
  int i = blockIdx.x * 256 + threadIdx.x;  // over 576*F
  if (i >= 576 * F) return;
  int c = i / F, k = i % F;
  float v = (c < 512) ? convw[((size_t)(c >> 6) * F + k) * 64 + (c & 63)]
                      : root[(size_t)k * 64 + (c & 63)];
  wt[(size_t)c * F + k] = f2bf(v);
}

// xbf[n] = hi/lo bf16 split of BNReLU(x[n]): [n][0..F-1]=hi, [n][F..2F-1]=lo
template <int F, bool APPLY_BN>
__global__ void k_tobf(const float* __restrict__ xin, const float* __restrict__ scsh,
                       ushort_t* __restrict__ xbf) {
  int i = blockIdx.x * 256 + threadIdx.x;  // over NN*F
  int n = i / F, k = i % F;
  float v = xin[i];
  if (APPLY_BN) v = fmaxf(fmaf(v, scsh[k], scsh[64 + k]), 0.0f);
  ushort_t hi = f2bf(v);
  xbf[(size_t)n * (2 * F) + k] = hi;
  xbf[(size_t)n * (2 * F) + F + k] = f2bf(v - bf2f(hi));
}

// MFMA xform: h[16 rows x 576 cols per block] = xbf(hi+lo) @ wt.
// B frags register-resident (wt <=74KB, L2-hot); A frags direct from global.
// Output staged in LDS (rows padded to 592 -> quad-rows on distinct bank
// groups), then written as one contiguous 18.4KB block with uint4 stores.
template <int F>
__global__ __launch_bounds__(256) void k_xmm(const ushort_t* __restrict__ xbf,
                                             const ushort_t* __restrict__ wt,
                                             ushort_t* __restrict__ h) {
  constexpr int KK = 2 * F;
  constexpr int LDR = 592;  // padded row (ushorts); 592*2=1184B = 74*16B
  __shared__ ushort_t ot[16 * LDR];
  int lane = threadIdx.x & 63;
  int w = threadIdx.x >> 6;
  int nbase = blockIdx.x * 16;
  int m = lane & 15;   // A row / B col within tile
  int q = lane >> 4;   // quad 0..3, k-offset q*8
  const ushort_t* xrow = xbf + (size_t)(nbase + m) * KK + q * 8;
  f32x4 acc[9];
  #pragma unroll
  for (int t = 0; t < 9; t++) acc[t] = (f32x4){0.f, 0.f, 0.f, 0.f};
  int ct0 = w * 9;
  #pragma unroll
  for (int ks = 0; ks < F / 32; ks++) {
    short8 ah = *(const short8*)(xrow + ks * 32);       // hi half
    short8 al = *(const short8*)(xrow + F + ks * 32);   // lo half
    #pragma unroll
    for (int t = 0; t < 9; t++) {
      const ushort_t* wp = wt + (size_t)((ct0 + t) * 16 + m) * F + ks * 32 + q * 8;
      short8 b = *(const short8*)wp;
      acc[t] = __builtin_amdgcn_mfma_f32_16x16x32_bf16(ah, b, acc[t], 0, 0, 0);
      acc[t] = __builtin_amdgcn_mfma_f32_16x16x32_bf16(al, b, acc[t], 0, 0, 0);
    }
  }
  #pragma unroll
  for (int t = 0; t < 9; t++) {
    int col = (ct0 + t) * 16 + m;
    #pragma unroll
    for (int j = 0; j < 4; j++) {
      int row = q * 4 + j;  // C/D: col=lane&15, row=(lane>>4)*4+reg
      ot[row * LDR + col] = f2bf(acc[t][j]);
    }
  }
  __syncthreads();
  // coalesced copy-out: 16 rows x 1152B, globally contiguous at h+nbase*HW
  uint4* dst = (uint4*)(h + (size_t)nbase * HW);
  for (int idx = threadIdx.x; idx < 16 * 72; idx += 256) {
    int row = idx / 72, i = idx - row * 72;
    dst[row * 72 + i] = *(const uint4*)&ot[row * LDR + i * 8];
  }
}

// 4-edges-per-instruction aggregation: wave = 1 node; lane groups of 16 each
// own one edge stream; each lane loads uint2 = 4 bf16 channels of its group's
// edge; flat acc += h * invcnt (no run logic); 2 shfl_xor combine at end.
// Epilogue: +self+bias, f32 store, BN column stats via LDS + replica atomics.
__global__ __launch_bounds__(256) void k_agg4(
    const ushort_t* __restrict__ h, const int* __restrict__ rs,
    const int2* __restrict__ eb, const float* __restrict__ bias,
    float* __restrict__ outp, float* __restrict__ statsrep) {
  __shared__ float red[512];
  int lane = threadIdx.x & 63, w = threadIdx.x >> 6;
  int n = blockIdx.x * 4 + w;
  int lo = rs[n * NR];
  int cnt = rs[n * NR + NR] - lo;
  int g = lane >> 4;          // edge group 0..3
  int c4 = (lane & 15) * 4;   // channel base
  float a0 = 0.f, a1 = 0.f, a2 = 0.f, a3 = 0.f;
  for (int base = 0; base < cnt; base += 16) {
    int2 eo[4];
    #pragma unroll
    for (int s = 0; s < 4; s++) {
      int el = base + s * 4 + g;
      int idx = lo + (el < cnt ? el : cnt - 1);
      eo[s] = eb[idx];
      if (el >= cnt) eo[s].y = 0;  // weight 0 for padding lanes
    }
    uint2 hv[4];
    #pragma unroll
    for (int s = 0; s < 4; s++)
      hv[s] = *(const uint2*)(h + (size_t)eo[s].x + c4);
    #pragma unroll
    for (int s = 0; s < 4; s++) {
      float ic = __int_as_float(eo[s].y);
      a0 = fmaf(__uint_as_float(hv[s].x << 16), ic, a0);
      a1 = fmaf(__uint_as_float(hv[s].x & 0xffff0000u), ic, a1);
      a2 = fmaf(__uint_as_float(hv[s].y << 16), ic, a2);
      a3 = fmaf(__uint_as_float(hv[s].y & 0xffff0000u), ic, a3);
    }
  }
  a0 += __shfl_xor(a0, 16); a0 += __shfl_xor(a0, 32);
  a1 += __shfl_xor(a1, 16); a1 += __shfl_xor(a1, 32);
  a2 += __shfl_xor(a2, 16); a2 += __shfl_xor(a2, 32);
  a3 += __shfl_xor(a3, 16); a3 += __shfl_xor(a3, 32);
  if (g == 0) {
    uint2 sv = *(const uint2*)(h + (size_t)n * HW + 512 + c4);
    float4 b4 = *(const float4*)(bias + c4);
    float d0 = a0 + __uint_as_float(sv.x << 16) + b4.x;
    float d1 = a1 + __uint_as_float(sv.x & 0xffff0000u) + b4.y;
    float d2 = a2 + __uint_as_float(sv.y << 16) + b4.z;
    float d3 = a3 + __uint_as_float(sv.y & 0xffff0000u) + b4.w;
    *(float4*)(outp + (size_t)n * HD + c4) = make_float4(d0, d1, d2, d3);
    *(float4*)(&red[w * 64 + c4]) = make_float4(d0, d1, d2, d3);
    *(float4*)(&red[256 + w * 64 + c4]) =
        make_float4(d0 * d0, d1 * d1, d2 * d2, d3 * d3);
  }
  __syncthreads();
  if (w == 0) {
    float ts = red[lane] + red[64 + lane] + red[128 + lane] + red[192 + lane];
    float tss = red[256 + lane] + red[320 + lane] + red[384 + lane] + red[448 + lane];
    int rp = blockIdx.x & (RREP - 1);
    atomicAdd(&statsrep[rp * 128 + lane], ts);
    atomicAdd(&statsrep[rp * 128 + 64 + lane], tss);
  }
}

// reduce stat replicas -> BN (scale, shift)
__global__ void k_finstats(const float* __restrict__ rep, const float* __restrict__ g,
                           const float* __restrict__ b, float* __restrict__ scsh) {
  int lane = threadIdx.x;  // 64
  float s = 0.f, ss = 0.f;
  for (int rp = 0; rp < RREP; rp++) {
    s += rep[rp * 128 + lane];
    ss += rep[rp * 128 + 64 + lane];
  }
  float mu = s * (1.0f / NN);
  float var = ss * (1.0f / NN) - mu * mu;
  float sc = g[lane] * rsqrtf(var + BN_EPS);
  scsh[lane] = sc;
  scsh[64 + lane] = b[lane] - mu * sc;
}

// sorted-batch segmented pooling over RAW layer outputs with inline BN+ReLU.
__global__ void k_poolseg(const float* __restrict__ t1, const float* __restrict__ t2,
                          const float* __restrict__ t3, const float* __restrict__ scsh,
                          const int* __restrict__ batch, float* __restrict__ psum,
                          unsigned* __restrict__ pmax, float* __restrict__ cntg) {
  __shared__ int bsh[PCH];
  int base = blockIdx.x * PCH;
  int c = threadIdx.x;  // 0..191
  for (int i = c; i < PCH; i += 192) bsh[i] = batch[base + i];
  __syncthreads();
  int L = c >> 6, cc = c & 63;
  const float* xs = (L == 0) ? t1 : (L == 1) ? t2 : t3;
  float sc = scsh[L * 128 + cc], sh = scsh[L * 128 + 64 + cc];
  int cur = bsh[0];
  float sum = 0.0f, mx = 0.0f;
  int runlen = 0;
  #pragma unroll 4
  for (int i = 0; i < PCH; i++) {
    int g = bsh[i];
    float v = fmaxf(fmaf(xs[(size_t)(base + i) * 64 + cc], sc, sh), 0.0f);
    if (g != cur) {  // wave-uniform, rare
      atomicAdd(&psum[cur * 192 + c], sum);
      atomicMax(&pmax[cur * 192 + c], __float_as_uint(mx));
      if (c == 0) atomicAdd(&cntg[cur], (float)runlen);
      cur = g; sum = 0.0f; mx = 0.0f; runlen = 0;
    }
    sum += v;
    mx = fmaxf(mx, v);
    runlen++;
  }
  atomicAdd(&psum[cur * 192 + c], sum);
  atomicMax(&pmax[cur * 192 + c], __float_as_uint(mx));
  if (c == 0) atomicAdd(&cntg[cur], (float)runlen);
}

__global__ void k_fc1(const float* __restrict__ psum, const unsigned* __restrict__ pmax,
                      const float* __restrict__ cntg, const float* __restrict__ w,
                      const float* __restrict__ bias, float* __restrict__ h1) {
  __shared__ float a[384];
  int g = blockIdx.x;
  float ic = 1.0f / fmaxf(cntg[g], 1.0f);
  for (int c = threadIdx.x; c < 384; c += 128) {
    a[c] = (c < 192) ? psum[g * 192 + c] * ic : __uint_as_float(pmax[g * 192 + (c - 192)]);
  }
  __syncthreads();
  int j = threadIdx.x;
  float acc = bias[j];
  for (int k = 0; k < 384; k++) acc = fmaf(a[k], w[k * 128 + j], acc);
  h1[g * 128 + j] = acc;
}

__global__ void k_fcbn_stats(const float* __restrict__ h1, const float* __restrict__ g,
                             const float* __restrict__ b, float* __restrict__ scsh) {
  __shared__ float sr[512], ssr[512];
  int j = threadIdx.x & 127, q = threadIdx.x >> 7;
  float s = 0.f, ss = 0.f;
  for (int i = q * 64; i < q * 64 + 64; i++) {
    float v = h1[i * 128 + j];
    s += v;
    ss = fmaf(v, v, ss);
  }
  sr[threadIdx.x] = s;
  ssr[threadIdx.x] = ss;
  __syncthreads();
  if (q == 0) {
    s = sr[j] + sr[128 + j] + sr[256 + j] + sr[384 + j];
    ss = ssr[j] + ssr[128 + j] + ssr[256 + j] + ssr[384 + j];
    float mu = s * (1.0f / NG);
    float var = ss * (1.0f / NG) - mu * mu;
    float sc = g[j] * rsqrtf(var + BN_EPS);
    scsh[j] = sc;
    scsh[128 + j] = b[j] - mu * sc;
  }
}

__global__ void k_leaky(float* __restrict__ h1, const float* __restrict__ scsh) {
  int j = threadIdx.x;
  int g = blockIdx.x;
  float v = fmaf(h1[g * 128 + j], scsh[j], scsh[128 + j]);
  h1[g * 128 + j] = v > 0.0f ? v : 0.2f * v;
}

__global__ void k_head(const float* __restrict__ h1, const float* __restrict__ fc2w,
                       const float* __restrict__ fc2b, const float* __restrict__ d1w,
                       const float* __restrict__ d1b, const float* __restrict__ d2w,
                       const float* __restrict__ d2b, float* __restrict__ out) {
  __shared__ float emb[16];
  int g = blockIdx.x;
  int t = threadIdx.x;  // 0..63
  if (t < 16) {
    float acc = fc2b[t];
    for (int k = 0; k < 128; k++) acc = fmaf(h1[g * 128 + k], fc2w[k * 16 + t], acc);
    emb[t] = acc;
    out[NG + g * 16 + t] = acc;
  }
  __syncthreads();
  float acc = d1b[t];
  for (int k = 0; k < 16; k++) acc = fmaf(emb[k], d1w[k * 64 + t], acc);
  acc = acc > 0.0f ? acc : 0.2f * acc;
  float p = acc * d2w[t];
  for (int off = 32; off > 0; off >>= 1) p += __shfl_down(p, off);
  if (t == 0) out[g] = p + d2b[0];
}

extern "C" void kernel_launch(void* const* d_in, const int* in_sizes, int n_in,
                              void* d_out, int out_size, void* d_ws, size_t ws_size,
                              hipStream_t stream) {
  const float* x    = (const float*)d_in[0];
  const int*   ei   = (const int*)d_in[1];
  const int*   ety  = (const int*)d_in[2];
  const int*   batch= (const int*)d_in[3];
  const float* c1w  = (const float*)d_in[4];
  const float* c1r  = (const float*)d_in[5];
  const float* c1b  = (const float*)d_in[6];
  const float* bn1g = (const float*)d_in[7];
  const float* bn1b = (const float*)d_in[8];
  const float* c2w  = (const float*)d_in[9];
  const float* c2r  = (const float*)d_in[10];
  const float* c2b  = (const float*)d_in[11];
  const float* bn2g = (const float*)d_in[12];
  const float* bn2b = (const float*)d_in[13];
  const float* c3w  = (const float*)d_in[14];
  const float* c3r  = (const float*)d_in[15];
  const float* c3b  = (const float*)d_in[16];
  const float* bn3g = (const float*)d_in[17];
  const float* bn3b = (const float*)d_in[18];
  const float* fc1w = (const float*)d_in[19];
  const float* fc1b = (const float*)d_in[20];
  const float* fbg  = (const float*)d_in[21];
  const float* fbb  = (const float*)d_in[22];
  const float* fc2w = (const float*)d_in[23];
  const float* fc2b = (const float*)d_in[24];
  const float* d1w  = (const float*)d_in[25];
  const float* d1b  = (const float*)d_in[26];
  const float* d2w  = (const float*)d_in[27];
  const float* d2b  = (const float*)d_in[28];
  const int* esrc = ei;
  const int* edst = ei + NE;
  float* out = (float*)d_out;

  float* W = (float*)d_ws;
  size_t o = 0;
  auto alloc = [&](size_t n) { float* p = W + o; o += (n + 63) & ~(size_t)63; return p; };
  unsigned* cnt      = (unsigned*)alloc(M_KEYS);
  float*    psum     = alloc(NG * 192);
  unsigned* pmax     = (unsigned*)alloc(NG * 192);
  float*    cntg     = alloc(NG);
  float*    statsrep = alloc(3 * RREP * 128);
  size_t zone = o;  // buffers [0, zone) zeroed every call
  int*      rowstart = (int*)alloc(M_KEYS + 1);
  int*      rank = (int*)alloc(NE);
  int2*     eb   = (int2*)alloc((size_t)2 * NE);
  unsigned* bsum = (unsigned*)alloc(1024);
  unsigned* boff = (unsigned*)alloc(1024);
  float*    scsh = alloc(3 * 128);
  float*    fcsc = alloc(256);
  float*    h1   = alloc(NG * 128);
  float*    tmp1 = alloc((size_t)NN * HD);
  float*    tmp2 = alloc((size_t)NN * HD);
  float*    tmp3 = alloc((size_t)NN * HD);
  ushort_t* hbig = (ushort_t*)alloc((size_t)NN * HW / 2);  // bf16 h
  ushort_t* xbf  = (ushort_t*)alloc((size_t)NN * HD);      // hi/lo bf16 x (2F shorts/row)
  ushort_t* wt1  = (ushort_t*)alloc(576 * FIN / 2);
  ushort_t* wt2  = (ushort_t*)alloc(576 * HD / 2);
  ushort_t* wt3  = (ushort_t*)alloc(576 * HD / 2);
  (void)ws_size; (void)in_sizes; (void)n_in; (void)out_size;

  // ---- preprocess: (dst,rel)-keyed CSR with {offset, invcnt} records ----
  k_zero<<<(int)((zone + 255) / 256), 256, 0, stream>>>(W, (int)zone);
  k_cnt<<<(NE + 255) / 256, 256, 0, stream>>>(edst, ety, cnt, rank);
  k_scanA<<<NB, 256, 0, stream>>>(cnt, bsum);
  k_scanB<<<1, 1024, 0, stream>>>(bsum, boff, rowstart);
  k_scanC<<<NB, 256, 0, stream>>>(cnt, boff, rowstart);
  k_place<<<(NE + 255) / 256, 256, 0, stream>>>(esrc, edst, ety, rank, rowstart, cnt, eb);
  k_wconv<FIN><<<(576 * FIN + 255) / 256, 256, 0, stream>>>(c1w, c1r, wt1);
  k_wconv<HD><<<(576 * HD + 255) / 256, 256, 0, stream>>>(c2w, c2r, wt2);
  k_wconv<HD><<<(576 * HD + 255) / 256, 256, 0, stream>>>(c3w, c3r, wt3);

  // ---- transform-first layers: tobf -> MFMA xform -> 4x-packed aggregate ----
  k_tobf<FIN, false><<<NN * FIN / 256, 256, 0, stream>>>(x, nullptr, xbf);
  k_xmm<FIN><<<NN / 16, 256, 0, stream>>>(xbf, wt1, hbig);
  k_agg4<<<NN / 4, 256, 0, stream>>>(hbig, rowstart, eb, c1b, tmp1, statsrep);
  k_finstats<<<1, 64, 0, stream>>>(statsrep, bn1g, bn1b, scsh);

  k_tobf<HD, true><<<NN * HD / 256, 256, 0, stream>>>(tmp1, scsh, xbf);
  k_xmm<HD><<<NN / 16, 256, 0, stream>>>(xbf, wt2, hbig);
  k_agg4<<<NN / 4, 256, 0, stream>>>(hbig, rowstart, eb, c2b, tmp2, statsrep + RREP * 128);
  k_finstats<<<1, 64, 0, stream>>>(statsrep + RREP * 128, bn2g, bn2b, scsh + 128);

  k_tobf<HD, true><<<NN * HD / 256, 256, 0, stream>>>(tmp2, scsh + 128, xbf);
  k_xmm<HD><<<NN / 16, 256, 0, stream>>>(xbf, wt3, hbig);
  k_agg4<<<NN / 4, 256, 0, stream>>>(hbig, rowstart, eb, c3b, tmp3, statsrep + 2 * RREP * 128);
  k_finstats<<<1, 64, 0, stream>>>(statsrep + 2 * RREP * 128, bn3g, bn3b, scsh + 256);

  // ---- pooling + head ----
  k_poolseg<<<NN / PCH, 192, 0, stream>>>(tmp1, tmp2, tmp3, scsh, batch, psum, pmax, cntg);
  k_fc1<<<NG, 128, 0, stream>>>(psum, pmax, cntg, fc1w, fc1b, h1);
  k_fcbn_stats<<<1, 512, 0, stream>>>(h1, fbg, fbb, fcsc);
  k_leaky<<<NG, 128, 0, stream>>>(h1, fcsc);
  k_head<<<NG, 64, 0, stream>>>(h1, fc2w, fc2b, d1w, d1b, d2w, d2b, out);
}